// Round 7
// baseline (1281.982 us; speedup 1.0000x reference)
//
#include <hip/hip_runtime.h>
#include <hip/hip_bf16.h>
#include <math.h>

#define N1      20000          // nodes per graph
#define NT      40000          // both graphs
#define E1      640000         // edges per graph
#define ET      1280000
#define FIN_D   256
#define HID_D   512
#define TOPK    1000
#define MP      40064          // 313 * 128  (padded M for both graphs)
#define SCAN_NB 157            // ceil(40000/256)

typedef __attribute__((ext_vector_type(8))) short short8;
typedef __attribute__((ext_vector_type(4))) float floatx4;
typedef unsigned int uintx4 __attribute__((ext_vector_type(4)));

__device__ __forceinline__ unsigned short f2bf(float f) {
    union { __hip_bfloat16 h; unsigned short u; } cv;
    cv.h = __float2bfloat16(f);
    return cv.u;
}
__device__ __forceinline__ float bflo(unsigned int u) {
    union { unsigned int i; float f; } c; c.i = u << 16; return c.f;
}
__device__ __forceinline__ float bfhi(unsigned int u) {
    union { unsigned int i; float f; } c; c.i = u & 0xffff0000u; return c.f;
}

// ---------------- CSR build (both graphs in one node space) ----------------
__global__ void hist_kernel(const int* __restrict__ ei1, const int* __restrict__ ei2,
                            int* __restrict__ deg) {
    int e = blockIdx.x * blockDim.x + threadIdx.x;
    if (e >= ET) return;
    int d = (e < E1) ? ei1[E1 + e] : (ei2[E1 + (e - E1)] + N1);
    atomicAdd(&deg[d], 1);
}

__global__ void scan1_kernel(const int* __restrict__ deg, int* __restrict__ tmp,
                             int* __restrict__ bsum) {
    __shared__ int tile[256];
    int t = threadIdx.x;
    int i = blockIdx.x * 256 + t;
    int v = (i < NT) ? deg[i] : 0;
    tile[t] = v;
    __syncthreads();
    for (int off = 1; off < 256; off <<= 1) {
        int x = (t >= off) ? tile[t - off] : 0;
        __syncthreads();
        tile[t] += x;
        __syncthreads();
    }
    if (i < NT) tmp[i] = tile[t] - v;
    if (t == 255) bsum[blockIdx.x] = tile[255];
}

__global__ void scan2_kernel(const int* __restrict__ bsum, int* __restrict__ boff,
                             int* __restrict__ row_start) {
    __shared__ int tile[256];
    int t = threadIdx.x;
    int v = (t < SCAN_NB) ? bsum[t] : 0;
    tile[t] = v;
    __syncthreads();
    for (int off = 1; off < 256; off <<= 1) {
        int x = (t >= off) ? tile[t - off] : 0;
        __syncthreads();
        tile[t] += x;
        __syncthreads();
    }
    if (t < SCAN_NB) boff[t] = tile[t] - v;
    if (t == 255) row_start[NT] = tile[255];
}

__global__ void scan3_kernel(const int* __restrict__ tmp, const int* __restrict__ boff,
                             int* __restrict__ row_start, int* __restrict__ cursor) {
    int i = blockIdx.x * 256 + threadIdx.x;
    if (i < NT) {
        int rs = tmp[i] + boff[blockIdx.x];
        row_start[i] = rs;
        cursor[i] = rs;
    }
}

__global__ void fill_kernel(const int* __restrict__ ei1, const int* __restrict__ ei2,
                            int* __restrict__ cursor, int* __restrict__ csr_src) {
    int e = blockIdx.x * blockDim.x + threadIdx.x;
    if (e >= ET) return;
    int s, d;
    if (e < E1) { s = ei1[e]; d = ei1[E1 + e]; }
    else        { int e2 = e - E1; s = ei2[e2] + N1; d = ei2[E1 + e2] + N1; }
    int p = atomicAdd(&cursor[d], 1);
    csr_src[p] = s;
}

// ---------------- conversions ----------------
__global__ void convx_kernel(const float* __restrict__ x, unsigned short* __restrict__ xb, int n4) {
    int i = blockIdx.x * 256 + threadIdx.x;
    if (i < n4) {
        float4 f = ((const float4*)x)[i];
        ushort4 u;
        u.x = f2bf(f.x); u.y = f2bf(f.y); u.z = f2bf(f.z); u.w = f2bf(f.w);
        ((ushort4*)xb)[i] = u;
    }
}

// W[K][N] fp32 -> Wt[N][K] bf16 (tiled transpose)
__global__ void convw_kernel(const float* __restrict__ W, unsigned short* __restrict__ Wt,
                             int K, int N) {
    __shared__ float tile[32][33];
    int k0 = blockIdx.x * 32, n0 = blockIdx.y * 32;
    int tx = threadIdx.x & 31, ty = threadIdx.x >> 5;
    for (int r = ty; r < 32; r += 8) tile[r][tx] = W[(size_t)(k0 + r) * N + n0 + tx];
    __syncthreads();
    for (int r = ty; r < 32; r += 8)
        Wt[(size_t)(n0 + r) * K + k0 + tx] = f2bf(tile[tx][r]);
}

// ---------------- GIN aggregation, XCD-slab + nt-stream version ---------------
// Slab of 32 bf16 cols pinned per XCD (blockIdx%8) => per-XCD WS 2.56 MB < 4 MB L2.
// KEY (r7): csr_src loads and h stores are NON-TEMPORAL so the streaming traffic
// does not evict the gather slab from L2. Self-term read stays temporal (it IS
// the gather table, read sequentially = free warm).
#define ACC8(u) do { \
    acc[0] += bflo((u).x); acc[1] += bfhi((u).x); \
    acc[2] += bflo((u).y); acc[3] += bfhi((u).y); \
    acc[4] += bflo((u).z); acc[5] += bfhi((u).z); \
    acc[6] += bflo((u).w); acc[7] += bfhi((u).w); } while (0)

template<int LPR, int NSLAB>   // LPR = uintx4 per full row (D/8); NSLAB = LPR/4
__launch_bounds__(256, 8)
__global__ void agg_slab_kernel(const unsigned short* __restrict__ x,
                                const int* __restrict__ row_start,
                                const int* __restrict__ csr_src,
                                unsigned short* __restrict__ h) {
    const int GRPS = NT / 64;                  // 625 node-groups of 64
    int b = blockIdx.x;
    int phase = b / (8 * GRPS);                // 0..NSLAB/8-1
    int rem = b % (8 * GRPS);
    int slab = phase * 8 + (rem & 7);          // stays on XCD (rem&7)
    int grp = rem >> 3;
    int nid = grp * 64 + (threadIdx.x >> 2);
    int c = threadIdx.x & 3;
    int chunk = slab * 4 + c;                  // 16B unit within row
    const uintx4* Xc = (const uintx4*)x + chunk;
    uintx4 v = Xc[(size_t)nid * LPR];          // temporal: warms the slab
    float acc[8];
    acc[0] = bflo(v.x); acc[1] = bfhi(v.x);
    acc[2] = bflo(v.y); acc[3] = bfhi(v.y);
    acc[4] = bflo(v.z); acc[5] = bfhi(v.z);
    acc[6] = bflo(v.w); acc[7] = bfhi(v.w);
    int s = row_start[nid], e = row_start[nid + 1];
    int p = s;
    // 8-deep batches: independent loads -> deep memory pipeline
    for (; p + 8 <= e; p += 8) {
        int n0 = __builtin_nontemporal_load(csr_src + p + 0);
        int n1 = __builtin_nontemporal_load(csr_src + p + 1);
        int n2 = __builtin_nontemporal_load(csr_src + p + 2);
        int n3 = __builtin_nontemporal_load(csr_src + p + 3);
        int n4 = __builtin_nontemporal_load(csr_src + p + 4);
        int n5 = __builtin_nontemporal_load(csr_src + p + 5);
        int n6 = __builtin_nontemporal_load(csr_src + p + 6);
        int n7 = __builtin_nontemporal_load(csr_src + p + 7);
        uintx4 u0 = Xc[(size_t)n0 * LPR];
        uintx4 u1 = Xc[(size_t)n1 * LPR];
        uintx4 u2 = Xc[(size_t)n2 * LPR];
        uintx4 u3 = Xc[(size_t)n3 * LPR];
        uintx4 u4 = Xc[(size_t)n4 * LPR];
        uintx4 u5 = Xc[(size_t)n5 * LPR];
        uintx4 u6 = Xc[(size_t)n6 * LPR];
        uintx4 u7 = Xc[(size_t)n7 * LPR];
        ACC8(u0); ACC8(u1); ACC8(u2); ACC8(u3);
        ACC8(u4); ACC8(u5); ACC8(u6); ACC8(u7);
    }
    for (; p + 2 <= e; p += 2) {
        int n0 = __builtin_nontemporal_load(csr_src + p + 0);
        int n1 = __builtin_nontemporal_load(csr_src + p + 1);
        uintx4 u0 = Xc[(size_t)n0 * LPR];
        uintx4 u1 = Xc[(size_t)n1 * LPR];
        ACC8(u0); ACC8(u1);
    }
    if (p < e) {
        int n0 = __builtin_nontemporal_load(csr_src + p);
        uintx4 u0 = Xc[(size_t)n0 * LPR];
        ACC8(u0);
    }
    uintx4 o;
    o.x = (unsigned)f2bf(acc[0]) | ((unsigned)f2bf(acc[1]) << 16);
    o.y = (unsigned)f2bf(acc[2]) | ((unsigned)f2bf(acc[3]) << 16);
    o.z = (unsigned)f2bf(acc[4]) | ((unsigned)f2bf(acc[5]) << 16);
    o.w = (unsigned)f2bf(acc[6]) | ((unsigned)f2bf(acc[7]) << 16);
    __builtin_nontemporal_store(o, (uintx4*)h + (size_t)nid * LPR + chunk);
}

// ---------------- bf16 MFMA GEMM: C = relu(A[MP,K] @ W[K,N] + bias), bf16 out ----
__launch_bounds__(256)
__global__ void gemm_mfma(const unsigned short* __restrict__ A,
                          const unsigned short* __restrict__ Wt,
                          const float* __restrict__ bias,
                          unsigned short* __restrict__ C,
                          int K, int N) {
    __shared__ unsigned short As[128 * 32];
    __shared__ unsigned short Bs[128 * 32];
    int tid = threadIdx.x;
    int lane = tid & 63;
    int w = tid >> 6;
    int wr = w >> 1, wc = w & 1;
    int row0 = blockIdx.x * 128;
    int col0 = blockIdx.y * 128;
    floatx4 acc[4][4] = {};
    int lr = tid >> 2;
    int c8 = (tid & 3) * 8;
    const unsigned short* Ag = A + (size_t)row0 * K;
    const unsigned short* Bg = Wt + (size_t)col0 * K;

    for (int kt = 0; kt < K; kt += 32) {
#pragma unroll
        for (int l = 0; l < 2; ++l) {
            int r = l * 64 + lr;
            __builtin_amdgcn_global_load_lds(
                (const __attribute__((address_space(1))) void*)(Ag + (size_t)r * K + kt + c8),
                (__attribute__((address_space(3))) void*)(As + l * 2048 + tid * 8),
                16, 0, 0);
            __builtin_amdgcn_global_load_lds(
                (const __attribute__((address_space(1))) void*)(Bg + (size_t)r * K + kt + c8),
                (__attribute__((address_space(3))) void*)(Bs + l * 2048 + tid * 8),
                16, 0, 0);
        }
        __syncthreads();
        short8 af[4], bf[4];
        int q8 = (lane >> 4) * 8;
#pragma unroll
        for (int i = 0; i < 4; ++i) {
            int m = wr * 64 + i * 16 + (lane & 15);
            af[i] = *(const short8*)&As[m * 32 + q8];
            int n = wc * 64 + i * 16 + (lane & 15);
            bf[i] = *(const short8*)&Bs[n * 32 + q8];
        }
#pragma unroll
        for (int i = 0; i < 4; ++i)
#pragma unroll
            for (int j = 0; j < 4; ++j)
                acc[i][j] = __builtin_amdgcn_mfma_f32_16x16x32_bf16(af[i], bf[j], acc[i][j], 0, 0, 0);
        __syncthreads();
    }
    int q = lane >> 4;
    int cn = lane & 15;
#pragma unroll
    for (int j = 0; j < 4; ++j) {
        int col = col0 + wc * 64 + j * 16 + cn;
        float bv = bias[col];
#pragma unroll
        for (int i = 0; i < 4; ++i) {
            int rowb = row0 + wr * 64 + i * 16 + q * 4;
#pragma unroll
            for (int r = 0; r < 4; ++r) {
                float vv = fmaxf(acc[i][j][r] + bv, 0.f);
                C[(size_t)(rowb + r) * N + col] = f2bf(vv);
            }
        }
    }
}

// ---------------- final linear [NT,512]bf16 @ [512,2]fp32 + b ----------------
__global__ void lin_kernel(const unsigned short* __restrict__ A, const float* __restrict__ w,
                           const float* __restrict__ b, float* __restrict__ o, int M) {
    int wave = threadIdx.x >> 6;
    int lane = threadIdx.x & 63;
    int row = blockIdx.x * 4 + wave;
    if (row >= M) return;
    const uint4* Ar = (const uint4*)(A + (size_t)row * 512);
    uint4 u = Ar[lane];
    float f[8];
    f[0] = bflo(u.x); f[1] = bfhi(u.x); f[2] = bflo(u.y); f[3] = bfhi(u.y);
    f[4] = bflo(u.z); f[5] = bfhi(u.z); f[6] = bflo(u.w); f[7] = bfhi(u.w);
    float s0 = 0.f, s1 = 0.f;
#pragma unroll
    for (int j = 0; j < 8; ++j) {
        int base = (lane * 8 + j) * 2;
        s0 = fmaf(f[j], w[base + 0], s0);
        s1 = fmaf(f[j], w[base + 1], s1);
    }
#pragma unroll
    for (int off = 32; off > 0; off >>= 1) {
        s0 += __shfl_down(s0, off, 64);
        s1 += __shfl_down(s1, off, 64);
    }
    if (lane == 0) { o[row * 2] = s0 + b[0]; o[row * 2 + 1] = s1 + b[1]; }
}

// ---------------- pairwise distance ----------------
__global__ void dist_kernel(const float* __restrict__ o, float* __restrict__ dist) {
    int i = blockIdx.x * blockDim.x + threadIdx.x;
    if (i < N1) {
        float2 a = ((const float2*)o)[i];
        float2 b = ((const float2*)o)[N1 + i];
        float d0 = a.x - b.x + 1e-6f, d1 = a.y - b.y + 1e-6f;
        dist[i] = sqrtf(d0 * d0 + d1 * d1);
    }
}

// ---------------- radix-select top-k ----------------
__global__ void histd_kernel(const float* __restrict__ dist, int* __restrict__ hist) {
    int i = blockIdx.x * blockDim.x + threadIdx.x;
    if (i < N1) {
        unsigned u = __float_as_uint(dist[i]);
        atomicAdd(&hist[u >> 19], 1);
    }
}

__global__ void selk_kernel(const int* __restrict__ hist, int* __restrict__ selout) {
    __shared__ int tile[256];
    int t = threadIdx.x;
    int running = 0;
    for (int tb = 0; tb < 16; ++tb) {
        int idx = 4095 - (tb * 256 + t);
        int v = hist[idx];
        tile[t] = v;
        __syncthreads();
        for (int off = 1; off < 256; off <<= 1) {
            int x = (t >= off) ? tile[t - off] : 0;
            __syncthreads();
            tile[t] += x;
            __syncthreads();
        }
        int incl = running + tile[t];
        if (incl >= TOPK && incl - v < TOPK) selout[0] = idx;
        running += tile[255];
        __syncthreads();
        if (running >= TOPK) break;
    }
}

__global__ void compact_kernel(const float* __restrict__ dist, const int* __restrict__ selout,
                               int* __restrict__ nc, float* __restrict__ cd, int* __restrict__ ci) {
    int i = blockIdx.x * blockDim.x + threadIdx.x;
    if (i >= N1) return;
    float d = dist[i];
    int b = (int)(__float_as_uint(d) >> 19);
    if (b >= selout[0]) {
        int p = atomicAdd(nc, 1);
        cd[p] = d;
        ci[p] = i;
    }
}

#define CCH 2048
__global__ void rankc_kernel(const float* __restrict__ cd, const int* __restrict__ ci,
                             const int* __restrict__ nc_p, float* __restrict__ vals) {
    __shared__ float ds[CCH];
    __shared__ int   di_[CCH];
    int nc = *nc_p;
    int t = threadIdx.x;
    int q = blockIdx.x * 256 + t;
    float dq = 0.f; int iq = 0;
    if (q < nc) { dq = cd[q]; iq = ci[q]; }
    int cnt = 0;
    for (int c0 = 0; c0 < nc; c0 += CCH) {
        int lim = min(CCH, nc - c0);
        for (int j = t; j < lim; j += 256) { ds[j] = cd[c0 + j]; di_[j] = ci[c0 + j]; }
        __syncthreads();
        if (q < nc) {
            for (int j = 0; j < lim; ++j) {
                float dj = ds[j];
                cnt += (dj > dq) || (dj == dq && di_[j] < iq);
            }
        }
        __syncthreads();
    }
    if (q < nc && cnt < TOPK) vals[cnt] = dq;
}

// ---------------- head MLP ----------------
__launch_bounds__(512)
__global__ void head_kernel(const float* __restrict__ vals,
                            const float* __restrict__ fc1_w, const float* __restrict__ fc1_b,
                            const float* __restrict__ ln1_g, const float* __restrict__ ln1_b,
                            const float* __restrict__ fc2_w, const float* __restrict__ fc2_b,
                            const float* __restrict__ ln2_g, const float* __restrict__ ln2_b,
                            const float* __restrict__ fc3_w, const float* __restrict__ fc3_b,
                            float* __restrict__ out) {
    __shared__ float sv[TOPK];
    __shared__ float a1[128];
    __shared__ float red[512];
    __shared__ float s_m, s_r;
    int t = threadIdx.x;
    for (int i = t; i < TOPK; i += 512) sv[i] = vals[i];
    __syncthreads();
    float h1 = 0.f;
    if (t < 128) {
        h1 = fc1_b[t];
        for (int j = 0; j < TOPK; ++j) h1 = fmaf(sv[j], fc1_w[j * 128 + t], h1);
    }
    red[t] = (t < 128) ? h1 : 0.f; __syncthreads();
    for (int s = 256; s > 0; s >>= 1) { if (t < s) red[t] += red[t + s]; __syncthreads(); }
    if (t == 0) s_m = red[0] / 128.f;
    __syncthreads();
    float m1 = s_m;
    float dv = (t < 128) ? (h1 - m1) : 0.f;
    red[t] = dv * dv; __syncthreads();
    for (int s = 256; s > 0; s >>= 1) { if (t < s) red[t] += red[t + s]; __syncthreads(); }
    if (t == 0) s_r = rsqrtf(red[0] / 128.f + 1e-5f);
    __syncthreads();
    float r1 = s_r;
    if (t < 128) a1[t] = fmaxf((h1 - m1) * r1 * ln1_g[t] + ln1_b[t], 0.f);
    __syncthreads();
    float h2 = fc2_b[t];
    for (int j = 0; j < 128; ++j) h2 = fmaf(a1[j], fc2_w[j * 512 + t], h2);
    red[t] = h2; __syncthreads();
    for (int s = 256; s > 0; s >>= 1) { if (t < s) red[t] += red[t + s]; __syncthreads(); }
    if (t == 0) s_m = red[0] / 512.f;
    __syncthreads();
    float m2 = s_m;
    float d2 = h2 - m2;
    red[t] = d2 * d2; __syncthreads();
    for (int s = 256; s > 0; s >>= 1) { if (t < s) red[t] += red[t + s]; __syncthreads(); }
    if (t == 0) s_r = rsqrtf(red[0] / 512.f + 1e-5f);
    __syncthreads();
    float r2 = s_r;
    float y2 = fmaxf((h2 - m2) * r2 * ln2_g[t] + ln2_b[t], 0.f);
    red[t] = y2 * fc3_w[t]; __syncthreads();
    for (int s = 256; s > 0; s >>= 1) { if (t < s) red[t] += red[t + s]; __syncthreads(); }
    if (t == 0) out[0] = 1.f / (1.f + expf(-(red[0] + fc3_b[0])));
}

extern "C" void kernel_launch(void* const* d_in, const int* in_sizes, int n_in,
                              void* d_out, int out_size, void* d_ws, size_t ws_size,
                              hipStream_t stream) {
    const float* x1   = (const float*)d_in[0];
    const int*   ei1  = (const int*)d_in[1];
    const float* x2   = (const float*)d_in[2];
    const int*   ei2  = (const int*)d_in[3];
    const float* w11  = (const float*)d_in[4];
    const float* b11  = (const float*)d_in[5];
    const float* w12  = (const float*)d_in[6];
    const float* b12  = (const float*)d_in[7];
    const float* w21  = (const float*)d_in[8];
    const float* b21  = (const float*)d_in[9];
    const float* w22  = (const float*)d_in[10];
    const float* b22  = (const float*)d_in[11];
    const float* w31  = (const float*)d_in[12];
    const float* b31  = (const float*)d_in[13];
    const float* w32  = (const float*)d_in[14];
    const float* b32  = (const float*)d_in[15];
    const float* lw   = (const float*)d_in[16];
    const float* lb   = (const float*)d_in[17];
    const float* fc1w = (const float*)d_in[18];
    const float* fc1b = (const float*)d_in[19];
    const float* ln1g = (const float*)d_in[20];
    const float* ln1b = (const float*)d_in[21];
    const float* fc2w = (const float*)d_in[22];
    const float* fc2b = (const float*)d_in[23];
    const float* ln2g = (const float*)d_in[24];
    const float* ln2b = (const float*)d_in[25];
    const float* fc3w = (const float*)d_in[26];
    const float* fc3b = (const float*)d_in[27];

    char* ws = (char*)d_ws;
    size_t off = 0;
    auto alloc = [&](size_t bytes) -> void* {
        void* p = ws + off;
        off += (bytes + 255) & ~(size_t)255;
        return p;
    };
    unsigned short* H0  = (unsigned short*)alloc((size_t)MP * HID_D * 2);
    unsigned short* H1  = (unsigned short*)alloc((size_t)MP * HID_D * 2);
    unsigned short* XB  = H1;   // alias: XB dead before gemm1 writes H1
    unsigned short* wt11 = (unsigned short*)alloc((size_t)HID_D * FIN_D * 2);
    unsigned short* wt12 = (unsigned short*)alloc((size_t)HID_D * HID_D * 2);
    unsigned short* wt21 = (unsigned short*)alloc((size_t)HID_D * HID_D * 2);
    unsigned short* wt22 = (unsigned short*)alloc((size_t)HID_D * HID_D * 2);
    unsigned short* wt31 = (unsigned short*)alloc((size_t)HID_D * HID_D * 2);
    unsigned short* wt32 = (unsigned short*)alloc((size_t)HID_D * HID_D * 2);
    float* o         = (float*)alloc((size_t)NT * 2 * 4);
    float* dist      = (float*)alloc((size_t)N1 * 4);
    float* vals      = (float*)alloc((size_t)TOPK * 4);
    int*   row_start = (int*)alloc((size_t)(NT + 1) * 4);
    int*   cursor    = (int*)alloc((size_t)NT * 4);
    int*   deg       = (int*)alloc((size_t)NT * 4);
    int*   scan_tmp  = (int*)alloc((size_t)NT * 4);
    int*   bsum      = (int*)alloc((size_t)SCAN_NB * 4);
    int*   boff      = (int*)alloc((size_t)SCAN_NB * 4);
    int*   csr_src   = (int*)alloc((size_t)ET * 4);
    int*   selblk    = (int*)alloc((size_t)(4096 + 64) * 4);  // hist + nc
    int*   hist      = selblk;
    int*   nc        = selblk + 4096;
    int*   selout    = (int*)alloc(2 * 4);
    float* cd        = (float*)alloc((size_t)N1 * 4);
    int*   ci        = (int*)alloc((size_t)N1 * 4);

    // ---- weight / input conversions ----
    {
        dim3 g11(FIN_D / 32, HID_D / 32);
        dim3 g55(HID_D / 32, HID_D / 32);
        convw_kernel<<<g11, 256, 0, stream>>>(w11, wt11, FIN_D, HID_D);
        convw_kernel<<<g55, 256, 0, stream>>>(w12, wt12, HID_D, HID_D);
        convw_kernel<<<g55, 256, 0, stream>>>(w21, wt21, HID_D, HID_D);
        convw_kernel<<<g55, 256, 0, stream>>>(w22, wt22, HID_D, HID_D);
        convw_kernel<<<g55, 256, 0, stream>>>(w31, wt31, HID_D, HID_D);
        convw_kernel<<<g55, 256, 0, stream>>>(w32, wt32, HID_D, HID_D);
        int n4 = N1 * FIN_D / 4;
        convx_kernel<<<(n4 + 255) / 256, 256, 0, stream>>>(x1, XB, n4);
        convx_kernel<<<(n4 + 255) / 256, 256, 0, stream>>>(x2, XB + (size_t)N1 * FIN_D, n4);
    }

    // ---- CSR build (both graphs, global node ids) ----
    hipMemsetAsync(deg, 0, NT * sizeof(int), stream);
    hist_kernel<<<(ET + 255) / 256, 256, 0, stream>>>(ei1, ei2, deg);
    scan1_kernel<<<SCAN_NB, 256, 0, stream>>>(deg, scan_tmp, bsum);
    scan2_kernel<<<1, 256, 0, stream>>>(bsum, boff, row_start);
    scan3_kernel<<<SCAN_NB, 256, 0, stream>>>(scan_tmp, boff, row_start, cursor);
    fill_kernel<<<(ET + 255) / 256, 256, 0, stream>>>(ei1, ei2, cursor, csr_src);

    // ---- GNN pipeline (both graphs batched) ----
    dim3 gemm_grid(MP / 128, HID_D / 128);
    const int GRPS = NT / 64;   // 625
    // layer 1 (D=256 input): 8 slabs
    agg_slab_kernel<32, 8><<<8 * GRPS, 256, 0, stream>>>(XB, row_start, csr_src, H0);
    gemm_mfma<<<gemm_grid, 256, 0, stream>>>(H0, wt11, b11, H1, FIN_D, HID_D);   // overwrites XB (dead)
    gemm_mfma<<<gemm_grid, 256, 0, stream>>>(H1, wt12, b12, H0, HID_D, HID_D);
    // layer 2 (D=512): 16 slabs, 2 phases
    agg_slab_kernel<64, 16><<<16 * GRPS, 256, 0, stream>>>(H0, row_start, csr_src, H1);
    gemm_mfma<<<gemm_grid, 256, 0, stream>>>(H1, wt21, b21, H0, HID_D, HID_D);
    gemm_mfma<<<gemm_grid, 256, 0, stream>>>(H0, wt22, b22, H1, HID_D, HID_D);
    // layer 3
    agg_slab_kernel<64, 16><<<16 * GRPS, 256, 0, stream>>>(H1, row_start, csr_src, H0);
    gemm_mfma<<<gemm_grid, 256, 0, stream>>>(H0, wt31, b31, H1, HID_D, HID_D);
    gemm_mfma<<<gemm_grid, 256, 0, stream>>>(H1, wt32, b32, H0, HID_D, HID_D);
    // final linear [NT,512] -> [NT,2]
    lin_kernel<<<(NT + 3) / 4, 256, 0, stream>>>(H0, lw, lb, o, NT);

    // ---- distance + radix-select top-k ----
    dist_kernel<<<(N1 + 255) / 256, 256, 0, stream>>>(o, dist);
    hipMemsetAsync(selblk, 0, (4096 + 64) * sizeof(int), stream);
    histd_kernel<<<(N1 + 255) / 256, 256, 0, stream>>>(dist, hist);
    selk_kernel<<<1, 256, 0, stream>>>(hist, selout);
    compact_kernel<<<(N1 + 255) / 256, 256, 0, stream>>>(dist, selout, nc, cd, ci);
    rankc_kernel<<<(N1 + 255) / 256, 256, 0, stream>>>(cd, ci, nc, vals);

    // ---- head MLP ----
    head_kernel<<<1, 512, 0, stream>>>(vals, fc1w, fc1b, ln1g, ln1b,
                                       fc2w, fc2b, ln2g, ln2b, fc3w, fc3b,
                                       (float*)d_out);
}

// Round 8
// 1028.732 us; speedup vs baseline: 1.2462x; 1.2462x over previous
//
#include <hip/hip_runtime.h>
#include <hip/hip_bf16.h>
#include <math.h>

#define N1      20000          // nodes per graph
#define NT      40000          // both graphs
#define E1      640000         // edges per graph
#define ET      1280000
#define FIN_D   256
#define HID_D   512
#define TOPK    1000
#define MP1     20096          // 157 * 128 (padded M per graph)
#define GRPS1   313            // ceil(20000/64)
#define SCAN_NB 157            // ceil(40000/256)

typedef __attribute__((ext_vector_type(8))) short short8;
typedef __attribute__((ext_vector_type(4))) float floatx4;
typedef unsigned int uintx4 __attribute__((ext_vector_type(4)));

__device__ __forceinline__ unsigned short f2bf(float f) {
    union { __hip_bfloat16 h; unsigned short u; } cv;
    cv.h = __float2bfloat16(f);
    return cv.u;
}
__device__ __forceinline__ float bflo(unsigned int u) {
    union { unsigned int i; float f; } c; c.i = u << 16; return c.f;
}
__device__ __forceinline__ float bfhi(unsigned int u) {
    union { unsigned int i; float f; } c; c.i = u & 0xffff0000u; return c.f;
}

// ---------------- CSR build (both graphs in one node space) ----------------
__global__ void hist_kernel(const int* __restrict__ ei1, const int* __restrict__ ei2,
                            int* __restrict__ deg) {
    int e = blockIdx.x * blockDim.x + threadIdx.x;
    if (e >= ET) return;
    int d = (e < E1) ? ei1[E1 + e] : (ei2[E1 + (e - E1)] + N1);
    atomicAdd(&deg[d], 1);
}

__global__ void scan1_kernel(const int* __restrict__ deg, int* __restrict__ tmp,
                             int* __restrict__ bsum) {
    __shared__ int tile[256];
    int t = threadIdx.x;
    int i = blockIdx.x * 256 + t;
    int v = (i < NT) ? deg[i] : 0;
    tile[t] = v;
    __syncthreads();
    for (int off = 1; off < 256; off <<= 1) {
        int x = (t >= off) ? tile[t - off] : 0;
        __syncthreads();
        tile[t] += x;
        __syncthreads();
    }
    if (i < NT) tmp[i] = tile[t] - v;
    if (t == 255) bsum[blockIdx.x] = tile[255];
}

__global__ void scan2_kernel(const int* __restrict__ bsum, int* __restrict__ boff,
                             int* __restrict__ row_start) {
    __shared__ int tile[256];
    int t = threadIdx.x;
    int v = (t < SCAN_NB) ? bsum[t] : 0;
    tile[t] = v;
    __syncthreads();
    for (int off = 1; off < 256; off <<= 1) {
        int x = (t >= off) ? tile[t - off] : 0;
        __syncthreads();
        tile[t] += x;
        __syncthreads();
    }
    if (t < SCAN_NB) boff[t] = tile[t] - v;
    if (t == 255) row_start[NT] = tile[255];
}

__global__ void scan3_kernel(const int* __restrict__ tmp, const int* __restrict__ boff,
                             int* __restrict__ row_start, int* __restrict__ cursor) {
    int i = blockIdx.x * 256 + threadIdx.x;
    if (i < NT) {
        int rs = tmp[i] + boff[blockIdx.x];
        row_start[i] = rs;
        cursor[i] = rs;
    }
}

__global__ void fill_kernel(const int* __restrict__ ei1, const int* __restrict__ ei2,
                            int* __restrict__ cursor, int* __restrict__ csr_src) {
    int e = blockIdx.x * blockDim.x + threadIdx.x;
    if (e >= ET) return;
    int s, d;
    if (e < E1) { s = ei1[e]; d = ei1[E1 + e]; }
    else        { int e2 = e - E1; s = ei2[e2] + N1; d = ei2[E1 + e2] + N1; }
    int p = atomicAdd(&cursor[d], 1);
    csr_src[p] = s;
}

// ---------------- conversions ----------------
__global__ void convx_kernel(const float* __restrict__ x, unsigned short* __restrict__ xb, int n4) {
    int i = blockIdx.x * 256 + threadIdx.x;
    if (i < n4) {
        float4 f = ((const float4*)x)[i];
        ushort4 u;
        u.x = f2bf(f.x); u.y = f2bf(f.y); u.z = f2bf(f.z); u.w = f2bf(f.w);
        ((ushort4*)xb)[i] = u;
    }
}

// W[K][N] fp32 -> Wt[N][K] bf16 (tiled transpose)
__global__ void convw_kernel(const float* __restrict__ W, unsigned short* __restrict__ Wt,
                             int K, int N) {
    __shared__ float tile[32][33];
    int k0 = blockIdx.x * 32, n0 = blockIdx.y * 32;
    int tx = threadIdx.x & 31, ty = threadIdx.x >> 5;
    for (int r = ty; r < 32; r += 8) tile[r][tx] = W[(size_t)(k0 + r) * N + n0 + tx];
    __syncthreads();
    for (int r = ty; r < 32; r += 8)
        Wt[(size_t)(n0 + r) * K + k0 + tx] = f2bf(tile[tx][r]);
}

// ---------------- GIN aggregation body (per graph) -----------------------------
// r5 structure: 32-col slab per XCD, 8-deep independent gathers, fp32 accum.
// x: per-graph local base; csr ids are GLOBAL -> local via (j - n0).
#define ACC8(u) do { \
    acc[0] += bflo((u).x); acc[1] += bfhi((u).x); \
    acc[2] += bflo((u).y); acc[3] += bfhi((u).y); \
    acc[4] += bflo((u).z); acc[5] += bfhi((u).z); \
    acc[6] += bflo((u).w); acc[7] += bfhi((u).w); } while (0)

template<int LPR, int NSLAB>   // LPR = uintx4 per row (D/8); NSLAB = LPR/4
__device__ __forceinline__ void agg_body(int ab, int tid,
                                         const unsigned short* __restrict__ x,
                                         const int* __restrict__ row_start,
                                         const int* __restrict__ csr_src,
                                         unsigned short* __restrict__ h, int n0) {
    int phase = ab / (8 * GRPS1);
    int rem = ab % (8 * GRPS1);
    int slab = phase * 8 + (rem & 7);          // XCD round-robin
    int grp = rem >> 3;
    int lid = grp * 64 + (tid >> 2);
    bool act = lid < N1;
    int lidc = act ? lid : (N1 - 1);
    int nid = n0 + lidc;
    int c = tid & 3;
    int chunk = slab * 4 + c;
    const uintx4* Xc = (const uintx4*)x + chunk;
    uintx4 v = Xc[(size_t)lidc * LPR];
    float acc[8];
    acc[0] = bflo(v.x); acc[1] = bfhi(v.x);
    acc[2] = bflo(v.y); acc[3] = bfhi(v.y);
    acc[4] = bflo(v.z); acc[5] = bfhi(v.z);
    acc[6] = bflo(v.w); acc[7] = bfhi(v.w);
    int s = row_start[nid], e = row_start[nid + 1];
    if (!act) e = s;
    int p = s;
    for (; p + 8 <= e; p += 8) {
        int n0_ = csr_src[p + 0] - n0, n1_ = csr_src[p + 1] - n0;
        int n2_ = csr_src[p + 2] - n0, n3_ = csr_src[p + 3] - n0;
        int n4_ = csr_src[p + 4] - n0, n5_ = csr_src[p + 5] - n0;
        int n6_ = csr_src[p + 6] - n0, n7_ = csr_src[p + 7] - n0;
        uintx4 u0 = Xc[(size_t)n0_ * LPR];
        uintx4 u1 = Xc[(size_t)n1_ * LPR];
        uintx4 u2 = Xc[(size_t)n2_ * LPR];
        uintx4 u3 = Xc[(size_t)n3_ * LPR];
        uintx4 u4 = Xc[(size_t)n4_ * LPR];
        uintx4 u5 = Xc[(size_t)n5_ * LPR];
        uintx4 u6 = Xc[(size_t)n6_ * LPR];
        uintx4 u7 = Xc[(size_t)n7_ * LPR];
        ACC8(u0); ACC8(u1); ACC8(u2); ACC8(u3);
        ACC8(u4); ACC8(u5); ACC8(u6); ACC8(u7);
    }
    for (; p + 2 <= e; p += 2) {
        int na = csr_src[p + 0] - n0, nb = csr_src[p + 1] - n0;
        uintx4 u0 = Xc[(size_t)na * LPR];
        uintx4 u1 = Xc[(size_t)nb * LPR];
        ACC8(u0); ACC8(u1);
    }
    if (p < e) {
        int na = csr_src[p] - n0;
        uintx4 u0 = Xc[(size_t)na * LPR];
        ACC8(u0);
    }
    if (act) {
        uintx4 o;
        o.x = (unsigned)f2bf(acc[0]) | ((unsigned)f2bf(acc[1]) << 16);
        o.y = (unsigned)f2bf(acc[2]) | ((unsigned)f2bf(acc[3]) << 16);
        o.z = (unsigned)f2bf(acc[4]) | ((unsigned)f2bf(acc[5]) << 16);
        o.w = (unsigned)f2bf(acc[6]) | ((unsigned)f2bf(acc[7]) << 16);
        ((uintx4*)h)[(size_t)lidc * LPR + chunk] = o;
    }
}

template<int LPR, int NSLAB>
__launch_bounds__(256, 8)
__global__ void agg_pg(const unsigned short* __restrict__ x,
                       const int* __restrict__ row_start,
                       const int* __restrict__ csr_src,
                       unsigned short* __restrict__ h, int n0) {
    agg_body<LPR, NSLAB>(blockIdx.x, threadIdx.x, x, row_start, csr_src, h, n0);
}

// ---------------- bf16 MFMA GEMM body: C = relu(A[MP1,K] @ W[K,512] + bias) -----
__device__ __forceinline__ void gemm_body(int bx, int by, int tid,
                                          unsigned short* smem,
                                          const unsigned short* __restrict__ A,
                                          const unsigned short* __restrict__ Wt,
                                          const float* __restrict__ bias,
                                          unsigned short* __restrict__ C, int K) {
    const int N = HID_D;
    unsigned short* As = smem;            // 128*32
    unsigned short* Bs = smem + 4096;     // 128*32
    int lane = tid & 63;
    int w = tid >> 6;
    int wr = w >> 1, wc = w & 1;
    int row0 = bx * 128;
    int col0 = by * 128;
    floatx4 acc[4][4] = {};
    int lr = tid >> 2;
    int c8 = (tid & 3) * 8;
    const unsigned short* Ag = A + (size_t)row0 * K;
    const unsigned short* Bg = Wt + (size_t)col0 * K;

    for (int kt = 0; kt < K; kt += 32) {
#pragma unroll
        for (int l = 0; l < 2; ++l) {
            int r = l * 64 + lr;
            __builtin_amdgcn_global_load_lds(
                (const __attribute__((address_space(1))) void*)(Ag + (size_t)r * K + kt + c8),
                (__attribute__((address_space(3))) void*)(As + l * 2048 + tid * 8),
                16, 0, 0);
            __builtin_amdgcn_global_load_lds(
                (const __attribute__((address_space(1))) void*)(Bg + (size_t)r * K + kt + c8),
                (__attribute__((address_space(3))) void*)(Bs + l * 2048 + tid * 8),
                16, 0, 0);
        }
        __syncthreads();
        short8 af[4], bf[4];
        int q8 = (lane >> 4) * 8;
#pragma unroll
        for (int i = 0; i < 4; ++i) {
            int m = wr * 64 + i * 16 + (lane & 15);
            af[i] = *(const short8*)&As[m * 32 + q8];
            int n = wc * 64 + i * 16 + (lane & 15);
            bf[i] = *(const short8*)&Bs[n * 32 + q8];
        }
#pragma unroll
        for (int i = 0; i < 4; ++i)
#pragma unroll
            for (int j = 0; j < 4; ++j)
                acc[i][j] = __builtin_amdgcn_mfma_f32_16x16x32_bf16(af[i], bf[j], acc[i][j], 0, 0, 0);
        __syncthreads();
    }
    int q = lane >> 4;
    int cn = lane & 15;
#pragma unroll
    for (int j = 0; j < 4; ++j) {
        int col = col0 + wc * 64 + j * 16 + cn;
        float bv = bias[col];
#pragma unroll
        for (int i = 0; i < 4; ++i) {
            int rowb = row0 + wr * 64 + i * 16 + q * 4;
#pragma unroll
            for (int r = 0; r < 4; ++r) {
                float vv = fmaxf(acc[i][j][r] + bv, 0.f);
                C[(size_t)(rowb + r) * N + col] = f2bf(vv);
            }
        }
    }
}

__launch_bounds__(256)
__global__ void gemm_mfma(const unsigned short* __restrict__ A,
                          const unsigned short* __restrict__ Wt,
                          const float* __restrict__ bias,
                          unsigned short* __restrict__ C, int K) {
    __shared__ unsigned short smem[8192];
    gemm_body(blockIdx.x, blockIdx.y, threadIdx.x, smem, A, Wt, bias, C, K);
}

// ---------------- fused: gemm(graph A) blocks first, agg(graph B) blocks after --
template<int LPR, int NSLAB>
__launch_bounds__(256)
__global__ void fused_k(const unsigned short* __restrict__ A,
                        const unsigned short* __restrict__ Wt,
                        const float* __restrict__ bias,
                        unsigned short* __restrict__ C, int K,
                        const unsigned short* __restrict__ x,
                        const int* __restrict__ row_start,
                        const int* __restrict__ csr_src,
                        unsigned short* __restrict__ h, int n0, int nGemm) {
    __shared__ unsigned short smem[8192];
    int b = blockIdx.x;
    if (b < nGemm) {
        gemm_body(b % 157, b / 157, threadIdx.x, smem, A, Wt, bias, C, K);
    } else {
        agg_body<LPR, NSLAB>(b - nGemm, threadIdx.x, x, row_start, csr_src, h, n0);
    }
}

// ---------------- final linear [M,512]bf16 @ [512,2]fp32 + b ----------------
__global__ void lin_kernel(const unsigned short* __restrict__ A, const float* __restrict__ w,
                           const float* __restrict__ b, float* __restrict__ o, int M) {
    int wave = threadIdx.x >> 6;
    int lane = threadIdx.x & 63;
    int row = blockIdx.x * 4 + wave;
    if (row >= M) return;
    const uint4* Ar = (const uint4*)(A + (size_t)row * 512);
    uint4 u = Ar[lane];
    float f[8];
    f[0] = bflo(u.x); f[1] = bfhi(u.x); f[2] = bflo(u.y); f[3] = bfhi(u.y);
    f[4] = bflo(u.z); f[5] = bfhi(u.z); f[6] = bflo(u.w); f[7] = bfhi(u.w);
    float s0 = 0.f, s1 = 0.f;
#pragma unroll
    for (int j = 0; j < 8; ++j) {
        int base = (lane * 8 + j) * 2;
        s0 = fmaf(f[j], w[base + 0], s0);
        s1 = fmaf(f[j], w[base + 1], s1);
    }
#pragma unroll
    for (int off = 32; off > 0; off >>= 1) {
        s0 += __shfl_down(s0, off, 64);
        s1 += __shfl_down(s1, off, 64);
    }
    if (lane == 0) { o[row * 2] = s0 + b[0]; o[row * 2 + 1] = s1 + b[1]; }
}

// ---------------- pairwise distance ----------------
__global__ void dist_kernel(const float* __restrict__ o, float* __restrict__ dist) {
    int i = blockIdx.x * blockDim.x + threadIdx.x;
    if (i < N1) {
        float2 a = ((const float2*)o)[i];
        float2 b = ((const float2*)o)[N1 + i];
        float d0 = a.x - b.x + 1e-6f, d1 = a.y - b.y + 1e-6f;
        dist[i] = sqrtf(d0 * d0 + d1 * d1);
    }
}

// ---------------- radix-select top-k ----------------
__global__ void histd_kernel(const float* __restrict__ dist, int* __restrict__ hist) {
    int i = blockIdx.x * blockDim.x + threadIdx.x;
    if (i < N1) {
        unsigned u = __float_as_uint(dist[i]);
        atomicAdd(&hist[u >> 19], 1);
    }
}

__global__ void selk_kernel(const int* __restrict__ hist, int* __restrict__ selout) {
    __shared__ int tile[256];
    int t = threadIdx.x;
    int running = 0;
    for (int tb = 0; tb < 16; ++tb) {
        int idx = 4095 - (tb * 256 + t);
        int v = hist[idx];
        tile[t] = v;
        __syncthreads();
        for (int off = 1; off < 256; off <<= 1) {
            int x = (t >= off) ? tile[t - off] : 0;
            __syncthreads();
            tile[t] += x;
            __syncthreads();
        }
        int incl = running + tile[t];
        if (incl >= TOPK && incl - v < TOPK) selout[0] = idx;
        running += tile[255];
        __syncthreads();
        if (running >= TOPK) break;
    }
}

__global__ void compact_kernel(const float* __restrict__ dist, const int* __restrict__ selout,
                               int* __restrict__ nc, float* __restrict__ cd, int* __restrict__ ci) {
    int i = blockIdx.x * blockDim.x + threadIdx.x;
    if (i >= N1) return;
    float d = dist[i];
    int b = (int)(__float_as_uint(d) >> 19);
    if (b >= selout[0]) {
        int p = atomicAdd(nc, 1);
        cd[p] = d;
        ci[p] = i;
    }
}

#define CCH 2048
__global__ void rankc_kernel(const float* __restrict__ cd, const int* __restrict__ ci,
                             const int* __restrict__ nc_p, float* __restrict__ vals) {
    __shared__ float ds[CCH];
    __shared__ int   di_[CCH];
    int nc = *nc_p;
    int t = threadIdx.x;
    int q = blockIdx.x * 256 + t;
    float dq = 0.f; int iq = 0;
    if (q < nc) { dq = cd[q]; iq = ci[q]; }
    int cnt = 0;
    for (int c0 = 0; c0 < nc; c0 += CCH) {
        int lim = min(CCH, nc - c0);
        for (int j = t; j < lim; j += 256) { ds[j] = cd[c0 + j]; di_[j] = ci[c0 + j]; }
        __syncthreads();
        if (q < nc) {
            for (int j = 0; j < lim; ++j) {
                float dj = ds[j];
                cnt += (dj > dq) || (dj == dq && di_[j] < iq);
            }
        }
        __syncthreads();
    }
    if (q < nc && cnt < TOPK) vals[cnt] = dq;
}

// ---------------- head MLP ----------------
__launch_bounds__(512)
__global__ void head_kernel(const float* __restrict__ vals,
                            const float* __restrict__ fc1_w, const float* __restrict__ fc1_b,
                            const float* __restrict__ ln1_g, const float* __restrict__ ln1_b,
                            const float* __restrict__ fc2_w, const float* __restrict__ fc2_b,
                            const float* __restrict__ ln2_g, const float* __restrict__ ln2_b,
                            const float* __restrict__ fc3_w, const float* __restrict__ fc3_b,
                            float* __restrict__ out) {
    __shared__ float sv[TOPK];
    __shared__ float a1[128];
    __shared__ float red[512];
    __shared__ float s_m, s_r;
    int t = threadIdx.x;
    for (int i = t; i < TOPK; i += 512) sv[i] = vals[i];
    __syncthreads();
    float h1 = 0.f;
    if (t < 128) {
        h1 = fc1_b[t];
        for (int j = 0; j < TOPK; ++j) h1 = fmaf(sv[j], fc1_w[j * 128 + t], h1);
    }
    red[t] = (t < 128) ? h1 : 0.f; __syncthreads();
    for (int s = 256; s > 0; s >>= 1) { if (t < s) red[t] += red[t + s]; __syncthreads(); }
    if (t == 0) s_m = red[0] / 128.f;
    __syncthreads();
    float m1 = s_m;
    float dv = (t < 128) ? (h1 - m1) : 0.f;
    red[t] = dv * dv; __syncthreads();
    for (int s = 256; s > 0; s >>= 1) { if (t < s) red[t] += red[t + s]; __syncthreads(); }
    if (t == 0) s_r = rsqrtf(red[0] / 128.f + 1e-5f);
    __syncthreads();
    float r1 = s_r;
    if (t < 128) a1[t] = fmaxf((h1 - m1) * r1 * ln1_g[t] + ln1_b[t], 0.f);
    __syncthreads();
    float h2 = fc2_b[t];
    for (int j = 0; j < 128; ++j) h2 = fmaf(a1[j], fc2_w[j * 512 + t], h2);
    red[t] = h2; __syncthreads();
    for (int s = 256; s > 0; s >>= 1) { if (t < s) red[t] += red[t + s]; __syncthreads(); }
    if (t == 0) s_m = red[0] / 512.f;
    __syncthreads();
    float m2 = s_m;
    float d2 = h2 - m2;
    red[t] = d2 * d2; __syncthreads();
    for (int s = 256; s > 0; s >>= 1) { if (t < s) red[t] += red[t + s]; __syncthreads(); }
    if (t == 0) s_r = rsqrtf(red[0] / 512.f + 1e-5f);
    __syncthreads();
    float r2 = s_r;
    float y2 = fmaxf((h2 - m2) * r2 * ln2_g[t] + ln2_b[t], 0.f);
    red[t] = y2 * fc3_w[t]; __syncthreads();
    for (int s = 256; s > 0; s >>= 1) { if (t < s) red[t] += red[t + s]; __syncthreads(); }
    if (t == 0) out[0] = 1.f / (1.f + expf(-(red[0] + fc3_b[0])));
}

extern "C" void kernel_launch(void* const* d_in, const int* in_sizes, int n_in,
                              void* d_out, int out_size, void* d_ws, size_t ws_size,
                              hipStream_t stream) {
    const float* x1   = (const float*)d_in[0];
    const int*   ei1  = (const int*)d_in[1];
    const float* x2   = (const float*)d_in[2];
    const int*   ei2  = (const int*)d_in[3];
    const float* w11  = (const float*)d_in[4];
    const float* b11  = (const float*)d_in[5];
    const float* w12  = (const float*)d_in[6];
    const float* b12  = (const float*)d_in[7];
    const float* w21  = (const float*)d_in[8];
    const float* b21  = (const float*)d_in[9];
    const float* w22  = (const float*)d_in[10];
    const float* b22  = (const float*)d_in[11];
    const float* w31  = (const float*)d_in[12];
    const float* b31  = (const float*)d_in[13];
    const float* w32  = (const float*)d_in[14];
    const float* b32  = (const float*)d_in[15];
    const float* lw   = (const float*)d_in[16];
    const float* lb   = (const float*)d_in[17];
    const float* fc1w = (const float*)d_in[18];
    const float* fc1b = (const float*)d_in[19];
    const float* ln1g = (const float*)d_in[20];
    const float* ln1b = (const float*)d_in[21];
    const float* fc2w = (const float*)d_in[22];
    const float* fc2b = (const float*)d_in[23];
    const float* ln2g = (const float*)d_in[24];
    const float* ln2b = (const float*)d_in[25];
    const float* fc3w = (const float*)d_in[26];
    const float* fc3b = (const float*)d_in[27];

    char* ws = (char*)d_ws;
    size_t off = 0;
    auto alloc = [&](size_t bytes) -> void* {
        void* p = ws + off;
        off += (bytes + 255) & ~(size_t)255;
        return p;
    };
    unsigned short* XB  = (unsigned short*)alloc((size_t)NT * FIN_D * 2);  // batched inputs
    unsigned short* H0a = (unsigned short*)alloc((size_t)MP1 * HID_D * 2);
    unsigned short* H1a = (unsigned short*)alloc((size_t)MP1 * HID_D * 2);
    unsigned short* H0b = (unsigned short*)alloc((size_t)MP1 * HID_D * 2);
    unsigned short* H1b = (unsigned short*)alloc((size_t)MP1 * HID_D * 2);
    unsigned short* wt11 = (unsigned short*)alloc((size_t)HID_D * FIN_D * 2);
    unsigned short* wt12 = (unsigned short*)alloc((size_t)HID_D * HID_D * 2);
    unsigned short* wt21 = (unsigned short*)alloc((size_t)HID_D * HID_D * 2);
    unsigned short* wt22 = (unsigned short*)alloc((size_t)HID_D * HID_D * 2);
    unsigned short* wt31 = (unsigned short*)alloc((size_t)HID_D * HID_D * 2);
    unsigned short* wt32 = (unsigned short*)alloc((size_t)HID_D * HID_D * 2);
    float* o         = (float*)alloc((size_t)NT * 2 * 4);
    float* dist      = (float*)alloc((size_t)N1 * 4);
    float* vals      = (float*)alloc((size_t)TOPK * 4);
    int*   row_start = (int*)alloc((size_t)(NT + 1) * 4);
    int*   cursor    = (int*)alloc((size_t)NT * 4);
    int*   deg       = (int*)alloc((size_t)NT * 4);
    int*   scan_tmp  = (int*)alloc((size_t)NT * 4);
    int*   bsum      = (int*)alloc((size_t)SCAN_NB * 4);
    int*   boff      = (int*)alloc((size_t)SCAN_NB * 4);
    int*   csr_src   = (int*)alloc((size_t)ET * 4);
    int*   selblk    = (int*)alloc((size_t)(4096 + 64) * 4);  // hist + nc
    int*   hist      = selblk;
    int*   nc        = selblk + 4096;
    int*   selout    = (int*)alloc(2 * 4);
    float* cd        = (float*)alloc((size_t)N1 * 4);
    int*   ci        = (int*)alloc((size_t)N1 * 4);

    // ---- weight / input conversions ----
    {
        dim3 g11(FIN_D / 32, HID_D / 32);
        dim3 g55(HID_D / 32, HID_D / 32);
        convw_kernel<<<g11, 256, 0, stream>>>(w11, wt11, FIN_D, HID_D);
        convw_kernel<<<g55, 256, 0, stream>>>(w12, wt12, HID_D, HID_D);
        convw_kernel<<<g55, 256, 0, stream>>>(w21, wt21, HID_D, HID_D);
        convw_kernel<<<g55, 256, 0, stream>>>(w22, wt22, HID_D, HID_D);
        convw_kernel<<<g55, 256, 0, stream>>>(w31, wt31, HID_D, HID_D);
        convw_kernel<<<g55, 256, 0, stream>>>(w32, wt32, HID_D, HID_D);
        int n4 = N1 * FIN_D / 4;
        convx_kernel<<<(n4 + 255) / 256, 256, 0, stream>>>(x1, XB, n4);
        convx_kernel<<<(n4 + 255) / 256, 256, 0, stream>>>(x2, XB + (size_t)N1 * FIN_D, n4);
    }

    // ---- CSR build (both graphs, global node ids) ----
    hipMemsetAsync(deg, 0, NT * sizeof(int), stream);
    hist_kernel<<<(ET + 255) / 256, 256, 0, stream>>>(ei1, ei2, deg);
    scan1_kernel<<<SCAN_NB, 256, 0, stream>>>(deg, scan_tmp, bsum);
    scan2_kernel<<<1, 256, 0, stream>>>(bsum, boff, row_start);
    scan3_kernel<<<SCAN_NB, 256, 0, stream>>>(scan_tmp, boff, row_start, cursor);
    fill_kernel<<<(ET + 255) / 256, 256, 0, stream>>>(ei1, ei2, cursor, csr_src);

    // ---- staggered two-graph pipeline: agg(A) overlapped with gemm(B) ----
    const unsigned short* XBg2 = XB + (size_t)N1 * FIN_D;
    const int NG = 628;                      // 157 x 4 gemm blocks
    dim3 gemm_grid(157, 4);
    int aggB256 = 8 * GRPS1;                 // 2504
    int aggB512 = 16 * GRPS1;                // 5008

    // s1: agg1(g1)
    agg_pg<32, 8><<<aggB256, 256, 0, stream>>>(XB, row_start, csr_src, H0a, 0);
    // s2: G11(g1) || agg1(g2)
    fused_k<32, 8><<<NG + aggB256, 256, 0, stream>>>(H0a, wt11, b11, H1a, FIN_D,
                                                     XBg2, row_start, csr_src, H0b, N1, NG);
    // s3: G12(g1); G11(g2)
    gemm_mfma<<<gemm_grid, 256, 0, stream>>>(H1a, wt12, b12, H0a, HID_D);
    gemm_mfma<<<gemm_grid, 256, 0, stream>>>(H0b, wt11, b11, H1b, FIN_D);
    // s4: G12(g2) || agg2(g1)
    fused_k<64, 16><<<NG + aggB512, 256, 0, stream>>>(H1b, wt12, b12, H0b, HID_D,
                                                      H0a, row_start, csr_src, H1a, 0, NG);
    // s5: G21(g1) || agg2(g2)
    fused_k<64, 16><<<NG + aggB512, 256, 0, stream>>>(H1a, wt21, b21, H0a, HID_D,
                                                      H0b, row_start, csr_src, H1b, N1, NG);
    // s6: G22(g1); G21(g2)
    gemm_mfma<<<gemm_grid, 256, 0, stream>>>(H0a, wt22, b22, H1a, HID_D);
    gemm_mfma<<<gemm_grid, 256, 0, stream>>>(H1b, wt21, b21, H0b, HID_D);
    // s7: G22(g2) || agg3(g1)
    fused_k<64, 16><<<NG + aggB512, 256, 0, stream>>>(H0b, wt22, b22, H1b, HID_D,
                                                      H1a, row_start, csr_src, H0a, 0, NG);
    // s8: G31(g1) || agg3(g2)
    fused_k<64, 16><<<NG + aggB512, 256, 0, stream>>>(H0a, wt31, b31, H1a, HID_D,
                                                      H1b, row_start, csr_src, H0b, N1, NG);
    // s9: G32(g1); G31(g2)
    gemm_mfma<<<gemm_grid, 256, 0, stream>>>(H1a, wt32, b32, H0a, HID_D);
    gemm_mfma<<<gemm_grid, 256, 0, stream>>>(H0b, wt31, b31, H1b, HID_D);
    // s10: G32(g2)
    gemm_mfma<<<gemm_grid, 256, 0, stream>>>(H1b, wt32, b32, H0b, HID_D);
    // s11: lin per graph
    lin_kernel<<<(N1 + 3) / 4, 256, 0, stream>>>(H0a, lw, lb, o, N1);
    lin_kernel<<<(N1 + 3) / 4, 256, 0, stream>>>(H0b, lw, lb, o + 2 * (size_t)N1, N1);

    // ---- distance + radix-select top-k ----
    dist_kernel<<<(N1 + 255) / 256, 256, 0, stream>>>(o, dist);
    hipMemsetAsync(selblk, 0, (4096 + 64) * sizeof(int), stream);
    histd_kernel<<<(N1 + 255) / 256, 256, 0, stream>>>(dist, hist);
    selk_kernel<<<1, 256, 0, stream>>>(hist, selout);
    compact_kernel<<<(N1 + 255) / 256, 256, 0, stream>>>(dist, selout, nc, cd, ci);
    rankc_kernel<<<(N1 + 255) / 256, 256, 0, stream>>>(cd, ci, nc, vals);

    // ---- head MLP ----
    head_kernel<<<1, 512, 0, stream>>>(vals, fc1w, fc1b, ln1g, ln1b,
                                       fc2w, fc2b, ln2g, ln2b, fc3w, fc3b,
                                       (float*)d_out);
}

// Round 9
// 1002.123 us; speedup vs baseline: 1.2793x; 1.0266x over previous
//
#include <hip/hip_runtime.h>
#include <hip/hip_bf16.h>
#include <math.h>

#define N1      20000          // nodes per graph
#define NT      40000          // both graphs
#define E1      640000         // edges per graph
#define ET      1280000
#define FIN_D   256
#define HID_D   512
#define TOPK    1000
#define MP1     20096          // 157 * 128 (padded M per graph)
#define GRPS1   313            // ceil(20000/64)
#define SCAN_NB 157            // ceil(40000/256)
#define NGEMM   628            // 157 x 4 blocks per 20096x512 gemm

typedef __attribute__((ext_vector_type(8))) short short8;
typedef __attribute__((ext_vector_type(4))) float floatx4;
typedef unsigned int uintx4 __attribute__((ext_vector_type(4)));

__device__ __forceinline__ unsigned short f2bf(float f) {
    union { __hip_bfloat16 h; unsigned short u; } cv;
    cv.h = __float2bfloat16(f);
    return cv.u;
}
__device__ __forceinline__ float bflo(unsigned int u) {
    union { unsigned int i; float f; } c; c.i = u << 16; return c.f;
}
__device__ __forceinline__ float bfhi(unsigned int u) {
    union { unsigned int i; float f; } c; c.i = u & 0xffff0000u; return c.f;
}

// ---------------- CSR build (both graphs in one node space) ----------------
__global__ void hist_kernel(const int* __restrict__ ei1, const int* __restrict__ ei2,
                            int* __restrict__ deg) {
    int e = blockIdx.x * blockDim.x + threadIdx.x;
    if (e >= ET) return;
    int d = (e < E1) ? ei1[E1 + e] : (ei2[E1 + (e - E1)] + N1);
    atomicAdd(&deg[d], 1);
}

__global__ void scan1_kernel(const int* __restrict__ deg, int* __restrict__ tmp,
                             int* __restrict__ bsum) {
    __shared__ int tile[256];
    int t = threadIdx.x;
    int i = blockIdx.x * 256 + t;
    int v = (i < NT) ? deg[i] : 0;
    tile[t] = v;
    __syncthreads();
    for (int off = 1; off < 256; off <<= 1) {
        int x = (t >= off) ? tile[t - off] : 0;
        __syncthreads();
        tile[t] += x;
        __syncthreads();
    }
    if (i < NT) tmp[i] = tile[t] - v;
    if (t == 255) bsum[blockIdx.x] = tile[255];
}

__global__ void scan2_kernel(const int* __restrict__ bsum, int* __restrict__ boff,
                             int* __restrict__ row_start) {
    __shared__ int tile[256];
    int t = threadIdx.x;
    int v = (t < SCAN_NB) ? bsum[t] : 0;
    tile[t] = v;
    __syncthreads();
    for (int off = 1; off < 256; off <<= 1) {
        int x = (t >= off) ? tile[t - off] : 0;
        __syncthreads();
        tile[t] += x;
        __syncthreads();
    }
    if (t < SCAN_NB) boff[t] = tile[t] - v;
    if (t == 255) row_start[NT] = tile[255];
}

__global__ void scan3_kernel(const int* __restrict__ tmp, const int* __restrict__ boff,
                             int* __restrict__ row_start, int* __restrict__ cursor) {
    int i = blockIdx.x * 256 + threadIdx.x;
    if (i < NT) {
        int rs = tmp[i] + boff[blockIdx.x];
        row_start[i] = rs;
        cursor[i] = rs;
    }
}

// fill graph1 edges only
__global__ void fill1_kernel(const int* __restrict__ ei1, int* __restrict__ cursor,
                             int* __restrict__ csr_src) {
    int e = blockIdx.x * 256 + threadIdx.x;
    if (e < E1) {
        int s = ei1[e], d = ei1[E1 + e];
        int p = atomicAdd(&cursor[d], 1);
        csr_src[p] = s;
    }
}

// fill graph2 edges (device body, fused into stage 1)
__device__ __forceinline__ void fill_g2_body(int e, const int* __restrict__ ei2,
                                             int* __restrict__ cursor, int* __restrict__ csr_src) {
    if (e < E1) {
        int s = ei2[e] + N1, d = ei2[E1 + e] + N1;
        int p = atomicAdd(&cursor[d], 1);
        csr_src[p] = s;
    }
}

// ---------------- conversions ----------------
__global__ void convx_kernel(const float* __restrict__ x, unsigned short* __restrict__ xb, int n4) {
    int i = blockIdx.x * 256 + threadIdx.x;
    if (i < n4) {
        float4 f = ((const float4*)x)[i];
        ushort4 u;
        u.x = f2bf(f.x); u.y = f2bf(f.y); u.z = f2bf(f.z); u.w = f2bf(f.w);
        ((ushort4*)xb)[i] = u;
    }
}

// W[K][N] fp32 -> Wt[N][K] bf16 (tiled transpose)
__global__ void convw_kernel(const float* __restrict__ W, unsigned short* __restrict__ Wt,
                             int K, int N) {
    __shared__ float tile[32][33];
    int k0 = blockIdx.x * 32, n0 = blockIdx.y * 32;
    int tx = threadIdx.x & 31, ty = threadIdx.x >> 5;
    for (int r = ty; r < 32; r += 8) tile[r][tx] = W[(size_t)(k0 + r) * N + n0 + tx];
    __syncthreads();
    for (int r = ty; r < 32; r += 8)
        Wt[(size_t)(n0 + r) * K + k0 + tx] = f2bf(tile[tx][r]);
}

// ---------------- GIN aggregation body (per graph) -----------------------------
#define ACC8(u) do { \
    acc[0] += bflo((u).x); acc[1] += bfhi((u).x); \
    acc[2] += bflo((u).y); acc[3] += bfhi((u).y); \
    acc[4] += bflo((u).z); acc[5] += bfhi((u).z); \
    acc[6] += bflo((u).w); acc[7] += bfhi((u).w); } while (0)

template<int LPR, int NSLAB>   // LPR = uintx4 per row (D/8); NSLAB = LPR/4
__device__ __forceinline__ void agg_body(int ab, int tid,
                                         const unsigned short* __restrict__ x,
                                         const int* __restrict__ row_start,
                                         const int* __restrict__ csr_src,
                                         unsigned short* __restrict__ h, int n0) {
    int phase = ab / (8 * GRPS1);
    int rem = ab % (8 * GRPS1);
    int slab = phase * 8 + (rem & 7);          // XCD round-robin
    int grp = rem >> 3;
    int lid = grp * 64 + (tid >> 2);
    bool act = lid < N1;
    int lidc = act ? lid : (N1 - 1);
    int nid = n0 + lidc;
    int c = tid & 3;
    int chunk = slab * 4 + c;
    const uintx4* Xc = (const uintx4*)x + chunk;
    uintx4 v = Xc[(size_t)lidc * LPR];
    float acc[8];
    acc[0] = bflo(v.x); acc[1] = bfhi(v.x);
    acc[2] = bflo(v.y); acc[3] = bfhi(v.y);
    acc[4] = bflo(v.z); acc[5] = bfhi(v.z);
    acc[6] = bflo(v.w); acc[7] = bfhi(v.w);
    int s = row_start[nid], e = row_start[nid + 1];
    if (!act) e = s;
    int p = s;
    for (; p + 8 <= e; p += 8) {
        int n0_ = csr_src[p + 0] - n0, n1_ = csr_src[p + 1] - n0;
        int n2_ = csr_src[p + 2] - n0, n3_ = csr_src[p + 3] - n0;
        int n4_ = csr_src[p + 4] - n0, n5_ = csr_src[p + 5] - n0;
        int n6_ = csr_src[p + 6] - n0, n7_ = csr_src[p + 7] - n0;
        uintx4 u0 = Xc[(size_t)n0_ * LPR];
        uintx4 u1 = Xc[(size_t)n1_ * LPR];
        uintx4 u2 = Xc[(size_t)n2_ * LPR];
        uintx4 u3 = Xc[(size_t)n3_ * LPR];
        uintx4 u4 = Xc[(size_t)n4_ * LPR];
        uintx4 u5 = Xc[(size_t)n5_ * LPR];
        uintx4 u6 = Xc[(size_t)n6_ * LPR];
        uintx4 u7 = Xc[(size_t)n7_ * LPR];
        ACC8(u0); ACC8(u1); ACC8(u2); ACC8(u3);
        ACC8(u4); ACC8(u5); ACC8(u6); ACC8(u7);
    }
    for (; p + 2 <= e; p += 2) {
        int na = csr_src[p + 0] - n0, nb = csr_src[p + 1] - n0;
        uintx4 u0 = Xc[(size_t)na * LPR];
        uintx4 u1 = Xc[(size_t)nb * LPR];
        ACC8(u0); ACC8(u1);
    }
    if (p < e) {
        int na = csr_src[p] - n0;
        uintx4 u0 = Xc[(size_t)na * LPR];
        ACC8(u0);
    }
    if (act) {
        uintx4 o;
        o.x = (unsigned)f2bf(acc[0]) | ((unsigned)f2bf(acc[1]) << 16);
        o.y = (unsigned)f2bf(acc[2]) | ((unsigned)f2bf(acc[3]) << 16);
        o.z = (unsigned)f2bf(acc[4]) | ((unsigned)f2bf(acc[5]) << 16);
        o.w = (unsigned)f2bf(acc[6]) | ((unsigned)f2bf(acc[7]) << 16);
        ((uintx4*)h)[(size_t)lidc * LPR + chunk] = o;
    }
}

// ---------------- stage 1: agg1(g1) || fill(g2) --------------------------------
__launch_bounds__(256, 8)
__global__ void fused_aggfill(const unsigned short* __restrict__ x,
                              const int* __restrict__ row_start,
                              const int* __restrict__ csr_src,
                              unsigned short* __restrict__ h,
                              const int* __restrict__ ei2,
                              int* __restrict__ cursor,
                              int* __restrict__ csr_w, int nAgg) {
    int b = blockIdx.x;
    if (b < nAgg) {
        agg_body<32, 8>(b, threadIdx.x, x, row_start, csr_src, h, 0);
    } else {
        fill_g2_body((b - nAgg) * 256 + threadIdx.x, ei2, cursor, csr_w);
    }
}

// ---------------- bf16 MFMA GEMM body: C = relu(A[MP1,K] @ W[K,512] + bias) -----
__device__ __forceinline__ void gemm_body(int bx, int by, int tid,
                                          unsigned short* smem,
                                          const unsigned short* __restrict__ A,
                                          const unsigned short* __restrict__ Wt,
                                          const float* __restrict__ bias,
                                          unsigned short* __restrict__ C, int K) {
    const int N = HID_D;
    unsigned short* As = smem;            // 128*32
    unsigned short* Bs = smem + 4096;     // 128*32
    int lane = tid & 63;
    int w = tid >> 6;
    int wr = w >> 1, wc = w & 1;
    int row0 = bx * 128;
    int col0 = by * 128;
    floatx4 acc[4][4] = {};
    int lr = tid >> 2;
    int c8 = (tid & 3) * 8;
    const unsigned short* Ag = A + (size_t)row0 * K;
    const unsigned short* Bg = Wt + (size_t)col0 * K;

    for (int kt = 0; kt < K; kt += 32) {
#pragma unroll
        for (int l = 0; l < 2; ++l) {
            int r = l * 64 + lr;
            __builtin_amdgcn_global_load_lds(
                (const __attribute__((address_space(1))) void*)(Ag + (size_t)r * K + kt + c8),
                (__attribute__((address_space(3))) void*)(As + l * 2048 + tid * 8),
                16, 0, 0);
            __builtin_amdgcn_global_load_lds(
                (const __attribute__((address_space(1))) void*)(Bg + (size_t)r * K + kt + c8),
                (__attribute__((address_space(3))) void*)(Bs + l * 2048 + tid * 8),
                16, 0, 0);
        }
        __syncthreads();
        short8 af[4], bf[4];
        int q8 = (lane >> 4) * 8;
#pragma unroll
        for (int i = 0; i < 4; ++i) {
            int m = wr * 64 + i * 16 + (lane & 15);
            af[i] = *(const short8*)&As[m * 32 + q8];
            int n = wc * 64 + i * 16 + (lane & 15);
            bf[i] = *(const short8*)&Bs[n * 32 + q8];
        }
#pragma unroll
        for (int i = 0; i < 4; ++i)
#pragma unroll
            for (int j = 0; j < 4; ++j)
                acc[i][j] = __builtin_amdgcn_mfma_f32_16x16x32_bf16(af[i], bf[j], acc[i][j], 0, 0, 0);
        __syncthreads();
    }
    int q = lane >> 4;
    int cn = lane & 15;
#pragma unroll
    for (int j = 0; j < 4; ++j) {
        int col = col0 + wc * 64 + j * 16 + cn;
        float bv = bias[col];
#pragma unroll
        for (int i = 0; i < 4; ++i) {
            int rowb = row0 + wr * 64 + i * 16 + q * 4;
#pragma unroll
            for (int r = 0; r < 4; ++r) {
                float vv = fmaxf(acc[i][j][r] + bv, 0.f);
                C[(size_t)(rowb + r) * N + col] = f2bf(vv);
            }
        }
    }
}

// two independent gemms (different graphs) in one launch
__launch_bounds__(256)
__global__ void gemm_pair(const unsigned short* __restrict__ A1,
                          const unsigned short* __restrict__ W1,
                          const float* __restrict__ b1,
                          unsigned short* __restrict__ C1, int K1,
                          const unsigned short* __restrict__ A2,
                          const unsigned short* __restrict__ W2,
                          const float* __restrict__ b2,
                          unsigned short* __restrict__ C2, int K2) {
    __shared__ unsigned short smem[8192];
    int b = blockIdx.x;
    if (b < NGEMM) {
        gemm_body(b % 157, b / 157, threadIdx.x, smem, A1, W1, b1, C1, K1);
    } else {
        b -= NGEMM;
        gemm_body(b % 157, b / 157, threadIdx.x, smem, A2, W2, b2, C2, K2);
    }
}

// ---------------- fused: gemm(graph A) blocks first, agg(graph B) blocks after --
template<int LPR, int NSLAB>
__launch_bounds__(256)
__global__ void fused_k(const unsigned short* __restrict__ A,
                        const unsigned short* __restrict__ Wt,
                        const float* __restrict__ bias,
                        unsigned short* __restrict__ C, int K,
                        const unsigned short* __restrict__ x,
                        const int* __restrict__ row_start,
                        const int* __restrict__ csr_src,
                        unsigned short* __restrict__ h, int n0, int nGemm) {
    __shared__ unsigned short smem[8192];
    int b = blockIdx.x;
    if (b < nGemm) {
        gemm_body(b % 157, b / 157, threadIdx.x, smem, A, Wt, bias, C, K);
    } else {
        agg_body<LPR, NSLAB>(b - nGemm, threadIdx.x, x, row_start, csr_src, h, n0);
    }
}

// ---------------- final linear [M,512]bf16 @ [512,2]fp32 + b ----------------
__device__ __forceinline__ void lin_body(int bb, int tid, const unsigned short* __restrict__ A,
                                         const float* __restrict__ w, const float* __restrict__ b,
                                         float* __restrict__ o, int M) {
    int wave = tid >> 6;
    int lane = tid & 63;
    int row = bb * 4 + wave;
    if (row >= M) return;
    const uint4* Ar = (const uint4*)(A + (size_t)row * 512);
    uint4 u = Ar[lane];
    float f[8];
    f[0] = bflo(u.x); f[1] = bfhi(u.x); f[2] = bflo(u.y); f[3] = bfhi(u.y);
    f[4] = bflo(u.z); f[5] = bfhi(u.z); f[6] = bflo(u.w); f[7] = bfhi(u.w);
    float s0 = 0.f, s1 = 0.f;
#pragma unroll
    for (int j = 0; j < 8; ++j) {
        int base = (lane * 8 + j) * 2;
        s0 = fmaf(f[j], w[base + 0], s0);
        s1 = fmaf(f[j], w[base + 1], s1);
    }
#pragma unroll
    for (int off = 32; off > 0; off >>= 1) {
        s0 += __shfl_down(s0, off, 64);
        s1 += __shfl_down(s1, off, 64);
    }
    if (lane == 0) { o[row * 2] = s0 + b[0]; o[row * 2 + 1] = s1 + b[1]; }
}

__global__ void lin_kernel(const unsigned short* __restrict__ A, const float* __restrict__ w,
                           const float* __restrict__ b, float* __restrict__ o, int M) {
    lin_body(blockIdx.x, threadIdx.x, A, w, b, o, M);
}

// s10: G32(g2) || lin(g1)
__launch_bounds__(256)
__global__ void fused_gemmlin(const unsigned short* __restrict__ A,
                              const unsigned short* __restrict__ Wt,
                              const float* __restrict__ bias,
                              unsigned short* __restrict__ C, int K,
                              const unsigned short* __restrict__ L,
                              const float* __restrict__ lw, const float* __restrict__ lb,
                              float* __restrict__ o) {
    __shared__ unsigned short smem[8192];
    int b = blockIdx.x;
    if (b < NGEMM) {
        gemm_body(b % 157, b / 157, threadIdx.x, smem, A, Wt, bias, C, K);
    } else {
        lin_body(b - NGEMM, threadIdx.x, L, lw, lb, o, N1);
    }
}

// ---------------- pairwise distance ----------------
__global__ void dist_kernel(const float* __restrict__ o, float* __restrict__ dist) {
    int i = blockIdx.x * blockDim.x + threadIdx.x;
    if (i < N1) {
        float2 a = ((const float2*)o)[i];
        float2 b = ((const float2*)o)[N1 + i];
        float d0 = a.x - b.x + 1e-6f, d1 = a.y - b.y + 1e-6f;
        dist[i] = sqrtf(d0 * d0 + d1 * d1);
    }
}

// ---------------- radix-select top-k ----------------
__global__ void histd_kernel(const float* __restrict__ dist, int* __restrict__ hist) {
    int i = blockIdx.x * blockDim.x + threadIdx.x;
    if (i < N1) {
        unsigned u = __float_as_uint(dist[i]);
        atomicAdd(&hist[u >> 19], 1);
    }
}

__global__ void selk_kernel(const int* __restrict__ hist, int* __restrict__ selout) {
    __shared__ int tile[256];
    int t = threadIdx.x;
    int running = 0;
    for (int tb = 0; tb < 16; ++tb) {
        int idx = 4095 - (tb * 256 + t);
        int v = hist[idx];
        tile[t] = v;
        __syncthreads();
        for (int off = 1; off < 256; off <<= 1) {
            int x = (t >= off) ? tile[t - off] : 0;
            __syncthreads();
            tile[t] += x;
            __syncthreads();
        }
        int incl = running + tile[t];
        if (incl >= TOPK && incl - v < TOPK) selout[0] = idx;
        running += tile[255];
        __syncthreads();
        if (running >= TOPK) break;
    }
}

__global__ void compact_kernel(const float* __restrict__ dist, const int* __restrict__ selout,
                               int* __restrict__ nc, float* __restrict__ cd, int* __restrict__ ci) {
    int i = blockIdx.x * blockDim.x + threadIdx.x;
    if (i >= N1) return;
    float d = dist[i];
    int b = (int)(__float_as_uint(d) >> 19);
    if (b >= selout[0]) {
        int p = atomicAdd(nc, 1);
        cd[p] = d;
        ci[p] = i;
    }
}

#define CCH 2048
__global__ void rankc_kernel(const float* __restrict__ cd, const int* __restrict__ ci,
                             const int* __restrict__ nc_p, float* __restrict__ vals) {
    __shared__ float ds[CCH];
    __shared__ int   di_[CCH];
    int nc = *nc_p;
    int t = threadIdx.x;
    int q = blockIdx.x * 256 + t;
    float dq = 0.f; int iq = 0;
    if (q < nc) { dq = cd[q]; iq = ci[q]; }
    int cnt = 0;
    for (int c0 = 0; c0 < nc; c0 += CCH) {
        int lim = min(CCH, nc - c0);
        for (int j = t; j < lim; j += 256) { ds[j] = cd[c0 + j]; di_[j] = ci[c0 + j]; }
        __syncthreads();
        if (q < nc) {
            for (int j = 0; j < lim; ++j) {
                float dj = ds[j];
                cnt += (dj > dq) || (dj == dq && di_[j] < iq);
            }
        }
        __syncthreads();
    }
    if (q < nc && cnt < TOPK) vals[cnt] = dq;
}

// ---------------- head MLP ----------------
__launch_bounds__(512)
__global__ void head_kernel(const float* __restrict__ vals,
                            const float* __restrict__ fc1_w, const float* __restrict__ fc1_b,
                            const float* __restrict__ ln1_g, const float* __restrict__ ln1_b,
                            const float* __restrict__ fc2_w, const float* __restrict__ fc2_b,
                            const float* __restrict__ ln2_g, const float* __restrict__ ln2_b,
                            const float* __restrict__ fc3_w, const float* __restrict__ fc3_b,
                            float* __restrict__ out) {
    __shared__ float sv[TOPK];
    __shared__ float a1[128];
    __shared__ float red[512];
    __shared__ float s_m, s_r;
    int t = threadIdx.x;
    for (int i = t; i < TOPK; i += 512) sv[i] = vals[i];
    __syncthreads();
    float h1 = 0.f;
    if (t < 128) {
        h1 = fc1_b[t];
        for (int j = 0; j < TOPK; ++j) h1 = fmaf(sv[j], fc1_w[j * 128 + t], h1);
    }
    red[t] = (t < 128) ? h1 : 0.f; __syncthreads();
    for (int s = 256; s > 0; s >>= 1) { if (t < s) red[t] += red[t + s]; __syncthreads(); }
    if (t == 0) s_m = red[0] / 128.f;
    __syncthreads();
    float m1 = s_m;
    float dv = (t < 128) ? (h1 - m1) : 0.f;
    red[t] = dv * dv; __syncthreads();
    for (int s = 256; s > 0; s >>= 1) { if (t < s) red[t] += red[t + s]; __syncthreads(); }
    if (t == 0) s_r = rsqrtf(red[0] / 128.f + 1e-5f);
    __syncthreads();
    float r1 = s_r;
    if (t < 128) a1[t] = fmaxf((h1 - m1) * r1 * ln1_g[t] + ln1_b[t], 0.f);
    __syncthreads();
    float h2 = fc2_b[t];
    for (int j = 0; j < 128; ++j) h2 = fmaf(a1[j], fc2_w[j * 512 + t], h2);
    red[t] = h2; __syncthreads();
    for (int s = 256; s > 0; s >>= 1) { if (t < s) red[t] += red[t + s]; __syncthreads(); }
    if (t == 0) s_m = red[0] / 512.f;
    __syncthreads();
    float m2 = s_m;
    float d2 = h2 - m2;
    red[t] = d2 * d2; __syncthreads();
    for (int s = 256; s > 0; s >>= 1) { if (t < s) red[t] += red[t + s]; __syncthreads(); }
    if (t == 0) s_r = rsqrtf(red[0] / 512.f + 1e-5f);
    __syncthreads();
    float r2 = s_r;
    float y2 = fmaxf((h2 - m2) * r2 * ln2_g[t] + ln2_b[t], 0.f);
    red[t] = y2 * fc3_w[t]; __syncthreads();
    for (int s = 256; s > 0; s >>= 1) { if (t < s) red[t] += red[t + s]; __syncthreads(); }
    if (t == 0) out[0] = 1.f / (1.f + expf(-(red[0] + fc3_b[0])));
}

extern "C" void kernel_launch(void* const* d_in, const int* in_sizes, int n_in,
                              void* d_out, int out_size, void* d_ws, size_t ws_size,
                              hipStream_t stream) {
    const float* x1   = (const float*)d_in[0];
    const int*   ei1  = (const int*)d_in[1];
    const float* x2   = (const float*)d_in[2];
    const int*   ei2  = (const int*)d_in[3];
    const float* w11  = (const float*)d_in[4];
    const float* b11  = (const float*)d_in[5];
    const float* w12  = (const float*)d_in[6];
    const float* b12  = (const float*)d_in[7];
    const float* w21  = (const float*)d_in[8];
    const float* b21  = (const float*)d_in[9];
    const float* w22  = (const float*)d_in[10];
    const float* b22  = (const float*)d_in[11];
    const float* w31  = (const float*)d_in[12];
    const float* b31  = (const float*)d_in[13];
    const float* w32  = (const float*)d_in[14];
    const float* b32  = (const float*)d_in[15];
    const float* lw   = (const float*)d_in[16];
    const float* lb   = (const float*)d_in[17];
    const float* fc1w = (const float*)d_in[18];
    const float* fc1b = (const float*)d_in[19];
    const float* ln1g = (const float*)d_in[20];
    const float* ln1b = (const float*)d_in[21];
    const float* fc2w = (const float*)d_in[22];
    const float* fc2b = (const float*)d_in[23];
    const float* ln2g = (const float*)d_in[24];
    const float* ln2b = (const float*)d_in[25];
    const float* fc3w = (const float*)d_in[26];
    const float* fc3b = (const float*)d_in[27];

    char* ws = (char*)d_ws;
    size_t off = 0;
    auto alloc = [&](size_t bytes) -> void* {
        void* p = ws + off;
        off += (bytes + 255) & ~(size_t)255;
        return p;
    };
    unsigned short* XB  = (unsigned short*)alloc((size_t)NT * FIN_D * 2);  // batched inputs
    unsigned short* H0a = (unsigned short*)alloc((size_t)MP1 * HID_D * 2);
    unsigned short* H1a = (unsigned short*)alloc((size_t)MP1 * HID_D * 2);
    unsigned short* H0b = (unsigned short*)alloc((size_t)MP1 * HID_D * 2);
    unsigned short* H1b = (unsigned short*)alloc((size_t)MP1 * HID_D * 2);
    unsigned short* wt11 = (unsigned short*)alloc((size_t)HID_D * FIN_D * 2);
    unsigned short* wt12 = (unsigned short*)alloc((size_t)HID_D * HID_D * 2);
    unsigned short* wt21 = (unsigned short*)alloc((size_t)HID_D * HID_D * 2);
    unsigned short* wt22 = (unsigned short*)alloc((size_t)HID_D * HID_D * 2);
    unsigned short* wt31 = (unsigned short*)alloc((size_t)HID_D * HID_D * 2);
    unsigned short* wt32 = (unsigned short*)alloc((size_t)HID_D * HID_D * 2);
    float* o         = (float*)alloc((size_t)NT * 2 * 4);
    float* dist      = (float*)alloc((size_t)N1 * 4);
    float* vals      = (float*)alloc((size_t)TOPK * 4);
    int*   row_start = (int*)alloc((size_t)(NT + 1) * 4);
    int*   cursor    = (int*)alloc((size_t)NT * 4);
    int*   deg       = (int*)alloc((size_t)NT * 4);
    int*   scan_tmp  = (int*)alloc((size_t)NT * 4);
    int*   bsum      = (int*)alloc((size_t)SCAN_NB * 4);
    int*   boff      = (int*)alloc((size_t)SCAN_NB * 4);
    int*   csr_src   = (int*)alloc((size_t)ET * 4);
    int*   selblk    = (int*)alloc((size_t)(4096 + 64) * 4);  // hist + nc
    int*   hist      = selblk;
    int*   nc        = selblk + 4096;
    int*   selout    = (int*)alloc(2 * 4);
    float* cd        = (float*)alloc((size_t)N1 * 4);
    int*   ci        = (int*)alloc((size_t)N1 * 4);

    // ---- weight / input conversions ----
    {
        dim3 g11(FIN_D / 32, HID_D / 32);
        dim3 g55(HID_D / 32, HID_D / 32);
        convw_kernel<<<g11, 256, 0, stream>>>(w11, wt11, FIN_D, HID_D);
        convw_kernel<<<g55, 256, 0, stream>>>(w12, wt12, HID_D, HID_D);
        convw_kernel<<<g55, 256, 0, stream>>>(w21, wt21, HID_D, HID_D);
        convw_kernel<<<g55, 256, 0, stream>>>(w22, wt22, HID_D, HID_D);
        convw_kernel<<<g55, 256, 0, stream>>>(w31, wt31, HID_D, HID_D);
        convw_kernel<<<g55, 256, 0, stream>>>(w32, wt32, HID_D, HID_D);
        int n4 = N1 * FIN_D / 4;
        convx_kernel<<<(n4 + 255) / 256, 256, 0, stream>>>(x1, XB, n4);
        convx_kernel<<<(n4 + 255) / 256, 256, 0, stream>>>(x2, XB + (size_t)N1 * FIN_D, n4);
    }

    // ---- CSR build: batched hist/scan, per-graph fill ----
    hipMemsetAsync(deg, 0, NT * sizeof(int), stream);
    hist_kernel<<<(ET + 255) / 256, 256, 0, stream>>>(ei1, ei2, deg);
    scan1_kernel<<<SCAN_NB, 256, 0, stream>>>(deg, scan_tmp, bsum);
    scan2_kernel<<<1, 256, 0, stream>>>(bsum, boff, row_start);
    scan3_kernel<<<SCAN_NB, 256, 0, stream>>>(scan_tmp, boff, row_start, cursor);
    fill1_kernel<<<(E1 + 255) / 256, 256, 0, stream>>>(ei1, cursor, csr_src);

    // ---- staggered two-graph pipeline ----
    const unsigned short* XBg2 = XB + (size_t)N1 * FIN_D;
    int aggB256 = 8 * GRPS1;                 // 2504
    int aggB512 = 16 * GRPS1;                // 5008
    int fillB   = (E1 + 255) / 256;          // 2500

    // s1: agg1(g1) || fill(g2)
    fused_aggfill<<<aggB256 + fillB, 256, 0, stream>>>(XB, row_start, csr_src, H0a,
                                                       ei2, cursor, csr_src, aggB256);
    // s2: G11(g1) || agg1(g2)
    fused_k<32, 8><<<NGEMM + aggB256, 256, 0, stream>>>(H0a, wt11, b11, H1a, FIN_D,
                                                        XBg2, row_start, csr_src, H0b, N1, NGEMM);
    // s3: G12(g1) + G11(g2) merged
    gemm_pair<<<2 * NGEMM, 256, 0, stream>>>(H1a, wt12, b12, H0a, HID_D,
                                             H0b, wt11, b11, H1b, FIN_D);
    // s4: G12(g2) || agg2(g1)
    fused_k<64, 16><<<NGEMM + aggB512, 256, 0, stream>>>(H1b, wt12, b12, H0b, HID_D,
                                                         H0a, row_start, csr_src, H1a, 0, NGEMM);
    // s5: G21(g1) || agg2(g2)
    fused_k<64, 16><<<NGEMM + aggB512, 256, 0, stream>>>(H1a, wt21, b21, H0a, HID_D,
                                                         H0b, row_start, csr_src, H1b, N1, NGEMM);
    // s6: G22(g1) + G21(g2) merged
    gemm_pair<<<2 * NGEMM, 256, 0, stream>>>(H0a, wt22, b22, H1a, HID_D,
                                             H1b, wt21, b21, H0b, HID_D);
    // s7: G22(g2) || agg3(g1)
    fused_k<64, 16><<<NGEMM + aggB512, 256, 0, stream>>>(H0b, wt22, b22, H1b, HID_D,
                                                         H1a, row_start, csr_src, H0a, 0, NGEMM);
    // s8: G31(g1) || agg3(g2)
    fused_k<64, 16><<<NGEMM + aggB512, 256, 0, stream>>>(H0a, wt31, b31, H1a, HID_D,
                                                         H1b, row_start, csr_src, H0b, N1, NGEMM);
    // s9: G32(g1) + G31(g2) merged
    gemm_pair<<<2 * NGEMM, 256, 0, stream>>>(H1a, wt32, b32, H0a, HID_D,
                                             H0b, wt31, b31, H1b, HID_D);
    // s10: G32(g2) || lin(g1)
    fused_gemmlin<<<NGEMM + (N1 + 3) / 4, 256, 0, stream>>>(H1b, wt32, b32, H0b, HID_D,
                                                            H0a, lw, lb, o);
    // s11: lin(g2)
    lin_kernel<<<(N1 + 3) / 4, 256, 0, stream>>>(H0b, lw, lb, o + 2 * (size_t)N1, N1);

    // ---- distance + radix-select top-k ----
    dist_kernel<<<(N1 + 255) / 256, 256, 0, stream>>>(o, dist);
    hipMemsetAsync(selblk, 0, (4096 + 64) * sizeof(int), stream);
    histd_kernel<<<(N1 + 255) / 256, 256, 0, stream>>>(dist, hist);
    selk_kernel<<<1, 256, 0, stream>>>(hist, selout);
    compact_kernel<<<(N1 + 255) / 256, 256, 0, stream>>>(dist, selout, nc, cd, ci);
    rankc_kernel<<<(N1 + 255) / 256, 256, 0, stream>>>(cd, ci, nc, vals);

    // ---- head MLP ----
    head_kernel<<<1, 512, 0, stream>>>(vals, fc1w, fc1b, ln1g, ln1b,
                                       fc2w, fc2b, ln2g, ln2b, fc3w, fc3b,
                                       (float*)d_out);
}

// Round 10
// 1000.138 us; speedup vs baseline: 1.2818x; 1.0020x over previous
//
#include <hip/hip_runtime.h>
#include <hip/hip_bf16.h>
#include <math.h>

#define N1      20000          // nodes per graph
#define NT      40000          // both graphs
#define E1      640000         // edges per graph
#define ET      1280000
#define FIN_D   256
#define HID_D   512
#define TOPK    1000
#define MP1     20096          // 157 * 128 (padded M per graph)
#define GRPS1   313            // ceil(20000/64)
#define SCAN_NB 157            // ceil(40000/256)
#define NGEMM   628            // 157 x 4 blocks per 20096x512 gemm

typedef __attribute__((ext_vector_type(8))) short short8;
typedef __attribute__((ext_vector_type(4))) float floatx4;
typedef unsigned int uintx4 __attribute__((ext_vector_type(4)));

__device__ __forceinline__ unsigned short f2bf(float f) {
    union { __hip_bfloat16 h; unsigned short u; } cv;
    cv.h = __float2bfloat16(f);
    return cv.u;
}
__device__ __forceinline__ float bflo(unsigned int u) {
    union { unsigned int i; float f; } c; c.i = u << 16; return c.f;
}
__device__ __forceinline__ float bfhi(unsigned int u) {
    union { unsigned int i; float f; } c; c.i = u & 0xffff0000u; return c.f;
}

// ---------------- fused prep: hist(both graphs) + 6x convw + 2x convx ----------
// all independent; one launch replaces 9.
__device__ __forceinline__ void convw_body(int bl, int K, float* tile /*32x33*/,
                                           const float* __restrict__ W,
                                           unsigned short* __restrict__ Wt) {
    int kb = K / 32;
    int k0 = (bl % kb) * 32, n0 = (bl / kb) * 32;
    int tx = threadIdx.x & 31, ty = threadIdx.x >> 5;
    for (int r = ty; r < 32; r += 8) tile[r * 33 + tx] = W[(size_t)(k0 + r) * HID_D + n0 + tx];
    __syncthreads();
    for (int r = ty; r < 32; r += 8)
        Wt[(size_t)(n0 + r) * K + k0 + tx] = f2bf(tile[tx * 33 + r]);
}
__device__ __forceinline__ void convx_body(int i, const float* __restrict__ x,
                                           unsigned short* __restrict__ xb) {
    float4 f = ((const float4*)x)[i];
    ushort4 u;
    u.x = f2bf(f.x); u.y = f2bf(f.y); u.z = f2bf(f.z); u.w = f2bf(f.w);
    ((ushort4*)xb)[i] = u;
}

__launch_bounds__(256)
__global__ void prep_kernel(const int* __restrict__ ei1, const int* __restrict__ ei2,
                            int* __restrict__ deg,
                            const float* w11, unsigned short* wt11,
                            const float* w12, unsigned short* wt12,
                            const float* w21, unsigned short* wt21,
                            const float* w22, unsigned short* wt22,
                            const float* w31, unsigned short* wt31,
                            const float* w32, unsigned short* wt32,
                            const float* x1, const float* x2, unsigned short* xb) {
    __shared__ float tile[32 * 33];
    int b = blockIdx.x;
    if (b < 5000) {                       // hist, both graphs
        int e = b * 256 + threadIdx.x;
        if (e < ET) {
            int d = (e < E1) ? ei1[E1 + e] : (ei2[E1 + (e - E1)] + N1);
            atomicAdd(&deg[d], 1);
        }
    } else if (b < 5128)  { convw_body(b - 5000, FIN_D, tile, w11, wt11); }
    else if (b < 5384)    { convw_body(b - 5128, HID_D, tile, w12, wt12); }
    else if (b < 5640)    { convw_body(b - 5384, HID_D, tile, w21, wt21); }
    else if (b < 5896)    { convw_body(b - 5640, HID_D, tile, w22, wt22); }
    else if (b < 6152)    { convw_body(b - 5896, HID_D, tile, w31, wt31); }
    else if (b < 6408)    { convw_body(b - 6152, HID_D, tile, w32, wt32); }
    else if (b < 11408)   { convx_body((b - 6408) * 256 + threadIdx.x, x1, xb); }
    else                  { convx_body((b - 11408) * 256 + threadIdx.x, x2,
                                       xb + (size_t)N1 * FIN_D); }
}

// ---------------- CSR scans + fills ----------------
__global__ void scan1_kernel(const int* __restrict__ deg, int* __restrict__ tmp,
                             int* __restrict__ bsum) {
    __shared__ int tile[256];
    int t = threadIdx.x;
    int i = blockIdx.x * 256 + t;
    int v = (i < NT) ? deg[i] : 0;
    tile[t] = v;
    __syncthreads();
    for (int off = 1; off < 256; off <<= 1) {
        int x = (t >= off) ? tile[t - off] : 0;
        __syncthreads();
        tile[t] += x;
        __syncthreads();
    }
    if (i < NT) tmp[i] = tile[t] - v;
    if (t == 255) bsum[blockIdx.x] = tile[255];
}

__global__ void scan2_kernel(const int* __restrict__ bsum, int* __restrict__ boff,
                             int* __restrict__ row_start) {
    __shared__ int tile[256];
    int t = threadIdx.x;
    int v = (t < SCAN_NB) ? bsum[t] : 0;
    tile[t] = v;
    __syncthreads();
    for (int off = 1; off < 256; off <<= 1) {
        int x = (t >= off) ? tile[t - off] : 0;
        __syncthreads();
        tile[t] += x;
        __syncthreads();
    }
    if (t < SCAN_NB) boff[t] = tile[t] - v;
    if (t == 255) row_start[NT] = tile[255];
}

__global__ void scan3_kernel(const int* __restrict__ tmp, const int* __restrict__ boff,
                             int* __restrict__ row_start, int* __restrict__ cursor) {
    int i = blockIdx.x * 256 + threadIdx.x;
    if (i < NT) {
        int rs = tmp[i] + boff[blockIdx.x];
        row_start[i] = rs;
        cursor[i] = rs;
    }
}

__global__ void fill1_kernel(const int* __restrict__ ei1, int* __restrict__ cursor,
                             int* __restrict__ csr_src) {
    int e = blockIdx.x * 256 + threadIdx.x;
    if (e < E1) {
        int s = ei1[e], d = ei1[E1 + e];
        int p = atomicAdd(&cursor[d], 1);
        csr_src[p] = s;
    }
}

__device__ __forceinline__ void fill_g2_body(int e, const int* __restrict__ ei2,
                                             int* __restrict__ cursor, int* __restrict__ csr_src) {
    if (e < E1) {
        int s = ei2[e] + N1, d = ei2[E1 + e] + N1;
        int p = atomicAdd(&cursor[d], 1);
        csr_src[p] = s;
    }
}

// ---------------- GIN aggregation body (per graph) -----------------------------
#define ACC8(u) do { \
    acc[0] += bflo((u).x); acc[1] += bfhi((u).x); \
    acc[2] += bflo((u).y); acc[3] += bfhi((u).y); \
    acc[4] += bflo((u).z); acc[5] += bfhi((u).z); \
    acc[6] += bflo((u).w); acc[7] += bfhi((u).w); } while (0)

template<int LPR, int NSLAB>   // LPR = uintx4 per row (D/8); NSLAB = LPR/4
__device__ __forceinline__ void agg_body(int ab, int tid,
                                         const unsigned short* __restrict__ x,
                                         const int* __restrict__ row_start,
                                         const int* __restrict__ csr_src,
                                         unsigned short* __restrict__ h, int n0) {
    int phase = ab / (8 * GRPS1);
    int rem = ab % (8 * GRPS1);
    int slab = phase * 8 + (rem & 7);          // XCD round-robin
    int grp = rem >> 3;
    int lid = grp * 64 + (tid >> 2);
    bool act = lid < N1;
    int lidc = act ? lid : (N1 - 1);
    int nid = n0 + lidc;
    int c = tid & 3;
    int chunk = slab * 4 + c;
    const uintx4* Xc = (const uintx4*)x + chunk;
    uintx4 v = Xc[(size_t)lidc * LPR];
    float acc[8];
    acc[0] = bflo(v.x); acc[1] = bfhi(v.x);
    acc[2] = bflo(v.y); acc[3] = bfhi(v.y);
    acc[4] = bflo(v.z); acc[5] = bfhi(v.z);
    acc[6] = bflo(v.w); acc[7] = bfhi(v.w);
    int s = row_start[nid], e = row_start[nid + 1];
    if (!act) e = s;
    int p = s;
    for (; p + 8 <= e; p += 8) {
        int n0_ = csr_src[p + 0] - n0, n1_ = csr_src[p + 1] - n0;
        int n2_ = csr_src[p + 2] - n0, n3_ = csr_src[p + 3] - n0;
        int n4_ = csr_src[p + 4] - n0, n5_ = csr_src[p + 5] - n0;
        int n6_ = csr_src[p + 6] - n0, n7_ = csr_src[p + 7] - n0;
        uintx4 u0 = Xc[(size_t)n0_ * LPR];
        uintx4 u1 = Xc[(size_t)n1_ * LPR];
        uintx4 u2 = Xc[(size_t)n2_ * LPR];
        uintx4 u3 = Xc[(size_t)n3_ * LPR];
        uintx4 u4 = Xc[(size_t)n4_ * LPR];
        uintx4 u5 = Xc[(size_t)n5_ * LPR];
        uintx4 u6 = Xc[(size_t)n6_ * LPR];
        uintx4 u7 = Xc[(size_t)n7_ * LPR];
        ACC8(u0); ACC8(u1); ACC8(u2); ACC8(u3);
        ACC8(u4); ACC8(u5); ACC8(u6); ACC8(u7);
    }
    for (; p + 2 <= e; p += 2) {
        int na = csr_src[p + 0] - n0, nb = csr_src[p + 1] - n0;
        uintx4 u0 = Xc[(size_t)na * LPR];
        uintx4 u1 = Xc[(size_t)nb * LPR];
        ACC8(u0); ACC8(u1);
    }
    if (p < e) {
        int na = csr_src[p] - n0;
        uintx4 u0 = Xc[(size_t)na * LPR];
        ACC8(u0);
    }
    if (act) {
        uintx4 o;
        o.x = (unsigned)f2bf(acc[0]) | ((unsigned)f2bf(acc[1]) << 16);
        o.y = (unsigned)f2bf(acc[2]) | ((unsigned)f2bf(acc[3]) << 16);
        o.z = (unsigned)f2bf(acc[4]) | ((unsigned)f2bf(acc[5]) << 16);
        o.w = (unsigned)f2bf(acc[6]) | ((unsigned)f2bf(acc[7]) << 16);
        ((uintx4*)h)[(size_t)lidc * LPR + chunk] = o;
    }
}

// ---------------- stage 1: agg1(g1) || fill(g2) --------------------------------
__launch_bounds__(256, 8)
__global__ void fused_aggfill(const unsigned short* __restrict__ x,
                              const int* __restrict__ row_start,
                              const int* __restrict__ csr_src,
                              unsigned short* __restrict__ h,
                              const int* __restrict__ ei2,
                              int* __restrict__ cursor,
                              int* __restrict__ csr_w, int nAgg) {
    int b = blockIdx.x;
    if (b < nAgg) {
        agg_body<32, 8>(b, threadIdx.x, x, row_start, csr_src, h, 0);
    } else {
        fill_g2_body((b - nAgg) * 256 + threadIdx.x, ei2, cursor, csr_w);
    }
}

// ---------------- bf16 MFMA GEMM body, BK=32 (16KB LDS; used inside fused_k) ----
__device__ __forceinline__ void gemm_body(int bx, int by, int tid,
                                          unsigned short* smem,
                                          const unsigned short* __restrict__ A,
                                          const unsigned short* __restrict__ Wt,
                                          const float* __restrict__ bias,
                                          unsigned short* __restrict__ C, int K) {
    const int N = HID_D;
    unsigned short* As = smem;            // 128*32
    unsigned short* Bs = smem + 4096;     // 128*32
    int lane = tid & 63;
    int w = tid >> 6;
    int wr = w >> 1, wc = w & 1;
    int row0 = bx * 128;
    int col0 = by * 128;
    floatx4 acc[4][4] = {};
    int lr = tid >> 2;
    int c8 = (tid & 3) * 8;
    const unsigned short* Ag = A + (size_t)row0 * K;
    const unsigned short* Bg = Wt + (size_t)col0 * K;

    for (int kt = 0; kt < K; kt += 32) {
#pragma unroll
        for (int l = 0; l < 2; ++l) {
            int r = l * 64 + lr;
            __builtin_amdgcn_global_load_lds(
                (const __attribute__((address_space(1))) void*)(Ag + (size_t)r * K + kt + c8),
                (__attribute__((address_space(3))) void*)(As + l * 2048 + tid * 8),
                16, 0, 0);
            __builtin_amdgcn_global_load_lds(
                (const __attribute__((address_space(1))) void*)(Bg + (size_t)r * K + kt + c8),
                (__attribute__((address_space(3))) void*)(Bs + l * 2048 + tid * 8),
                16, 0, 0);
        }
        __syncthreads();
        short8 af[4], bf[4];
        int q8 = (lane >> 4) * 8;
#pragma unroll
        for (int i = 0; i < 4; ++i) {
            int m = wr * 64 + i * 16 + (lane & 15);
            af[i] = *(const short8*)&As[m * 32 + q8];
            int n = wc * 64 + i * 16 + (lane & 15);
            bf[i] = *(const short8*)&Bs[n * 32 + q8];
        }
#pragma unroll
        for (int i = 0; i < 4; ++i)
#pragma unroll
            for (int j = 0; j < 4; ++j)
                acc[i][j] = __builtin_amdgcn_mfma_f32_16x16x32_bf16(af[i], bf[j], acc[i][j], 0, 0, 0);
        __syncthreads();
    }
    int q = lane >> 4;
    int cn = lane & 15;
#pragma unroll
    for (int j = 0; j < 4; ++j) {
        int col = col0 + wc * 64 + j * 16 + cn;
        float bv = bias[col];
#pragma unroll
        for (int i = 0; i < 4; ++i) {
            int rowb = row0 + wr * 64 + i * 16 + q * 4;
#pragma unroll
            for (int r = 0; r < 4; ++r) {
                float vv = fmaxf(acc[i][j][r] + bv, 0.f);
                C[(size_t)(rowb + r) * N + col] = f2bf(vv);
            }
        }
    }
}

// ---------------- bf16 MFMA GEMM body, BK=64 (32KB LDS; unfused gemm stages) ----
__device__ __forceinline__ void gemm_body64(int bx, int by, int tid,
                                            unsigned short* smem,
                                            const unsigned short* __restrict__ A,
                                            const unsigned short* __restrict__ Wt,
                                            const float* __restrict__ bias,
                                            unsigned short* __restrict__ C, int K) {
    const int N = HID_D;
    unsigned short* As = smem;            // 128*64
    unsigned short* Bs = smem + 8192;     // 128*64
    int lane = tid & 63;
    int w = tid >> 6;
    int wr = w >> 1, wc = w & 1;
    int row0 = bx * 128;
    int col0 = by * 128;
    floatx4 acc[4][4] = {};
    int lr = tid >> 3;                    // 0..31
    int c8 = (tid & 7) * 8;               // 0..56
    const unsigned short* Ag = A + (size_t)row0 * K;
    const unsigned short* Bg = Wt + (size_t)col0 * K;

    for (int kt = 0; kt < K; kt += 64) {
#pragma unroll
        for (int l = 0; l < 4; ++l) {
            int r = l * 32 + lr;
            __builtin_amdgcn_global_load_lds(
                (const __attribute__((address_space(1))) void*)(Ag + (size_t)r * K + kt + c8),
                (__attribute__((address_space(3))) void*)(As + l * 2048 + tid * 8),
                16, 0, 0);
            __builtin_amdgcn_global_load_lds(
                (const __attribute__((address_space(1))) void*)(Bg + (size_t)r * K + kt + c8),
                (__attribute__((address_space(3))) void*)(Bs + l * 2048 + tid * 8),
                16, 0, 0);
        }
        __syncthreads();
#pragma unroll
        for (int kb = 0; kb < 2; ++kb) {
            short8 af[4], bf[4];
            int q8 = kb * 32 + (lane >> 4) * 8;
#pragma unroll
            for (int i = 0; i < 4; ++i) {
                int m = wr * 64 + i * 16 + (lane & 15);
                af[i] = *(const short8*)&As[m * 64 + q8];
                int n = wc * 64 + i * 16 + (lane & 15);
                bf[i] = *(const short8*)&Bs[n * 64 + q8];
            }
#pragma unroll
            for (int i = 0; i < 4; ++i)
#pragma unroll
                for (int j = 0; j < 4; ++j)
                    acc[i][j] = __builtin_amdgcn_mfma_f32_16x16x32_bf16(af[i], bf[j], acc[i][j], 0, 0, 0);
        }
        __syncthreads();
    }
    int q = lane >> 4;
    int cn = lane & 15;
#pragma unroll
    for (int j = 0; j < 4; ++j) {
        int col = col0 + wc * 64 + j * 16 + cn;
        float bv = bias[col];
#pragma unroll
        for (int i = 0; i < 4; ++i) {
            int rowb = row0 + wr * 64 + i * 16 + q * 4;
#pragma unroll
            for (int r = 0; r < 4; ++r) {
                float vv = fmaxf(acc[i][j][r] + bv, 0.f);
                C[(size_t)(rowb + r) * N + col] = f2bf(vv);
            }
        }
    }
}

// two independent gemms (different graphs) in one launch, BK=64
__launch_bounds__(256)
__global__ void gemm_pair(const unsigned short* __restrict__ A1,
                          const unsigned short* __restrict__ W1,
                          const float* __restrict__ b1,
                          unsigned short* __restrict__ C1, int K1,
                          const unsigned short* __restrict__ A2,
                          const unsigned short* __restrict__ W2,
                          const float* __restrict__ b2,
                          unsigned short* __restrict__ C2, int K2) {
    __shared__ unsigned short smem[16384];
    int b = blockIdx.x;
    if (b < NGEMM) {
        gemm_body64(b % 157, b / 157, threadIdx.x, smem, A1, W1, b1, C1, K1);
    } else {
        b -= NGEMM;
        gemm_body64(b % 157, b / 157, threadIdx.x, smem, A2, W2, b2, C2, K2);
    }
}

// ---------------- fused: gemm (BK=32) blocks first, agg blocks after ------------
template<int LPR, int NSLAB>
__launch_bounds__(256)
__global__ void fused_k(const unsigned short* __restrict__ A,
                        const unsigned short* __restrict__ Wt,
                        const float* __restrict__ bias,
                        unsigned short* __restrict__ C, int K,
                        const unsigned short* __restrict__ x,
                        const int* __restrict__ row_start,
                        const int* __restrict__ csr_src,
                        unsigned short* __restrict__ h, int n0, int nGemm) {
    __shared__ unsigned short smem[8192];
    int b = blockIdx.x;
    if (b < nGemm) {
        gemm_body(b % 157, b / 157, threadIdx.x, smem, A, Wt, bias, C, K);
    } else {
        agg_body<LPR, NSLAB>(b - nGemm, threadIdx.x, x, row_start, csr_src, h, n0);
    }
}

// ---------------- final linear [M,512]bf16 @ [512,2]fp32 + b ----------------
__device__ __forceinline__ void lin_body(int bb, int tid, const unsigned short* __restrict__ A,
                                         const float* __restrict__ w, const float* __restrict__ b,
                                         float* __restrict__ o, int M) {
    int wave = tid >> 6;
    int lane = tid & 63;
    int row = bb * 4 + wave;
    if (row >= M) return;
    const uint4* Ar = (const uint4*)(A + (size_t)row * 512);
    uint4 u = Ar[lane];
    float f[8];
    f[0] = bflo(u.x); f[1] = bfhi(u.x); f[2] = bflo(u.y); f[3] = bfhi(u.y);
    f[4] = bflo(u.z); f[5] = bfhi(u.z); f[6] = bflo(u.w); f[7] = bfhi(u.w);
    float s0 = 0.f, s1 = 0.f;
#pragma unroll
    for (int j = 0; j < 8; ++j) {
        int base = (lane * 8 + j) * 2;
        s0 = fmaf(f[j], w[base + 0], s0);
        s1 = fmaf(f[j], w[base + 1], s1);
    }
#pragma unroll
    for (int off = 32; off > 0; off >>= 1) {
        s0 += __shfl_down(s0, off, 64);
        s1 += __shfl_down(s1, off, 64);
    }
    if (lane == 0) { o[row * 2] = s0 + b[0]; o[row * 2 + 1] = s1 + b[1]; }
}

// s10: G32(g2) || lin(g1)
__launch_bounds__(256)
__global__ void fused_gemmlin(const unsigned short* __restrict__ A,
                              const unsigned short* __restrict__ Wt,
                              const float* __restrict__ bias,
                              unsigned short* __restrict__ C, int K,
                              const unsigned short* __restrict__ L,
                              const float* __restrict__ lw, const float* __restrict__ lb,
                              float* __restrict__ o) {
    __shared__ unsigned short smem[16384];
    int b = blockIdx.x;
    if (b < NGEMM) {
        gemm_body64(b % 157, b / 157, threadIdx.x, smem, A, Wt, bias, C, K);
    } else {
        lin_body(b - NGEMM, threadIdx.x, L, lw, lb, o, N1);
    }
}

// s11: lin(g2) + dist + hist fused
__global__ void lin_dist_kernel(const unsigned short* __restrict__ A,
                                const float* __restrict__ w, const float* __restrict__ b,
                                const float* __restrict__ o1,
                                float* __restrict__ o2out,
                                float* __restrict__ dist, int* __restrict__ hist) {
    int tid = threadIdx.x;
    int wave = tid >> 6;
    int lane = tid & 63;
    int row = blockIdx.x * 4 + wave;
    if (row >= N1) return;
    const uint4* Ar = (const uint4*)(A + (size_t)row * 512);
    uint4 u = Ar[lane];
    float f[8];
    f[0] = bflo(u.x); f[1] = bfhi(u.x); f[2] = bflo(u.y); f[3] = bfhi(u.y);
    f[4] = bflo(u.z); f[5] = bfhi(u.z); f[6] = bflo(u.w); f[7] = bfhi(u.w);
    float s0 = 0.f, s1 = 0.f;
#pragma unroll
    for (int j = 0; j < 8; ++j) {
        int base = (lane * 8 + j) * 2;
        s0 = fmaf(f[j], w[base + 0], s0);
        s1 = fmaf(f[j], w[base + 1], s1);
    }
#pragma unroll
    for (int off = 32; off > 0; off >>= 1) {
        s0 += __shfl_down(s0, off, 64);
        s1 += __shfl_down(s1, off, 64);
    }
    if (lane == 0) {
        float vx = s0 + b[0], vy = s1 + b[1];
        o2out[row * 2] = vx; o2out[row * 2 + 1] = vy;
        float2 a = ((const float2*)o1)[row];
        float d0 = a.x - vx + 1e-6f, d1 = a.y - vy + 1e-6f;
        float d = sqrtf(d0 * d0 + d1 * d1);
        dist[row] = d;
        atomicAdd(&hist[__float_as_uint(d) >> 19], 1);
    }
}

// ---------------- radix-select top-k ----------------
__global__ void selk_kernel(const int* __restrict__ hist, int* __restrict__ selout) {
    __shared__ int tile[256];
    int t = threadIdx.x;
    int running = 0;
    for (int tb = 0; tb < 16; ++tb) {
        int idx = 4095 - (tb * 256 + t);
        int v = hist[idx];
        tile[t] = v;
        __syncthreads();
        for (int off = 1; off < 256; off <<= 1) {
            int x = (t >= off) ? tile[t - off] : 0;
            __syncthreads();
            tile[t] += x;
            __syncthreads();
        }
        int incl = running + tile[t];
        if (incl >= TOPK && incl - v < TOPK) selout[0] = idx;
        running += tile[255];
        __syncthreads();
        if (running >= TOPK) break;
    }
}

__global__ void compact_kernel(const float* __restrict__ dist, const int* __restrict__ selout,
                               int* __restrict__ nc, float* __restrict__ cd, int* __restrict__ ci) {
    int i = blockIdx.x * blockDim.x + threadIdx.x;
    if (i >= N1) return;
    float d = dist[i];
    int b = (int)(__float_as_uint(d) >> 19);
    if (b >= selout[0]) {
        int p = atomicAdd(nc, 1);
        cd[p] = d;
        ci[p] = i;
    }
}

#define CCH 2048
__global__ void rankc_kernel(const float* __restrict__ cd, const int* __restrict__ ci,
                             const int* __restrict__ nc_p, float* __restrict__ vals) {
    __shared__ float ds[CCH];
    __shared__ int   di_[CCH];
    int nc = *nc_p;
    if (blockIdx.x * 256 >= nc) return;      // empty block: skip entirely
    int t = threadIdx.x;
    int q = blockIdx.x * 256 + t;
    float dq = 0.f; int iq = 0;
    if (q < nc) { dq = cd[q]; iq = ci[q]; }
    int cnt = 0;
    for (int c0 = 0; c0 < nc; c0 += CCH) {
        int lim = min(CCH, nc - c0);
        for (int j = t; j < lim; j += 256) { ds[j] = cd[c0 + j]; di_[j] = ci[c0 + j]; }
        __syncthreads();
        if (q < nc) {
            for (int j = 0; j < lim; ++j) {
                float dj = ds[j];
                cnt += (dj > dq) || (dj == dq && di_[j] < iq);
            }
        }
        __syncthreads();
    }
    if (q < nc && cnt < TOPK) vals[cnt] = dq;
}

// ---------------- head MLP (fc1 split 4-way) ----------------
__launch_bounds__(512)
__global__ void head_kernel(const float* __restrict__ vals,
                            const float* __restrict__ fc1_w, const float* __restrict__ fc1_b,
                            const float* __restrict__ ln1_g, const float* __restrict__ ln1_b,
                            const float* __restrict__ fc2_w, const float* __restrict__ fc2_b,
                            const float* __restrict__ ln2_g, const float* __restrict__ ln2_b,
                            const float* __restrict__ fc3_w, const float* __restrict__ fc3_b,
                            float* __restrict__ out) {
    __shared__ float sv[TOPK];
    __shared__ float a1[128];
    __shared__ float red[512];
    __shared__ float s_m, s_r;
    int t = threadIdx.x;
    for (int i = t; i < TOPK; i += 512) sv[i] = vals[i];
    __syncthreads();
    // fc1: 4 groups of 128 threads, each covers 250 of the j range
    int g = t >> 7, c = t & 127;
    float part = 0.f;
    for (int j = g * 250; j < g * 250 + 250; ++j)
        part = fmaf(sv[j], fc1_w[j * 128 + c], part);
    red[t] = part;
    __syncthreads();
    float h1 = 0.f;
    if (t < 128) h1 = fc1_b[t] + red[t] + red[t + 128] + red[t + 256] + red[t + 384];
    __syncthreads();
    red[t] = (t < 128) ? h1 : 0.f; __syncthreads();
    for (int s = 256; s > 0; s >>= 1) { if (t < s) red[t] += red[t + s]; __syncthreads(); }
    if (t == 0) s_m = red[0] / 128.f;
    __syncthreads();
    float m1 = s_m;
    float dv = (t < 128) ? (h1 - m1) : 0.f;
    red[t] = dv * dv; __syncthreads();
    for (int s = 256; s > 0; s >>= 1) { if (t < s) red[t] += red[t + s]; __syncthreads(); }
    if (t == 0) s_r = rsqrtf(red[0] / 128.f + 1e-5f);
    __syncthreads();
    float r1 = s_r;
    if (t < 128) a1[t] = fmaxf((h1 - m1) * r1 * ln1_g[t] + ln1_b[t], 0.f);
    __syncthreads();
    float h2 = fc2_b[t];
    for (int j = 0; j < 128; ++j) h2 = fmaf(a1[j], fc2_w[j * 512 + t], h2);
    red[t] = h2; __syncthreads();
    for (int s = 256; s > 0; s >>= 1) { if (t < s) red[t] += red[t + s]; __syncthreads(); }
    if (t == 0) s_m = red[0] / 512.f;
    __syncthreads();
    float m2 = s_m;
    float d2 = h2 - m2;
    red[t] = d2 * d2; __syncthreads();
    for (int s = 256; s > 0; s >>= 1) { if (t < s) red[t] += red[t + s]; __syncthreads(); }
    if (t == 0) s_r = rsqrtf(red[0] / 512.f + 1e-5f);
    __syncthreads();
    float r2 = s_r;
    float y2 = fmaxf((h2 - m2) * r2 * ln2_g[t] + ln2_b[t], 0.f);
    red[t] = y2 * fc3_w[t]; __syncthreads();
    for (int s = 256; s > 0; s >>= 1) { if (t < s) red[t] += red[t + s]; __syncthreads(); }
    if (t == 0) out[0] = 1.f / (1.f + expf(-(red[0] + fc3_b[0])));
}

extern "C" void kernel_launch(void* const* d_in, const int* in_sizes, int n_in,
                              void* d_out, int out_size, void* d_ws, size_t ws_size,
                              hipStream_t stream) {
    const float* x1   = (const float*)d_in[0];
    const int*   ei1  = (const int*)d_in[1];
    const float* x2   = (const float*)d_in[2];
    const int*   ei2  = (const int*)d_in[3];
    const float* w11  = (const float*)d_in[4];
    const float* b11  = (const float*)d_in[5];
    const float* w12  = (const float*)d_in[6];
    const float* b12  = (const float*)d_in[7];
    const float* w21  = (const float*)d_in[8];
    const float* b21  = (const float*)d_in[9];
    const float* w22  = (const float*)d_in[10];
    const float* b22  = (const float*)d_in[11];
    const float* w31  = (const float*)d_in[12];
    const float* b31  = (const float*)d_in[13];
    const float* w32  = (const float*)d_in[14];
    const float* b32  = (const float*)d_in[15];
    const float* lw   = (const float*)d_in[16];
    const float* lb   = (const float*)d_in[17];
    const float* fc1w = (const float*)d_in[18];
    const float* fc1b = (const float*)d_in[19];
    const float* ln1g = (const float*)d_in[20];
    const float* ln1b = (const float*)d_in[21];
    const float* fc2w = (const float*)d_in[22];
    const float* fc2b = (const float*)d_in[23];
    const float* ln2g = (const float*)d_in[24];
    const float* ln2b = (const float*)d_in[25];
    const float* fc3w = (const float*)d_in[26];
    const float* fc3b = (const float*)d_in[27];

    char* ws = (char*)d_ws;
    size_t off = 0;
    auto alloc = [&](size_t bytes) -> void* {
        void* p = ws + off;
        off += (bytes + 255) & ~(size_t)255;
        return p;
    };
    unsigned short* XB  = (unsigned short*)alloc((size_t)NT * FIN_D * 2);  // batched inputs
    unsigned short* H0a = (unsigned short*)alloc((size_t)MP1 * HID_D * 2);
    unsigned short* H1a = (unsigned short*)alloc((size_t)MP1 * HID_D * 2);
    unsigned short* H0b = (unsigned short*)alloc((size_t)MP1 * HID_D * 2);
    unsigned short* H1b = (unsigned short*)alloc((size_t)MP1 * HID_D * 2);
    unsigned short* wt11 = (unsigned short*)alloc((size_t)HID_D * FIN_D * 2);
    unsigned short* wt12 = (unsigned short*)alloc((size_t)HID_D * HID_D * 2);
    unsigned short* wt21 = (unsigned short*)alloc((size_t)HID_D * HID_D * 2);
    unsigned short* wt22 = (unsigned short*)alloc((size_t)HID_D * HID_D * 2);
    unsigned short* wt31 = (unsigned short*)alloc((size_t)HID_D * HID_D * 2);
    unsigned short* wt32 = (unsigned short*)alloc((size_t)HID_D * HID_D * 2);
    float* o         = (float*)alloc((size_t)NT * 2 * 4);
    float* dist      = (float*)alloc((size_t)N1 * 4);
    float* vals      = (float*)alloc((size_t)TOPK * 4);
    int*   row_start = (int*)alloc((size_t)(NT + 1) * 4);
    int*   cursor    = (int*)alloc((size_t)NT * 4);
    int*   deg       = (int*)alloc((size_t)NT * 4);
    int*   scan_tmp  = (int*)alloc((size_t)NT * 4);
    int*   bsum      = (int*)alloc((size_t)SCAN_NB * 4);
    int*   boff      = (int*)alloc((size_t)SCAN_NB * 4);
    int*   csr_src   = (int*)alloc((size_t)ET * 4);
    int*   selblk    = (int*)alloc((size_t)(4096 + 64) * 4);  // hist + nc
    int*   hist      = selblk;
    int*   nc        = selblk + 4096;
    int*   selout    = (int*)alloc(2 * 4);
    float* cd        = (float*)alloc((size_t)N1 * 4);
    int*   ci        = (int*)alloc((size_t)N1 * 4);

    // ---- fused prep: hist + all conversions in one launch ----
    hipMemsetAsync(deg, 0, NT * sizeof(int), stream);
    hipMemsetAsync(selblk, 0, (4096 + 64) * sizeof(int), stream);
    prep_kernel<<<16408, 256, 0, stream>>>(ei1, ei2, deg,
                                           w11, wt11, w12, wt12, w21, wt21,
                                           w22, wt22, w31, wt31, w32, wt32,
                                           x1, x2, XB);
    scan1_kernel<<<SCAN_NB, 256, 0, stream>>>(deg, scan_tmp, bsum);
    scan2_kernel<<<1, 256, 0, stream>>>(bsum, boff, row_start);
    scan3_kernel<<<SCAN_NB, 256, 0, stream>>>(scan_tmp, boff, row_start, cursor);
    fill1_kernel<<<(E1 + 255) / 256, 256, 0, stream>>>(ei1, cursor, csr_src);

    // ---- staggered two-graph pipeline ----
    const unsigned short* XBg2 = XB + (size_t)N1 * FIN_D;
    int aggB256 = 8 * GRPS1;                 // 2504
    int aggB512 = 16 * GRPS1;                // 5008
    int fillB   = (E1 + 255) / 256;          // 2500

    // s1: agg1(g1) || fill(g2)
    fused_aggfill<<<aggB256 + fillB, 256, 0, stream>>>(XB, row_start, csr_src, H0a,
                                                       ei2, cursor, csr_src, aggB256);
    // s2: G11(g1) || agg1(g2)
    fused_k<32, 8><<<NGEMM + aggB256, 256, 0, stream>>>(H0a, wt11, b11, H1a, FIN_D,
                                                        XBg2, row_start, csr_src, H0b, N1, NGEMM);
    // s3: G12(g1) + G11(g2) merged (BK=64)
    gemm_pair<<<2 * NGEMM, 256, 0, stream>>>(H1a, wt12, b12, H0a, HID_D,
                                             H0b, wt11, b11, H1b, FIN_D);
    // s4: G12(g2) || agg2(g1)
    fused_k<64, 16><<<NGEMM + aggB512, 256, 0, stream>>>(H1b, wt12, b12, H0b, HID_D,
                                                         H0a, row_start, csr_src, H1a, 0, NGEMM);
    // s5: G21(g1) || agg2(g2)
    fused_k<64, 16><<<NGEMM + aggB512, 256, 0, stream>>>(H1a, wt21, b21, H0a, HID_D,
                                                         H0b, row_start, csr_src, H1b, N1, NGEMM);
    // s6: G22(g1) + G21(g2) merged (BK=64)
    gemm_pair<<<2 * NGEMM, 256, 0, stream>>>(H0a, wt22, b22, H1a, HID_D,
                                             H1b, wt21, b21, H0b, HID_D);
    // s7: G22(g2) || agg3(g1)
    fused_k<64, 16><<<NGEMM + aggB512, 256, 0, stream>>>(H0b, wt22, b22, H1b, HID_D,
                                                         H1a, row_start, csr_src, H0a, 0, NGEMM);
    // s8: G31(g1) || agg3(g2)
    fused_k<64, 16><<<NGEMM + aggB512, 256, 0, stream>>>(H0a, wt31, b31, H1a, HID_D,
                                                         H1b, row_start, csr_src, H0b, N1, NGEMM);
    // s9: G32(g1) + G31(g2) merged (BK=64)
    gemm_pair<<<2 * NGEMM, 256, 0, stream>>>(H1a, wt32, b32, H0a, HID_D,
                                             H0b, wt31, b31, H1b, HID_D);
    // s10: G32(g2) || lin(g1)  (BK=64)
    fused_gemmlin<<<NGEMM + (N1 + 3) / 4, 256, 0, stream>>>(H1b, wt32, b32, H0b, HID_D,
                                                            H0a, lw, lb, o);
    // s11: lin(g2) + dist + hist fused
    lin_dist_kernel<<<(N1 + 3) / 4, 256, 0, stream>>>(H0b, lw, lb, o,
                                                      o + 2 * (size_t)N1, dist, hist);

    // ---- radix-select top-k + head ----
    selk_kernel<<<1, 256, 0, stream>>>(hist, selout);
    compact_kernel<<<(N1 + 255) / 256, 256, 0, stream>>>(dist, selout, nc, cd, ci);
    rankc_kernel<<<(N1 + 255) / 256, 256, 0, stream>>>(cd, ci, nc, vals);
    head_kernel<<<1, 512, 0, stream>>>(vals, fc1w, fc1b, ln1g, ln1b,
                                       fc2w, fc2b, ln2g, ln2b, fc3w, fc3b,
                                       (float*)d_out);
}

// Round 11
// 969.292 us; speedup vs baseline: 1.3226x; 1.0318x over previous
//
#include <hip/hip_runtime.h>
#include <hip/hip_bf16.h>
#include <math.h>

#define N1      20000          // nodes per graph
#define NT      40000          // both graphs
#define E1      640000         // edges per graph
#define ET      1280000
#define FIN_D   256
#define HID_D   512
#define TOPK    1000
#define MP1     20096          // 157 * 128 (padded M per graph)
#define SCAN_NB 157            // ceil(40000/256)
#define NGEMM   628            // 157 x 4 blocks per 20096x512 gemm
#define AGG256  2500           // 4 slabs * 625 groups (32 nodes/group)
#define AGG512  5000           // 8 slabs * 625 groups

typedef __attribute__((ext_vector_type(8))) short short8;
typedef __attribute__((ext_vector_type(4))) float floatx4;
typedef __attribute__((ext_vector_type(2))) float floatx2;
typedef unsigned int uintx4 __attribute__((ext_vector_type(4)));

__device__ __forceinline__ unsigned short f2bf(float f) {
    union { __hip_bfloat16 h; unsigned short u; } cv;
    cv.h = __float2bfloat16(f);
    return cv.u;
}
__device__ __forceinline__ float bflo(unsigned int u) {
    union { unsigned int i; float f; } c; c.i = u << 16; return c.f;
}
__device__ __forceinline__ float bfhi(unsigned int u) {
    union { unsigned int i; float f; } c; c.i = u & 0xffff0000u; return c.f;
}

// ---------------- fused prep: hist + 6x convw + 2x convx (bf16 + fp8) ----------
__device__ __forceinline__ void convw_body(int bl, int K, float* tile /*32x33*/,
                                           const float* __restrict__ W,
                                           unsigned short* __restrict__ Wt) {
    int kb = K / 32;
    int k0 = (bl % kb) * 32, n0 = (bl / kb) * 32;
    int tx = threadIdx.x & 31, ty = threadIdx.x >> 5;
    for (int r = ty; r < 32; r += 8) tile[r * 33 + tx] = W[(size_t)(k0 + r) * HID_D + n0 + tx];
    __syncthreads();
    for (int r = ty; r < 32; r += 8)
        Wt[(size_t)(n0 + r) * K + k0 + tx] = f2bf(tile[tx * 33 + r]);
}
__device__ __forceinline__ void convx_body(int i, const float* __restrict__ x,
                                           unsigned short* __restrict__ xb,
                                           unsigned char* __restrict__ x8) {
    float4 f = ((const float4*)x)[i];
    ushort4 u;
    u.x = f2bf(f.x); u.y = f2bf(f.y); u.z = f2bf(f.z); u.w = f2bf(f.w);
    ((ushort4*)xb)[i] = u;
    int p = __builtin_amdgcn_cvt_pk_fp8_f32(f.x, f.y, 0, false);
    p = __builtin_amdgcn_cvt_pk_fp8_f32(f.z, f.w, p, true);
    ((unsigned int*)x8)[i] = (unsigned int)p;
}

__launch_bounds__(256)
__global__ void prep_kernel(const int* __restrict__ ei1, const int* __restrict__ ei2,
                            int* __restrict__ deg,
                            const float* w11, unsigned short* wt11,
                            const float* w12, unsigned short* wt12,
                            const float* w21, unsigned short* wt21,
                            const float* w22, unsigned short* wt22,
                            const float* w31, unsigned short* wt31,
                            const float* w32, unsigned short* wt32,
                            const float* x1, const float* x2,
                            unsigned short* xb, unsigned char* x8) {
    __shared__ float tile[32 * 33];
    int b = blockIdx.x;
    if (b < 5000) {                       // hist, both graphs
        int e = b * 256 + threadIdx.x;
        if (e < ET) {
            int d = (e < E1) ? ei1[E1 + e] : (ei2[E1 + (e - E1)] + N1);
            atomicAdd(&deg[d], 1);
        }
    } else if (b < 5128)  { convw_body(b - 5000, FIN_D, tile, w11, wt11); }
    else if (b < 5384)    { convw_body(b - 5128, HID_D, tile, w12, wt12); }
    else if (b < 5640)    { convw_body(b - 5384, HID_D, tile, w21, wt21); }
    else if (b < 5896)    { convw_body(b - 5640, HID_D, tile, w22, wt22); }
    else if (b < 6152)    { convw_body(b - 5896, HID_D, tile, w31, wt31); }
    else if (b < 6408)    { convw_body(b - 6152, HID_D, tile, w32, wt32); }
    else if (b < 11408)   { convx_body((b - 6408) * 256 + threadIdx.x, x1, xb, x8); }
    else                  { convx_body((b - 11408) * 256 + threadIdx.x, x2,
                                       xb + (size_t)N1 * FIN_D, x8 + (size_t)N1 * FIN_D); }
}

// ---------------- CSR scans + fills ----------------
__global__ void scan1_kernel(const int* __restrict__ deg, int* __restrict__ tmp,
                             int* __restrict__ bsum) {
    __shared__ int tile[256];
    int t = threadIdx.x;
    int i = blockIdx.x * 256 + t;
    int v = (i < NT) ? deg[i] : 0;
    tile[t] = v;
    __syncthreads();
    for (int off = 1; off < 256; off <<= 1) {
        int x = (t >= off) ? tile[t - off] : 0;
        __syncthreads();
        tile[t] += x;
        __syncthreads();
    }
    if (i < NT) tmp[i] = tile[t] - v;
    if (t == 255) bsum[blockIdx.x] = tile[255];
}

__global__ void scan2_kernel(const int* __restrict__ bsum, int* __restrict__ boff,
                             int* __restrict__ row_start) {
    __shared__ int tile[256];
    int t = threadIdx.x;
    int v = (t < SCAN_NB) ? bsum[t] : 0;
    tile[t] = v;
    __syncthreads();
    for (int off = 1; off < 256; off <<= 1) {
        int x = (t >= off) ? tile[t - off] : 0;
        __syncthreads();
        tile[t] += x;
        __syncthreads();
    }
    if (t < SCAN_NB) boff[t] = tile[t] - v;
    if (t == 255) row_start[NT] = tile[255];
}

__global__ void scan3_kernel(const int* __restrict__ tmp, const int* __restrict__ boff,
                             int* __restrict__ row_start, int* __restrict__ cursor) {
    int i = blockIdx.x * 256 + threadIdx.x;
    if (i < NT) {
        int rs = tmp[i] + boff[blockIdx.x];
        row_start[i] = rs;
        cursor[i] = rs;
    }
}

__global__ void fill1_kernel(const int* __restrict__ ei1, int* __restrict__ cursor,
                             int* __restrict__ csr_src) {
    int e = blockIdx.x * 256 + threadIdx.x;
    if (e < E1) {
        int s = ei1[e], d = ei1[E1 + e];
        int p = atomicAdd(&cursor[d], 1);
        csr_src[p] = s;
    }
}

__device__ __forceinline__ void fill_g2_body(int e, const int* __restrict__ ei2,
                                             int* __restrict__ cursor, int* __restrict__ csr_src) {
    if (e < E1) {
        int s = ei2[e] + N1, d = ei2[E1 + e] + N1;
        int p = atomicAdd(&cursor[d], 1);
        csr_src[p] = s;
    }
}

// ---------------- fp8 GIN aggregation body ------------------------------------
// Row = D fp8 bytes. Slab = 64B (8 lanes x uint2). 8 lanes/node, 32 nodes/block.
// Gather: 1 line per edge per pass; D/64 passes. Accum fp32, h output bf16
// (identical 16B/lane store pattern as the proven bf16 agg).
#define ACCF8(u) do { \
    floatx2 a0 = __builtin_amdgcn_cvt_pk_f32_fp8((int)(u).x, false); \
    floatx2 a1 = __builtin_amdgcn_cvt_pk_f32_fp8((int)(u).x, true);  \
    floatx2 a2 = __builtin_amdgcn_cvt_pk_f32_fp8((int)(u).y, false); \
    floatx2 a3 = __builtin_amdgcn_cvt_pk_f32_fp8((int)(u).y, true);  \
    acc[0] += a0.x; acc[1] += a0.y; acc[2] += a1.x; acc[3] += a1.y; \
    acc[4] += a2.x; acc[5] += a2.y; acc[6] += a3.x; acc[7] += a3.y; } while (0)

template<int LPR2, int NSLAB>   // LPR2 = uint2 per fp8 row (D/8); NSLAB = D/64
__device__ __forceinline__ void agg8_body(int ab, int tid,
                                          const unsigned char* __restrict__ x8,
                                          const int* __restrict__ row_start,
                                          const int* __restrict__ csr_src,
                                          unsigned short* __restrict__ h, int n0) {
    int slab = ab & (NSLAB - 1);               // XCD-pinned (blockIdx round-robin)
    int grp  = ab / NSLAB;                     // 0..624
    int node = grp * 32 + (tid >> 3);          // exact: 625*32 = 20000
    int lanec = tid & 7;
    int chunk = slab * 8 + lanec;              // uint2 index within fp8 row
    const uint2* Xc = (const uint2*)x8 + chunk;
    uint2 v = Xc[(size_t)node * LPR2];
    float acc[8] = {};
    ACCF8(v);                                  // self term (fp8)
    int nid = n0 + node;
    int s = row_start[nid], e = row_start[nid + 1];
    int p = s;
    for (; p + 8 <= e; p += 8) {
        int m0 = csr_src[p + 0] - n0, m1 = csr_src[p + 1] - n0;
        int m2 = csr_src[p + 2] - n0, m3 = csr_src[p + 3] - n0;
        int m4 = csr_src[p + 4] - n0, m5 = csr_src[p + 5] - n0;
        int m6 = csr_src[p + 6] - n0, m7 = csr_src[p + 7] - n0;
        uint2 u0 = Xc[(size_t)m0 * LPR2];
        uint2 u1 = Xc[(size_t)m1 * LPR2];
        uint2 u2 = Xc[(size_t)m2 * LPR2];
        uint2 u3 = Xc[(size_t)m3 * LPR2];
        uint2 u4 = Xc[(size_t)m4 * LPR2];
        uint2 u5 = Xc[(size_t)m5 * LPR2];
        uint2 u6 = Xc[(size_t)m6 * LPR2];
        uint2 u7 = Xc[(size_t)m7 * LPR2];
        ACCF8(u0); ACCF8(u1); ACCF8(u2); ACCF8(u3);
        ACCF8(u4); ACCF8(u5); ACCF8(u6); ACCF8(u7);
    }
    for (; p + 2 <= e; p += 2) {
        int ma = csr_src[p + 0] - n0, mb = csr_src[p + 1] - n0;
        uint2 u0 = Xc[(size_t)ma * LPR2];
        uint2 u1 = Xc[(size_t)mb * LPR2];
        ACCF8(u0); ACCF8(u1);
    }
    if (p < e) {
        int ma = csr_src[p] - n0;
        uint2 u0 = Xc[(size_t)ma * LPR2];
        ACCF8(u0);
    }
    // bf16 output, 16B/lane, 128B contiguous per node (proven-sane store pattern)
    uintx4 o;
    o.x = (unsigned)f2bf(acc[0]) | ((unsigned)f2bf(acc[1]) << 16);
    o.y = (unsigned)f2bf(acc[2]) | ((unsigned)f2bf(acc[3]) << 16);
    o.z = (unsigned)f2bf(acc[4]) | ((unsigned)f2bf(acc[5]) << 16);
    o.w = (unsigned)f2bf(acc[6]) | ((unsigned)f2bf(acc[7]) << 16);
    ((uintx4*)h)[(size_t)node * LPR2 + chunk] = o;
}

// ---------------- stage 1: agg1(g1) || fill(g2) --------------------------------
__launch_bounds__(256, 8)
__global__ void fused_aggfill(const unsigned char* __restrict__ x8,
                              const int* __restrict__ row_start,
                              const int* __restrict__ csr_src,
                              unsigned short* __restrict__ h,
                              const int* __restrict__ ei2,
                              int* __restrict__ cursor,
                              int* __restrict__ csr_w, int nAgg) {
    int b = blockIdx.x;
    if (b < nAgg) {
        agg8_body<32, 4>(b, threadIdx.x, x8, row_start, csr_src, h, 0);
    } else {
        fill_g2_body((b - nAgg) * 256 + threadIdx.x, ei2, cursor, csr_w);
    }
}

// ---------------- fp8 tile store (epilogue helper, coalesced via LDS) ----------
__device__ __forceinline__ void store_fp8_tile(int row0, int col0, int tid,
                                               unsigned short* smem,
                                               floatx4 acc[4][4], const float* __restrict__ bias,
                                               unsigned char* __restrict__ C8,
                                               int wr, int wc, int lane) {
    unsigned char* tile = (unsigned char*)smem;    // 128*128 = 16KB
    int q = lane >> 4, cn = lane & 15;
#pragma unroll
    for (int j = 0; j < 4; ++j) {
        int lcol = wc * 64 + j * 16 + cn;
        float bv = bias[col0 + lcol];
#pragma unroll
        for (int i = 0; i < 4; ++i) {
            int lrow = wr * 64 + i * 16 + q * 4;
#pragma unroll
            for (int r = 0; r < 4; ++r) {
                float vv = fmaxf(acc[i][j][r] + bv, 0.f);
                int t8 = __builtin_amdgcn_cvt_pk_fp8_f32(vv, 0.f, 0, false);
                tile[(lrow + r) * 128 + lcol] = (unsigned char)(t8 & 0xff);
            }
        }
    }
    __syncthreads();
    // 1024 uint4s, fully coalesced 16B stores; 128B-contiguous rows
#pragma unroll
    for (int it = 0; it < 4; ++it) {
        int idx = it * 256 + tid;
        int lrow = idx >> 3, c16 = idx & 7;
        *(uint4*)(C8 + (size_t)(row0 + lrow) * HID_D + col0 + c16 * 16) =
            *(const uint4*)(tile + lrow * 128 + c16 * 16);
    }
}

// ---------------- bf16 MFMA GEMM body, BK=32 (16KB LDS) ------------------------
__device__ __forceinline__ void gemm_body(int bx, int by, int tid,
                                          unsigned short* smem,
                                          const unsigned short* __restrict__ A,
                                          const unsigned short* __restrict__ Wt,
                                          const float* __restrict__ bias,
                                          unsigned short* __restrict__ C,
                                          unsigned char* __restrict__ C8, int K) {
    const int N = HID_D;
    unsigned short* As = smem;
    unsigned short* Bs = smem + 4096;
    int lane = tid & 63;
    int w = tid >> 6;
    int wr = w >> 1, wc = w & 1;
    int row0 = bx * 128;
    int col0 = by * 128;
    floatx4 acc[4][4] = {};
    int lr = tid >> 2;
    int c8 = (tid & 3) * 8;
    const unsigned short* Ag = A + (size_t)row0 * K;
    const unsigned short* Bg = Wt + (size_t)col0 * K;

    for (int kt = 0; kt < K; kt += 32) {
#pragma unroll
        for (int l = 0; l < 2; ++l) {
            int r = l * 64 + lr;
            __builtin_amdgcn_global_load_lds(
                (const __attribute__((address_space(1))) void*)(Ag + (size_t)r * K + kt + c8),
                (__attribute__((address_space(3))) void*)(As + l * 2048 + tid * 8),
                16, 0, 0);
            __builtin_amdgcn_global_load_lds(
                (const __attribute__((address_space(1))) void*)(Bg + (size_t)r * K + kt + c8),
                (__attribute__((address_space(3))) void*)(Bs + l * 2048 + tid * 8),
                16, 0, 0);
        }
        __syncthreads();
        short8 af[4], bf[4];
        int q8 = (lane >> 4) * 8;
#pragma unroll
        for (int i = 0; i < 4; ++i) {
            int m = wr * 64 + i * 16 + (lane & 15);
            af[i] = *(const short8*)&As[m * 32 + q8];
            int n = wc * 64 + i * 16 + (lane & 15);
            bf[i] = *(const short8*)&Bs[n * 32 + q8];
        }
#pragma unroll
        for (int i = 0; i < 4; ++i)
#pragma unroll
            for (int j = 0; j < 4; ++j)
                acc[i][j] = __builtin_amdgcn_mfma_f32_16x16x32_bf16(af[i], bf[j], acc[i][j], 0, 0, 0);
        __syncthreads();
    }
    if (C8) {   // fp8-only output (consumed exclusively by the next aggregation)
        store_fp8_tile(row0, col0, tid, smem, acc, bias, C8, wr, wc, lane);
        return;
    }
    int q = lane >> 4;
    int cn = lane & 15;
#pragma unroll
    for (int j = 0; j < 4; ++j) {
        int col = col0 + wc * 64 + j * 16 + cn;
        float bv = bias[col];
#pragma unroll
        for (int i = 0; i < 4; ++i) {
            int rowb = row0 + wr * 64 + i * 16 + q * 4;
#pragma unroll
            for (int r = 0; r < 4; ++r) {
                float vv = fmaxf(acc[i][j][r] + bv, 0.f);
                C[(size_t)(rowb + r) * N + col] = f2bf(vv);
            }
        }
    }
}

// ---------------- bf16 MFMA GEMM body, BK=64 (32KB LDS) ------------------------
__device__ __forceinline__ void gemm_body64(int bx, int by, int tid,
                                            unsigned short* smem,
                                            const unsigned short* __restrict__ A,
                                            const unsigned short* __restrict__ Wt,
                                            const float* __restrict__ bias,
                                            unsigned short* __restrict__ C,
                                            unsigned char* __restrict__ C8, int K) {
    const int N = HID_D;
    unsigned short* As = smem;
    unsigned short* Bs = smem + 8192;
    int lane = tid & 63;
    int w = tid >> 6;
    int wr = w >> 1, wc = w & 1;
    int row0 = bx * 128;
    int col0 = by * 128;
    floatx4 acc[4][4] = {};
    int lr = tid >> 3;
    int c8 = (tid & 7) * 8;
    const unsigned short* Ag = A + (size_t)row0 * K;
    const unsigned short* Bg = Wt + (size_t)col0 * K;

    for (int kt = 0; kt < K; kt += 64) {
#pragma unroll
        for (int l = 0; l < 4; ++l) {
            int r = l * 32 + lr;
            __builtin_amdgcn_global_load_lds(
                (const __attribute__((address_space(1))) void*)(Ag + (size_t)r * K + kt + c8),
                (__attribute__((address_space(3))) void*)(As + l * 2048 + tid * 8),
                16, 0, 0);
            __builtin_amdgcn_global_load_lds(
                (const __attribute__((address_space(1))) void*)(Bg + (size_t)r * K + kt + c8),
                (__attribute__((address_space(3))) void*)(Bs + l * 2048 + tid * 8),
                16, 0, 0);
        }
        __syncthreads();
#pragma unroll
        for (int kb = 0; kb < 2; ++kb) {
            short8 af[4], bf[4];
            int q8 = kb * 32 + (lane >> 4) * 8;
#pragma unroll
            for (int i = 0; i < 4; ++i) {
                int m = wr * 64 + i * 16 + (lane & 15);
                af[i] = *(const short8*)&As[m * 64 + q8];
                int n = wc * 64 + i * 16 + (lane & 15);
                bf[i] = *(const short8*)&Bs[n * 64 + q8];
            }
#pragma unroll
            for (int i = 0; i < 4; ++i)
#pragma unroll
                for (int j = 0; j < 4; ++j)
                    acc[i][j] = __builtin_amdgcn_mfma_f32_16x16x32_bf16(af[i], bf[j], acc[i][j], 0, 0, 0);
        }
        __syncthreads();
    }
    if (C8) {
        store_fp8_tile(row0, col0, tid, smem, acc, bias, C8, wr, wc, lane);
        return;
    }
    int q = lane >> 4;
    int cn = lane & 15;
#pragma unroll
    for (int j = 0; j < 4; ++j) {
        int col = col0 + wc * 64 + j * 16 + cn;
        float bv = bias[col];
#pragma unroll
        for (int i = 0; i < 4; ++i) {
            int rowb = row0 + wr * 64 + i * 16 + q * 4;
#pragma unroll
            for (int r = 0; r < 4; ++r) {
                float vv = fmaxf(acc[i][j][r] + bv, 0.f);
                C[(size_t)(rowb + r) * N + col] = f2bf(vv);
            }
        }
    }
}

// two independent gemms (different graphs) in one launch, BK=64
__launch_bounds__(256)
__global__ void gemm_pair(const unsigned short* __restrict__ A1,
                          const unsigned short* __restrict__ W1,
                          const float* __restrict__ b1,
                          unsigned short* __restrict__ C1, unsigned char* C81, int K1,
                          const unsigned short* __restrict__ A2,
                          const unsigned short* __restrict__ W2,
                          const float* __restrict__ b2,
                          unsigned short* __restrict__ C2, unsigned char* C82, int K2) {
    __shared__ unsigned short smem[16384];
    int b = blockIdx.x;
    if (b < NGEMM) {
        gemm_body64(b % 157, b / 157, threadIdx.x, smem, A1, W1, b1, C1, C81, K1);
    } else {
        b -= NGEMM;
        gemm_body64(b % 157, b / 157, threadIdx.x, smem, A2, W2, b2, C2, C82, K2);
    }
}

// ---------------- fused: gemm (BK=32) blocks first, fp8-agg blocks after --------
template<int LPR2, int NSLAB>
__launch_bounds__(256)
__global__ void fused_k(const unsigned short* __restrict__ A,
                        const unsigned short* __restrict__ Wt,
                        const float* __restrict__ bias,
                        unsigned short* __restrict__ C, unsigned char* C8, int K,
                        const unsigned char* __restrict__ x8,
                        const int* __restrict__ row_start,
                        const int* __restrict__ csr_src,
                        unsigned short* __restrict__ h, int n0, int nGemm) {
    __shared__ unsigned short smem[8192];
    int b = blockIdx.x;
    if (b < nGemm) {
        gemm_body(b % 157, b / 157, threadIdx.x, smem, A, Wt, bias, C, C8, K);
    } else {
        agg8_body<LPR2, NSLAB>(b - nGemm, threadIdx.x, x8, row_start, csr_src, h, n0);
    }
}

// ---------------- final linear [M,512]bf16 @ [512,2]fp32 + b ----------------
__device__ __forceinline__ void lin_body(int bb, int tid, const unsigned short* __restrict__ A,
                                         const float* __restrict__ w, const float* __restrict__ b,
                                         float* __restrict__ o, int M) {
    int wave = tid >> 6;
    int lane = tid & 63;
    int row = bb * 4 + wave;
    if (row >= M) return;
    const uint4* Ar = (const uint4*)(A + (size_t)row * 512);
    uint4 u = Ar[lane];
    float f[8];
    f[0] = bflo(u.x); f[1] = bfhi(u.x); f[2] = bflo(u.y); f[3] = bfhi(u.y);
    f[4] = bflo(u.z); f[5] = bfhi(u.z); f[6] = bflo(u.w); f[7] = bfhi(u.w);
    float s0 = 0.f, s1 = 0.f;
#pragma unroll
    for (int j = 0; j < 8; ++j) {
        int base = (lane * 8 + j) * 2;
        s0 = fmaf(f[j], w[base + 0], s0);
        s1 = fmaf(f[j], w[base + 1], s1);
    }
#pragma unroll
    for (int off = 32; off > 0; off >>= 1) {
        s0 += __shfl_down(s0, off, 64);
        s1 += __shfl_down(s1, off, 64);
    }
    if (lane == 0) { o[row * 2] = s0 + b[0]; o[row * 2 + 1] = s1 + b[1]; }
}

// s10: G32(g2) || lin(g1)
__launch_bounds__(256)
__global__ void fused_gemmlin(const unsigned short* __restrict__ A,
                              const unsigned short* __restrict__ Wt,
                              const float* __restrict__ bias,
                              unsigned short* __restrict__ C, int K,
                              const unsigned short* __restrict__ L,
                              const float* __restrict__ lw, const float* __restrict__ lb,
                              float* __restrict__ o) {
    __shared__ unsigned short smem[16384];
    int b = blockIdx.x;
    if (b < NGEMM) {
        gemm_body64(b % 157, b / 157, threadIdx.x, smem, A, Wt, bias, C, nullptr, K);
    } else {
        lin_body(b - NGEMM, threadIdx.x, L, lw, lb, o, N1);
    }
}

// s11: lin(g2) + dist + hist fused
__global__ void lin_dist_kernel(const unsigned short* __restrict__ A,
                                const float* __restrict__ w, const float* __restrict__ b,
                                const float* __restrict__ o1,
                                float* __restrict__ o2out,
                                float* __restrict__ dist, int* __restrict__ hist) {
    int tid = threadIdx.x;
    int wave = tid >> 6;
    int lane = tid & 63;
    int row = blockIdx.x * 4 + wave;
    if (row >= N1) return;
    const uint4* Ar = (const uint4*)(A + (size_t)row * 512);
    uint4 u = Ar[lane];
    float f[8];
    f[0] = bflo(u.x); f[1] = bfhi(u.x); f[2] = bflo(u.y); f[3] = bfhi(u.y);
    f[4] = bflo(u.z); f[5] = bfhi(u.z); f[6] = bflo(u.w); f[7] = bfhi(u.w);
    float s0 = 0.f, s1 = 0.f;
#pragma unroll
    for (int j = 0; j < 8; ++j) {
        int base = (lane * 8 + j) * 2;
        s0 = fmaf(f[j], w[base + 0], s0);
        s1 = fmaf(f[j], w[base + 1], s1);
    }
#pragma unroll
    for (int off = 32; off > 0; off >>= 1) {
        s0 += __shfl_down(s0, off, 64);
        s1 += __shfl_down(s1, off, 64);
    }
    if (lane == 0) {
        float vx = s0 + b[0], vy = s1 + b[1];
        o2out[row * 2] = vx; o2out[row * 2 + 1] = vy;
        float2 a = ((const float2*)o1)[row];
        float d0 = a.x - vx + 1e-6f, d1 = a.y - vy + 1e-6f;
        float d = sqrtf(d0 * d0 + d1 * d1);
        dist[row] = d;
        atomicAdd(&hist[__float_as_uint(d) >> 19], 1);
    }
}

// ---------------- radix-select top-k ----------------
__global__ void selk_kernel(const int* __restrict__ hist, int* __restrict__ selout) {
    __shared__ int tile[256];
    int t = threadIdx.x;
    int running = 0;
    for (int tb = 0; tb < 16; ++tb) {
        int idx = 4095 - (tb * 256 + t);
        int v = hist[idx];
        tile[t] = v;
        __syncthreads();
        for (int off = 1; off < 256; off <<= 1) {
            int x = (t >= off) ? tile[t - off] : 0;
            __syncthreads();
            tile[t] += x;
            __syncthreads();
        }
        int incl = running + tile[t];
        if (incl >= TOPK && incl - v < TOPK) selout[0] = idx;
        running += tile[255];
        __syncthreads();
        if (running >= TOPK) break;
    }
}

__global__ void compact_kernel(const float* __restrict__ dist, const int* __restrict__ selout,
                               int* __restrict__ nc, float* __restrict__ cd, int* __restrict__ ci) {
    int i = blockIdx.x * blockDim.x + threadIdx.x;
    if (i >= N1) return;
    float d = dist[i];
    int b = (int)(__float_as_uint(d) >> 19);
    if (b >= selout[0]) {
        int p = atomicAdd(nc, 1);
        cd[p] = d;
        ci[p] = i;
    }
}

#define CCH 2048
__global__ void rankc_kernel(const float* __restrict__ cd, const int* __restrict__ ci,
                             const int* __restrict__ nc_p, float* __restrict__ vals) {
    __shared__ float ds[CCH];
    __shared__ int   di_[CCH];
    int nc = *nc_p;
    if (blockIdx.x * 256 >= nc) return;
    int t = threadIdx.x;
    int q = blockIdx.x * 256 + t;
    float dq = 0.f; int iq = 0;
    if (q < nc) { dq = cd[q]; iq = ci[q]; }
    int cnt = 0;
    for (int c0 = 0; c0 < nc; c0 += CCH) {
        int lim = min(CCH, nc - c0);
        for (int j = t; j < lim; j += 256) { ds[j] = cd[c0 + j]; di_[j] = ci[c0 + j]; }
        __syncthreads();
        if (q < nc) {
            for (int j = 0; j < lim; ++j) {
                float dj = ds[j];
                cnt += (dj > dq) || (dj == dq && di_[j] < iq);
            }
        }
        __syncthreads();
    }
    if (q < nc && cnt < TOPK) vals[cnt] = dq;
}

// ---------------- head MLP (fc1 split 4-way) ----------------
__launch_bounds__(512)
__global__ void head_kernel(const float* __restrict__ vals,
                            const float* __restrict__ fc1_w, const float* __restrict__ fc1_b,
                            const float* __restrict__ ln1_g, const float* __restrict__ ln1_b,
                            const float* __restrict__ fc2_w, const float* __restrict__ fc2_b,
                            const float* __restrict__ ln2_g, const float* __restrict__ ln2_b,
                            const float* __restrict__ fc3_w, const float* __restrict__ fc3_b,
                            float* __restrict__ out) {
    __shared__ float sv[TOPK];
    __shared__ float a1[128];
    __shared__ float red[512];
    __shared__ float s_m, s_r;
    int t = threadIdx.x;
    for (int i = t; i < TOPK; i += 512) sv[i] = vals[i];
    __syncthreads();
    int g = t >> 7, c = t & 127;
    float part = 0.f;
    for (int j = g * 250; j < g * 250 + 250; ++j)
        part = fmaf(sv[j], fc1_w[j * 128 + c], part);
    red[t] = part;
    __syncthreads();
    float h1 = 0.f;
    if (t < 128) h1 = fc1_b[t] + red[t] + red[t + 128] + red[t + 256] + red[t + 384];
    __syncthreads();
    red[t] = (t < 128) ? h1 : 0.f; __syncthreads();
    for (int s = 256; s > 0; s >>= 1) { if (t < s) red[t] += red[t + s]; __syncthreads(); }
    if (t == 0) s_m = red[0] / 128.f;
    __syncthreads();
    float m1 = s_m;
    float dv = (t < 128) ? (h1 - m1) : 0.f;
    red[t] = dv * dv; __syncthreads();
    for (int s = 256; s > 0; s >>= 1) { if (t < s) red[t] += red[t + s]; __syncthreads(); }
    if (t == 0) s_r = rsqrtf(red[0] / 128.f + 1e-5f);
    __syncthreads();
    float r1 = s_r;
    if (t < 128) a1[t] = fmaxf((h1 - m1) * r1 * ln1_g[t] + ln1_b[t], 0.f);
    __syncthreads();
    float h2 = fc2_b[t];
    for (int j = 0; j < 128; ++j) h2 = fmaf(a1[j], fc2_w[j * 512 + t], h2);
    red[t] = h2; __syncthreads();
    for (int s = 256; s > 0; s >>= 1) { if (t < s) red[t] += red[t + s]; __syncthreads(); }
    if (t == 0) s_m = red[0] / 512.f;
    __syncthreads();
    float m2 = s_m;
    float d2 = h2 - m2;
    red[t] = d2 * d2; __syncthreads();
    for (int s = 256; s > 0; s >>= 1) { if (t < s) red[t] += red[t + s]; __syncthreads(); }
    if (t == 0) s_r = rsqrtf(red[0] / 512.f + 1e-5f);
    __syncthreads();
    float r2 = s_r;
    float y2 = fmaxf((h2 - m2) * r2 * ln2_g[t] + ln2_b[t], 0.f);
    red[t] = y2 * fc3_w[t]; __syncthreads();
    for (int s = 256; s > 0; s >>= 1) { if (t < s) red[t] += red[t + s]; __syncthreads(); }
    if (t == 0) out[0] = 1.f / (1.f + expf(-(red[0] + fc3_b[0])));
}

extern "C" void kernel_launch(void* const* d_in, const int* in_sizes, int n_in,
                              void* d_out, int out_size, void* d_ws, size_t ws_size,
                              hipStream_t stream) {
    const float* x1   = (const float*)d_in[0];
    const int*   ei1  = (const int*)d_in[1];
    const float* x2   = (const float*)d_in[2];
    const int*   ei2  = (const int*)d_in[3];
    const float* w11  = (const float*)d_in[4];
    const float* b11  = (const float*)d_in[5];
    const float* w12  = (const float*)d_in[6];
    const float* b12  = (const float*)d_in[7];
    const float* w21  = (const float*)d_in[8];
    const float* b21  = (const float*)d_in[9];
    const float* w22  = (const float*)d_in[10];
    const float* b22  = (const float*)d_in[11];
    const float* w31  = (const float*)d_in[12];
    const float* b31  = (const float*)d_in[13];
    const float* w32  = (const float*)d_in[14];
    const float* b32  = (const float*)d_in[15];
    const float* lw   = (const float*)d_in[16];
    const float* lb   = (const float*)d_in[17];
    const float* fc1w = (const float*)d_in[18];
    const float* fc1b = (const float*)d_in[19];
    const float* ln1g = (const float*)d_in[20];
    const float* ln1b = (const float*)d_in[21];
    const float* fc2w = (const float*)d_in[22];
    const float* fc2b = (const float*)d_in[23];
    const float* ln2g = (const float*)d_in[24];
    const float* ln2b = (const float*)d_in[25];
    const float* fc3w = (const float*)d_in[26];
    const float* fc3b = (const float*)d_in[27];

    char* ws = (char*)d_ws;
    size_t off = 0;
    auto alloc = [&](size_t bytes) -> void* {
        void* p = ws + off;
        off += (bytes + 255) & ~(size_t)255;
        return p;
    };
    unsigned short* XB  = (unsigned short*)alloc((size_t)NT * FIN_D * 2);
    unsigned char*  XB8 = (unsigned char*)alloc((size_t)NT * FIN_D);       // fp8 inputs
    unsigned short* H0a = (unsigned short*)alloc((size_t)MP1 * HID_D * 2);
    unsigned short* H1a = (unsigned short*)alloc((size_t)MP1 * HID_D * 2);
    unsigned short* H0b = (unsigned short*)alloc((size_t)MP1 * HID_D * 2);
    unsigned short* H1b = (unsigned short*)alloc((size_t)MP1 * HID_D * 2);
    unsigned char*  F8a = (unsigned char*)alloc((size_t)MP1 * HID_D);      // fp8 agg tables
    unsigned char*  F8b = (unsigned char*)alloc((size_t)MP1 * HID_D);
    unsigned short* wt11 = (unsigned short*)alloc((size_t)HID_D * FIN_D * 2);
    unsigned short* wt12 = (unsigned short*)alloc((size_t)HID_D * HID_D * 2);
    unsigned short* wt21 = (unsigned short*)alloc((size_t)HID_D * HID_D * 2);
    unsigned short* wt22 = (unsigned short*)alloc((size_t)HID_D * HID_D * 2);
    unsigned short* wt31 = (unsigned short*)alloc((size_t)HID_D * HID_D * 2);
    unsigned short* wt32 = (unsigned short*)alloc((size_t)HID_D * HID_D * 2);
    float* o         = (float*)alloc((size_t)NT * 2 * 4);
    float* dist      = (float*)alloc((size_t)N1 * 4);
    float* vals      = (float*)alloc((size_t)TOPK * 4);
    int*   row_start = (int*)alloc((size_t)(NT + 1) * 4);
    int*   cursor    = (int*)alloc((size_t)NT * 4);
    int*   deg       = (int*)alloc((size_t)NT * 4);
    int*   scan_tmp  = (int*)alloc((size_t)NT * 4);
    int*   bsum      = (int*)alloc((size_t)SCAN_NB * 4);
    int*   boff      = (int*)alloc((size_t)SCAN_NB * 4);
    int*   csr_src   = (int*)alloc((size_t)ET * 4);
    int*   selblk    = (int*)alloc((size_t)(4096 + 64) * 4);
    int*   hist      = selblk;
    int*   nc        = selblk + 4096;
    int*   selout    = (int*)alloc(2 * 4);
    float* cd        = (float*)alloc((size_t)N1 * 4);
    int*   ci        = (int*)alloc((size_t)N1 * 4);

    // ---- fused prep ----
    hipMemsetAsync(deg, 0, NT * sizeof(int), stream);
    hipMemsetAsync(selblk, 0, (4096 + 64) * sizeof(int), stream);
    prep_kernel<<<16408, 256, 0, stream>>>(ei1, ei2, deg,
                                           w11, wt11, w12, wt12, w21, wt21,
                                           w22, wt22, w31, wt31, w32, wt32,
                                           x1, x2, XB, XB8);
    scan1_kernel<<<SCAN_NB, 256, 0, stream>>>(deg, scan_tmp, bsum);
    scan2_kernel<<<1, 256, 0, stream>>>(bsum, boff, row_start);
    scan3_kernel<<<SCAN_NB, 256, 0, stream>>>(scan_tmp, boff, row_start, cursor);
    fill1_kernel<<<(E1 + 255) / 256, 256, 0, stream>>>(ei1, cursor, csr_src);

    // ---- staggered two-graph pipeline (fp8 gather tables) ----
    const unsigned char* XB8g2 = XB8 + (size_t)N1 * FIN_D;
    int fillB = (E1 + 255) / 256;            // 2500

    // s1: agg1(g1) fp8 || fill(g2)
    fused_aggfill<<<AGG256 + fillB, 256, 0, stream>>>(XB8, row_start, csr_src, H0a,
                                                      ei2, cursor, csr_src, AGG256);
    // s2: G11(g1) bf16 || agg1(g2) fp8
    fused_k<32, 4><<<NGEMM + AGG256, 256, 0, stream>>>(H0a, wt11, b11, H1a, nullptr, FIN_D,
                                                       XB8g2, row_start, csr_src, H0b, N1, NGEMM);
    // s3: G12(g1)->fp8 F8a + G11(g2)->bf16 H1b
    gemm_pair<<<2 * NGEMM, 256, 0, stream>>>(H1a, wt12, b12, nullptr, F8a, HID_D,
                                             H0b, wt11, b11, H1b, nullptr, FIN_D);
    // s4: G12(g2)->fp8 F8b || agg2(g1): F8a -> H1a
    fused_k<64, 8><<<NGEMM + AGG512, 256, 0, stream>>>(H1b, wt12, b12, nullptr, F8b, HID_D,
                                                       F8a, row_start, csr_src, H1a, 0, NGEMM);
    // s5: G21(g1): H1a -> H0a || agg2(g2): F8b -> H1b
    fused_k<64, 8><<<NGEMM + AGG512, 256, 0, stream>>>(H1a, wt21, b21, H0a, nullptr, HID_D,
                                                       F8b, row_start, csr_src, H1b, N1, NGEMM);
    // s6: G22(g1)->fp8 F8a + G21(g2): H1b -> H0b
    gemm_pair<<<2 * NGEMM, 256, 0, stream>>>(H0a, wt22, b22, nullptr, F8a, HID_D,
                                             H1b, wt21, b21, H0b, nullptr, HID_D);
    // s7: G22(g2)->fp8 F8b || agg3(g1): F8a -> H1a
    fused_k<64, 8><<<NGEMM + AGG512, 256, 0, stream>>>(H0b, wt22, b22, nullptr, F8b, HID_D,
                                                       F8a, row_start, csr_src, H1a, 0, NGEMM);
    // s8: G31(g1): H1a -> H0a || agg3(g2): F8b -> H1b
    fused_k<64, 8><<<NGEMM + AGG512, 256, 0, stream>>>(H1a, wt31, b31, H0a, nullptr, HID_D,
                                                       F8b, row_start, csr_src, H1b, N1, NGEMM);
    // s9: G32(g1): H0a -> H1a + G31(g2): H1b -> H0b
    gemm_pair<<<2 * NGEMM, 256, 0, stream>>>(H0a, wt32, b32, H1a, nullptr, HID_D,
                                             H1b, wt31, b31, H0b, nullptr, HID_D);
    // s10: G32(g2): H0b -> H1b || lin(g1) reads H1a
    fused_gemmlin<<<NGEMM + (N1 + 3) / 4, 256, 0, stream>>>(H0b, wt32, b32, H1b, HID_D,
                                                            H1a, lw, lb, o);
    // s11: lin(g2) + dist + hist fused
    lin_dist_kernel<<<(N1 + 3) / 4, 256, 0, stream>>>(H1b, lw, lb, o,
                                                      o + 2 * (size_t)N1, dist, hist);

    // ---- radix-select top-k + head ----
    selk_kernel<<<1, 256, 0, stream>>>(hist, selout);
    compact_kernel<<<(N1 + 255) / 256, 256, 0, stream>>>(dist, selout, nc, cd, ci);
    rankc_kernel<<<(N1 + 255) / 256, 256, 0, stream>>>(cd, ci, nc, vals);
    head_kernel<<<1, 512, 0, stream>>>(vals, fc1w, fc1b, ln1g, ln1b,
                                       fc2w, fc2b, ln2g, ln2b, fc3w, fc3b,
                                       (float*)d_out);
}

// Round 12
// 893.340 us; speedup vs baseline: 1.4350x; 1.0850x over previous
//
#include <hip/hip_runtime.h>
#include <hip/hip_bf16.h>
#include <math.h>

#define N1      20000          // nodes per graph
#define NT      40000          // both graphs
#define E1      640000         // edges per graph
#define ET      1280000
#define FIN_D   256
#define HID_D   512
#define TOPK    1000
#define MP1     20096          // 157 * 128 (padded M per graph)
#define SCAN_NB 157            // ceil(40000/256)
#define NGEMM   628            // 157 x 4 blocks per 20096x512 gemm
#define AGG256  2500           // 4 slabs * 625 groups (32 nodes/group)
#define AGG512  5000           // 8 slabs * 625 groups

typedef __attribute__((ext_vector_type(8))) short short8;
typedef __attribute__((ext_vector_type(4))) float floatx4;
typedef __attribute__((ext_vector_type(2))) float floatx2;
typedef unsigned int uintx4 __attribute__((ext_vector_type(4)));

__device__ __forceinline__ unsigned short f2bf(float f) {
    union { __hip_bfloat16 h; unsigned short u; } cv;
    cv.h = __float2bfloat16(f);
    return cv.u;
}
__device__ __forceinline__ float bflo(unsigned int u) {
    union { unsigned int i; float f; } c; c.i = u << 16; return c.f;
}
__device__ __forceinline__ float bfhi(unsigned int u) {
    union { unsigned int i; float f; } c; c.i = u & 0xffff0000u; return c.f;
}

// ---------------- fused prep: hist + 6x convw + 2x convx (bf16 + fp8) ----------
__device__ __forceinline__ void convw_body(int bl, int K, float* tile /*32x33*/,
                                           const float* __restrict__ W,
                                           unsigned short* __restrict__ Wt) {
    int kb = K / 32;
    int k0 = (bl % kb) * 32, n0 = (bl / kb) * 32;
    int tx = threadIdx.x & 31, ty = threadIdx.x >> 5;
    for (int r = ty; r < 32; r += 8) tile[r * 33 + tx] = W[(size_t)(k0 + r) * HID_D + n0 + tx];
    __syncthreads();
    for (int r = ty; r < 32; r += 8)
        Wt[(size_t)(n0 + r) * K + k0 + tx] = f2bf(tile[tx * 33 + r]);
}
__device__ __forceinline__ void convx_body(int i, const float* __restrict__ x,
                                           unsigned short* __restrict__ xb,
                                           unsigned char* __restrict__ x8) {
    float4 f = ((const float4*)x)[i];
    ushort4 u;
    u.x = f2bf(f.x); u.y = f2bf(f.y); u.z = f2bf(f.z); u.w = f2bf(f.w);
    ((ushort4*)xb)[i] = u;
    int p = __builtin_amdgcn_cvt_pk_fp8_f32(f.x, f.y, 0, false);
    p = __builtin_amdgcn_cvt_pk_fp8_f32(f.z, f.w, p, true);
    ((unsigned int*)x8)[i] = (unsigned int)p;
}

__launch_bounds__(256)
__global__ void prep_kernel(const int* __restrict__ ei1, const int* __restrict__ ei2,
                            int* __restrict__ deg,
                            const float* w11, unsigned short* wt11,
                            const float* w12, unsigned short* wt12,
                            const float* w21, unsigned short* wt21,
                            const float* w22, unsigned short* wt22,
                            const float* w31, unsigned short* wt31,
                            const float* w32, unsigned short* wt32,
                            const float* x1, const float* x2,
                            unsigned short* xb, unsigned char* x8) {
    __shared__ float tile[32 * 33];
    int b = blockIdx.x;
    if (b < 5000) {                       // hist, both graphs
        int e = b * 256 + threadIdx.x;
        if (e < ET) {
            int d = (e < E1) ? ei1[E1 + e] : (ei2[E1 + (e - E1)] + N1);
            atomicAdd(&deg[d], 1);
        }
    } else if (b < 5128)  { convw_body(b - 5000, FIN_D, tile, w11, wt11); }
    else if (b < 5384)    { convw_body(b - 5128, HID_D, tile, w12, wt12); }
    else if (b < 5640)    { convw_body(b - 5384, HID_D, tile, w21, wt21); }
    else if (b < 5896)    { convw_body(b - 5640, HID_D, tile, w22, wt22); }
    else if (b < 6152)    { convw_body(b - 5896, HID_D, tile, w31, wt31); }
    else if (b < 6408)    { convw_body(b - 6152, HID_D, tile, w32, wt32); }
    else if (b < 11408)   { convx_body((b - 6408) * 256 + threadIdx.x, x1, xb, x8); }
    else                  { convx_body((b - 11408) * 256 + threadIdx.x, x2,
                                       xb + (size_t)N1 * FIN_D, x8 + (size_t)N1 * FIN_D); }
}

// ---------------- CSR scans + fills ----------------
__global__ void scan1_kernel(const int* __restrict__ deg, int* __restrict__ tmp,
                             int* __restrict__ bsum) {
    __shared__ int tile[256];
    int t = threadIdx.x;
    int i = blockIdx.x * 256 + t;
    int v = (i < NT) ? deg[i] : 0;
    tile[t] = v;
    __syncthreads();
    for (int off = 1; off < 256; off <<= 1) {
        int x = (t >= off) ? tile[t - off] : 0;
        __syncthreads();
        tile[t] += x;
        __syncthreads();
    }
    if (i < NT) tmp[i] = tile[t] - v;
    if (t == 255) bsum[blockIdx.x] = tile[255];
}

__global__ void scan2_kernel(const int* __restrict__ bsum, int* __restrict__ boff,
                             int* __restrict__ row_start) {
    __shared__ int tile[256];
    int t = threadIdx.x;
    int v = (t < SCAN_NB) ? bsum[t] : 0;
    tile[t] = v;
    __syncthreads();
    for (int off = 1; off < 256; off <<= 1) {
        int x = (t >= off) ? tile[t - off] : 0;
        __syncthreads();
        tile[t] += x;
        __syncthreads();
    }
    if (t < SCAN_NB) boff[t] = tile[t] - v;
    if (t == 255) row_start[NT] = tile[255];
}

__global__ void scan3_kernel(const int* __restrict__ tmp, const int* __restrict__ boff,
                             int* __restrict__ row_start, int* __restrict__ cursor) {
    int i = blockIdx.x * 256 + threadIdx.x;
    if (i < NT) {
        int rs = tmp[i] + boff[blockIdx.x];
        row_start[i] = rs;
        cursor[i] = rs;
    }
}

__global__ void fill1_kernel(const int* __restrict__ ei1, int* __restrict__ cursor,
                             int* __restrict__ csr_src) {
    int e = blockIdx.x * 256 + threadIdx.x;
    if (e < E1) {
        int s = ei1[e], d = ei1[E1 + e];
        int p = atomicAdd(&cursor[d], 1);
        csr_src[p] = s;
    }
}

__device__ __forceinline__ void fill_g2_body(int e, const int* __restrict__ ei2,
                                             int* __restrict__ cursor, int* __restrict__ csr_src) {
    if (e < E1) {
        int s = ei2[e] + N1, d = ei2[E1 + e] + N1;
        int p = atomicAdd(&cursor[d], 1);
        csr_src[p] = s;
    }
}

// ---------------- fp8 GIN aggregation body ------------------------------------
#define ACCF8(u) do { \
    floatx2 a0 = __builtin_amdgcn_cvt_pk_f32_fp8((int)(u).x, false); \
    floatx2 a1 = __builtin_amdgcn_cvt_pk_f32_fp8((int)(u).x, true);  \
    floatx2 a2 = __builtin_amdgcn_cvt_pk_f32_fp8((int)(u).y, false); \
    floatx2 a3 = __builtin_amdgcn_cvt_pk_f32_fp8((int)(u).y, true);  \
    acc[0] += a0.x; acc[1] += a0.y; acc[2] += a1.x; acc[3] += a1.y; \
    acc[4] += a2.x; acc[5] += a2.y; acc[6] += a3.x; acc[7] += a3.y; } while (0)

template<int LPR2, int NSLAB>   // LPR2 = uint2 per fp8 row (D/8); NSLAB = D/64
__device__ __forceinline__ void agg8_body(int ab, int tid,
                                          const unsigned char* __restrict__ x8,
                                          const int* __restrict__ row_start,
                                          const int* __restrict__ csr_src,
                                          unsigned short* __restrict__ h, int n0) {
    int slab = ab & (NSLAB - 1);               // XCD-pinned (blockIdx round-robin)
    int grp  = ab / NSLAB;                     // 0..624
    int node = grp * 32 + (tid >> 3);          // exact: 625*32 = 20000
    int lanec = tid & 7;
    int chunk = slab * 8 + lanec;              // uint2 index within fp8 row
    const uint2* Xc = (const uint2*)x8 + chunk;
    uint2 v = Xc[(size_t)node * LPR2];
    float acc[8] = {};
    ACCF8(v);                                  // self term (fp8)
    int nid = n0 + node;
    int s = row_start[nid], e = row_start[nid + 1];
    int p = s;
    for (; p + 8 <= e; p += 8) {
        int m0 = csr_src[p + 0] - n0, m1 = csr_src[p + 1] - n0;
        int m2 = csr_src[p + 2] - n0, m3 = csr_src[p + 3] - n0;
        int m4 = csr_src[p + 4] - n0, m5 = csr_src[p + 5] - n0;
        int m6 = csr_src[p + 6] - n0, m7 = csr_src[p + 7] - n0;
        uint2 u0 = Xc[(size_t)m0 * LPR2];
        uint2 u1 = Xc[(size_t)m1 * LPR2];
        uint2 u2 = Xc[(size_t)m2 * LPR2];
        uint2 u3 = Xc[(size_t)m3 * LPR2];
        uint2 u4 = Xc[(size_t)m4 * LPR2];
        uint2 u5 = Xc[(size_t)m5 * LPR2];
        uint2 u6 = Xc[(size_t)m6 * LPR2];
        uint2 u7 = Xc[(size_t)m7 * LPR2];
        ACCF8(u0); ACCF8(u1); ACCF8(u2); ACCF8(u3);
        ACCF8(u4); ACCF8(u5); ACCF8(u6); ACCF8(u7);
    }
    for (; p + 2 <= e; p += 2) {
        int ma = csr_src[p + 0] - n0, mb = csr_src[p + 1] - n0;
        uint2 u0 = Xc[(size_t)ma * LPR2];
        uint2 u1 = Xc[(size_t)mb * LPR2];
        ACCF8(u0); ACCF8(u1);
    }
    if (p < e) {
        int ma = csr_src[p] - n0;
        uint2 u0 = Xc[(size_t)ma * LPR2];
        ACCF8(u0);
    }
    uintx4 o;
    o.x = (unsigned)f2bf(acc[0]) | ((unsigned)f2bf(acc[1]) << 16);
    o.y = (unsigned)f2bf(acc[2]) | ((unsigned)f2bf(acc[3]) << 16);
    o.z = (unsigned)f2bf(acc[4]) | ((unsigned)f2bf(acc[5]) << 16);
    o.w = (unsigned)f2bf(acc[6]) | ((unsigned)f2bf(acc[7]) << 16);
    ((uintx4*)h)[(size_t)node * LPR2 + chunk] = o;
}

// ---------------- stage 1: agg1(g1) || fill(g2) --------------------------------
__launch_bounds__(256, 8)
__global__ void fused_aggfill(const unsigned char* __restrict__ x8,
                              const int* __restrict__ row_start,
                              const int* __restrict__ csr_src,
                              unsigned short* __restrict__ h,
                              const int* __restrict__ ei2,
                              int* __restrict__ cursor,
                              int* __restrict__ csr_w, int nAgg) {
    int b = blockIdx.x;
    if (b < nAgg) {
        agg8_body<32, 4>(b, threadIdx.x, x8, row_start, csr_src, h, 0);
    } else {
        fill_g2_body((b - nAgg) * 256 + threadIdx.x, ei2, cursor, csr_w);
    }
}

// ---------------- fp8 tile store (epilogue helper, coalesced via LDS) ----------
__device__ __forceinline__ void store_fp8_tile(int row0, int col0, int tid,
                                               unsigned short* smem,
                                               floatx4 acc[4][4], const float* __restrict__ bias,
                                               unsigned char* __restrict__ C8,
                                               int wr, int wc, int lane) {
    unsigned char* tile = (unsigned char*)smem;    // 128*128 = 16KB
    int q = lane >> 4, cn = lane & 15;
#pragma unroll
    for (int j = 0; j < 4; ++j) {
        int lcol = wc * 64 + j * 16 + cn;
        float bv = bias[col0 + lcol];
#pragma unroll
        for (int i = 0; i < 4; ++i) {
            int lrow = wr * 64 + i * 16 + q * 4;
#pragma unroll
            for (int r = 0; r < 4; ++r) {
                float vv = fmaxf(acc[i][j][r] + bv, 0.f);
                int t8 = __builtin_amdgcn_cvt_pk_fp8_f32(vv, 0.f, 0, false);
                tile[(lrow + r) * 128 + lcol] = (unsigned char)(t8 & 0xff);
            }
        }
    }
    __syncthreads();
#pragma unroll
    for (int it = 0; it < 4; ++it) {
        int idx = it * 256 + tid;
        int lrow = idx >> 3, c16 = idx & 7;
        *(uint4*)(C8 + (size_t)(row0 + lrow) * HID_D + col0 + c16 * 16) =
            *(const uint4*)(tile + lrow * 128 + c16 * 16);
    }
}

// ---------------- bf16 MFMA GEMM body, BK=32 (16KB LDS) ------------------------
__device__ __forceinline__ void gemm_body(int bx, int by, int tid,
                                          unsigned short* smem,
                                          const unsigned short* __restrict__ A,
                                          const unsigned short* __restrict__ Wt,
                                          const float* __restrict__ bias,
                                          unsigned short* __restrict__ C,
                                          unsigned char* __restrict__ C8, int K) {
    const int N = HID_D;
    unsigned short* As = smem;
    unsigned short* Bs = smem + 4096;
    int lane = tid & 63;
    int w = tid >> 6;
    int wr = w >> 1, wc = w & 1;
    int row0 = bx * 128;
    int col0 = by * 128;
    floatx4 acc[4][4] = {};
    int lr = tid >> 2;
    int c8 = (tid & 3) * 8;
    const unsigned short* Ag = A + (size_t)row0 * K;
    const unsigned short* Bg = Wt + (size_t)col0 * K;

    for (int kt = 0; kt < K; kt += 32) {
#pragma unroll
        for (int l = 0; l < 2; ++l) {
            int r = l * 64 + lr;
            __builtin_amdgcn_global_load_lds(
                (const __attribute__((address_space(1))) void*)(Ag + (size_t)r * K + kt + c8),
                (__attribute__((address_space(3))) void*)(As + l * 2048 + tid * 8),
                16, 0, 0);
            __builtin_amdgcn_global_load_lds(
                (const __attribute__((address_space(1))) void*)(Bg + (size_t)r * K + kt + c8),
                (__attribute__((address_space(3))) void*)(Bs + l * 2048 + tid * 8),
                16, 0, 0);
        }
        __syncthreads();
        short8 af[4], bf[4];
        int q8 = (lane >> 4) * 8;
#pragma unroll
        for (int i = 0; i < 4; ++i) {
            int m = wr * 64 + i * 16 + (lane & 15);
            af[i] = *(const short8*)&As[m * 32 + q8];
            int n = wc * 64 + i * 16 + (lane & 15);
            bf[i] = *(const short8*)&Bs[n * 32 + q8];
        }
#pragma unroll
        for (int i = 0; i < 4; ++i)
#pragma unroll
            for (int j = 0; j < 4; ++j)
                acc[i][j] = __builtin_amdgcn_mfma_f32_16x16x32_bf16(af[i], bf[j], acc[i][j], 0, 0, 0);
        __syncthreads();
    }
    if (C8) {
        store_fp8_tile(row0, col0, tid, smem, acc, bias, C8, wr, wc, lane);
        return;
    }
    int q = lane >> 4;
    int cn = lane & 15;
#pragma unroll
    for (int j = 0; j < 4; ++j) {
        int col = col0 + wc * 64 + j * 16 + cn;
        float bv = bias[col];
#pragma unroll
        for (int i = 0; i < 4; ++i) {
            int rowb = row0 + wr * 64 + i * 16 + q * 4;
#pragma unroll
            for (int r = 0; r < 4; ++r) {
                float vv = fmaxf(acc[i][j][r] + bv, 0.f);
                C[(size_t)(rowb + r) * N + col] = f2bf(vv);
            }
        }
    }
}

// ---------------- bf16 MFMA GEMM body, BK=64 (32KB LDS) ------------------------
__device__ __forceinline__ void gemm_body64(int bx, int by, int tid,
                                            unsigned short* smem,
                                            const unsigned short* __restrict__ A,
                                            const unsigned short* __restrict__ Wt,
                                            const float* __restrict__ bias,
                                            unsigned short* __restrict__ C,
                                            unsigned char* __restrict__ C8, int K) {
    const int N = HID_D;
    unsigned short* As = smem;
    unsigned short* Bs = smem + 8192;
    int lane = tid & 63;
    int w = tid >> 6;
    int wr = w >> 1, wc = w & 1;
    int row0 = bx * 128;
    int col0 = by * 128;
    floatx4 acc[4][4] = {};
    int lr = tid >> 3;
    int c8 = (tid & 7) * 8;
    const unsigned short* Ag = A + (size_t)row0 * K;
    const unsigned short* Bg = Wt + (size_t)col0 * K;

    for (int kt = 0; kt < K; kt += 64) {
#pragma unroll
        for (int l = 0; l < 4; ++l) {
            int r = l * 32 + lr;
            __builtin_amdgcn_global_load_lds(
                (const __attribute__((address_space(1))) void*)(Ag + (size_t)r * K + kt + c8),
                (__attribute__((address_space(3))) void*)(As + l * 2048 + tid * 8),
                16, 0, 0);
            __builtin_amdgcn_global_load_lds(
                (const __attribute__((address_space(1))) void*)(Bg + (size_t)r * K + kt + c8),
                (__attribute__((address_space(3))) void*)(Bs + l * 2048 + tid * 8),
                16, 0, 0);
        }
        __syncthreads();
#pragma unroll
        for (int kb = 0; kb < 2; ++kb) {
            short8 af[4], bf[4];
            int q8 = kb * 32 + (lane >> 4) * 8;
#pragma unroll
            for (int i = 0; i < 4; ++i) {
                int m = wr * 64 + i * 16 + (lane & 15);
                af[i] = *(const short8*)&As[m * 64 + q8];
                int n = wc * 64 + i * 16 + (lane & 15);
                bf[i] = *(const short8*)&Bs[n * 64 + q8];
            }
#pragma unroll
            for (int i = 0; i < 4; ++i)
#pragma unroll
                for (int j = 0; j < 4; ++j)
                    acc[i][j] = __builtin_amdgcn_mfma_f32_16x16x32_bf16(af[i], bf[j], acc[i][j], 0, 0, 0);
        }
        __syncthreads();
    }
    if (C8) {
        store_fp8_tile(row0, col0, tid, smem, acc, bias, C8, wr, wc, lane);
        return;
    }
    int q = lane >> 4;
    int cn = lane & 15;
#pragma unroll
    for (int j = 0; j < 4; ++j) {
        int col = col0 + wc * 64 + j * 16 + cn;
        float bv = bias[col];
#pragma unroll
        for (int i = 0; i < 4; ++i) {
            int rowb = row0 + wr * 64 + i * 16 + q * 4;
#pragma unroll
            for (int r = 0; r < 4; ++r) {
                float vv = fmaxf(acc[i][j][r] + bv, 0.f);
                C[(size_t)(rowb + r) * N + col] = f2bf(vv);
            }
        }
    }
}

// two independent gemms (different graphs) in one launch, BK=64
__launch_bounds__(256)
__global__ void gemm_pair(const unsigned short* __restrict__ A1,
                          const unsigned short* __restrict__ W1,
                          const float* __restrict__ b1,
                          unsigned short* __restrict__ C1, unsigned char* C81, int K1,
                          const unsigned short* __restrict__ A2,
                          const unsigned short* __restrict__ W2,
                          const float* __restrict__ b2,
                          unsigned short* __restrict__ C2, unsigned char* C82, int K2) {
    __shared__ unsigned short smem[16384];
    int b = blockIdx.x;
    if (b < NGEMM) {
        gemm_body64(b % 157, b / 157, threadIdx.x, smem, A1, W1, b1, C1, C81, K1);
    } else {
        b -= NGEMM;
        gemm_body64(b % 157, b / 157, threadIdx.x, smem, A2, W2, b2, C2, C82, K2);
    }
}

// ---------------- fused: gemm (BK=32) blocks first, fp8-agg blocks after --------
template<int LPR2, int NSLAB>
__launch_bounds__(256)
__global__ void fused_k(const unsigned short* __restrict__ A,
                        const unsigned short* __restrict__ Wt,
                        const float* __restrict__ bias,
                        unsigned short* __restrict__ C, unsigned char* C8, int K,
                        const unsigned char* __restrict__ x8,
                        const int* __restrict__ row_start,
                        const int* __restrict__ csr_src,
                        unsigned short* __restrict__ h, int n0, int nGemm) {
    __shared__ unsigned short smem[8192];
    int b = blockIdx.x;
    if (b < nGemm) {
        gemm_body(b % 157, b / 157, threadIdx.x, smem, A, Wt, bias, C, C8, K);
    } else {
        agg8_body<LPR2, NSLAB>(b - nGemm, threadIdx.x, x8, row_start, csr_src, h, n0);
    }
}

// ---------------- final linear [M,512]bf16 @ [512,2]fp32 + b ----------------
__device__ __forceinline__ void lin_body(int bb, int tid, const unsigned short* __restrict__ A,
                                         const float* __restrict__ w, const float* __restrict__ b,
                                         float* __restrict__ o, int M) {
    int wave = tid >> 6;
    int lane = tid & 63;
    int row = bb * 4 + wave;
    if (row >= M) return;
    const uint4* Ar = (const uint4*)(A + (size_t)row * 512);
    uint4 u = Ar[lane];
    float f[8];
    f[0] = bflo(u.x); f[1] = bfhi(u.x); f[2] = bflo(u.y); f[3] = bfhi(u.y);
    f[4] = bflo(u.z); f[5] = bfhi(u.z); f[6] = bflo(u.w); f[7] = bfhi(u.w);
    float s0 = 0.f, s1 = 0.f;
#pragma unroll
    for (int j = 0; j < 8; ++j) {
        int base = (lane * 8 + j) * 2;
        s0 = fmaf(f[j], w[base + 0], s0);
        s1 = fmaf(f[j], w[base + 1], s1);
    }
#pragma unroll
    for (int off = 32; off > 0; off >>= 1) {
        s0 += __shfl_down(s0, off, 64);
        s1 += __shfl_down(s1, off, 64);
    }
    if (lane == 0) { o[row * 2] = s0 + b[0]; o[row * 2 + 1] = s1 + b[1]; }
}

// s10: G32(g2) || lin(g1)
__launch_bounds__(256)
__global__ void fused_gemmlin(const unsigned short* __restrict__ A,
                              const unsigned short* __restrict__ Wt,
                              const float* __restrict__ bias,
                              unsigned short* __restrict__ C, int K,
                              const unsigned short* __restrict__ L,
                              const float* __restrict__ lw, const float* __restrict__ lb,
                              float* __restrict__ o) {
    __shared__ unsigned short smem[16384];
    int b = blockIdx.x;
    if (b < NGEMM) {
        gemm_body64(b % 157, b / 157, threadIdx.x, smem, A, Wt, bias, C, nullptr, K);
    } else {
        lin_body(b - NGEMM, threadIdx.x, L, lw, lb, o, N1);
    }
}

// s11: lin(g2) + dist (NO histogram atomics - they serialize; see hist_lds)
__global__ void lin_dist_kernel(const unsigned short* __restrict__ A,
                                const float* __restrict__ w, const float* __restrict__ b,
                                const float* __restrict__ o1,
                                float* __restrict__ o2out,
                                float* __restrict__ dist) {
    int tid = threadIdx.x;
    int wave = tid >> 6;
    int lane = tid & 63;
    int row = blockIdx.x * 4 + wave;
    if (row >= N1) return;
    const uint4* Ar = (const uint4*)(A + (size_t)row * 512);
    uint4 u = Ar[lane];
    float f[8];
    f[0] = bflo(u.x); f[1] = bfhi(u.x); f[2] = bflo(u.y); f[3] = bfhi(u.y);
    f[4] = bflo(u.z); f[5] = bfhi(u.z); f[6] = bflo(u.w); f[7] = bfhi(u.w);
    float s0 = 0.f, s1 = 0.f;
#pragma unroll
    for (int j = 0; j < 8; ++j) {
        int base = (lane * 8 + j) * 2;
        s0 = fmaf(f[j], w[base + 0], s0);
        s1 = fmaf(f[j], w[base + 1], s1);
    }
#pragma unroll
    for (int off = 32; off > 0; off >>= 1) {
        s0 += __shfl_down(s0, off, 64);
        s1 += __shfl_down(s1, off, 64);
    }
    if (lane == 0) {
        float vx = s0 + b[0], vy = s1 + b[1];
        o2out[row * 2] = vx; o2out[row * 2 + 1] = vy;
        float2 a = ((const float2*)o1)[row];
        float d0 = a.x - vx + 1e-6f, d1 = a.y - vy + 1e-6f;
        dist[row] = sqrtf(d0 * d0 + d1 * d1);
    }
}

// LDS-privatized histogram: distances cluster into few buckets, so global
// atomics serialize (the 88us lin_dist pathology). 20 blocks x 1000 values;
// per-block LDS histogram then flush nonzero buckets only.
#define HBLK 20
#define HPB  1000
__launch_bounds__(256)
__global__ void hist_lds_kernel(const float* __restrict__ dist, int* __restrict__ hist) {
    __shared__ int lh[4096];
    int t = threadIdx.x;
    for (int i = t; i < 4096; i += 256) lh[i] = 0;
    __syncthreads();
    int base = blockIdx.x * HPB;
    for (int i = t; i < HPB; i += 256) {
        int idx = base + i;
        if (idx < N1) atomicAdd(&lh[__float_as_uint(dist[idx]) >> 19], 1);
    }
    __syncthreads();
    for (int i = t; i < 4096; i += 256) {
        int v = lh[i];
        if (v) atomicAdd(&hist[i], v);
    }
}

// ---------------- radix-select top-k ----------------
__global__ void selk_kernel(const int* __restrict__ hist, int* __restrict__ selout) {
    __shared__ int tile[256];
    int t = threadIdx.x;
    int running = 0;
    for (int tb = 0; tb < 16; ++tb) {
        int idx = 4095 - (tb * 256 + t);
        int v = hist[idx];
        tile[t] = v;
        __syncthreads();
        for (int off = 1; off < 256; off <<= 1) {
            int x = (t >= off) ? tile[t - off] : 0;
            __syncthreads();
            tile[t] += x;
            __syncthreads();
        }
        int incl = running + tile[t];
        if (incl >= TOPK && incl - v < TOPK) selout[0] = idx;
        running += tile[255];
        __syncthreads();
        if (running >= TOPK) break;
    }
}

__global__ void compact_kernel(const float* __restrict__ dist, const int* __restrict__ selout,
                               int* __restrict__ nc, float* __restrict__ cd, int* __restrict__ ci) {
    int i = blockIdx.x * blockDim.x + threadIdx.x;
    if (i >= N1) return;
    float d = dist[i];
    int b = (int)(__float_as_uint(d) >> 19);
    if (b >= selout[0]) {
        int p = atomicAdd(nc, 1);
        cd[p] = d;
        ci[p] = i;
    }
}

#define CCH 2048
__global__ void rankc_kernel(const float* __restrict__ cd, const int* __restrict__ ci,
                             const int* __restrict__ nc_p, float* __restrict__ vals) {
    __shared__ float ds[CCH];
    __shared__ int   di_[CCH];
    int nc = *nc_p;
    if (blockIdx.x * 256 >= nc) return;
    int t = threadIdx.x;
    int q = blockIdx.x * 256 + t;
    float dq = 0.f; int iq = 0;
    if (q < nc) { dq = cd[q]; iq = ci[q]; }
    int cnt = 0;
    for (int c0 = 0; c0 < nc; c0 += CCH) {
        int lim = min(CCH, nc - c0);
        for (int j = t; j < lim; j += 256) { ds[j] = cd[c0 + j]; di_[j] = ci[c0 + j]; }
        __syncthreads();
        if (q < nc) {
            for (int j = 0; j < lim; ++j) {
                float dj = ds[j];
                cnt += (dj > dq) || (dj == dq && di_[j] < iq);
            }
        }
        __syncthreads();
    }
    if (q < nc && cnt < TOPK) vals[cnt] = dq;
}

// ---------------- head MLP (fc1 split 4-way) ----------------
__launch_bounds__(512)
__global__ void head_kernel(const float* __restrict__ vals,
                            const float* __restrict__ fc1_w, const float* __restrict__ fc1_b,
                            const float* __restrict__ ln1_g, const float* __restrict__ ln1_b,
                            const float* __restrict__ fc2_w, const float* __restrict__ fc2_b,
                            const float* __restrict__ ln2_g, const float* __restrict__ ln2_b,
                            const float* __restrict__ fc3_w, const float* __restrict__ fc3_b,
                            float* __restrict__ out) {
    __shared__ float sv[TOPK];
    __shared__ float a1[128];
    __shared__ float red[512];
    __shared__ float s_m, s_r;
    int t = threadIdx.x;
    for (int i = t; i < TOPK; i += 512) sv[i] = vals[i];
    __syncthreads();
    int g = t >> 7, c = t & 127;
    float part = 0.f;
    for (int j = g * 250; j < g * 250 + 250; ++j)
        part = fmaf(sv[j], fc1_w[j * 128 + c], part);
    red[t] = part;
    __syncthreads();
    float h1 = 0.f;
    if (t < 128) h1 = fc1_b[t] + red[t] + red[t + 128] + red[t + 256] + red[t + 384];
    __syncthreads();
    red[t] = (t < 128) ? h1 : 0.f; __syncthreads();
    for (int s = 256; s > 0; s >>= 1) { if (t < s) red[t] += red[t + s]; __syncthreads(); }
    if (t == 0) s_m = red[0] / 128.f;
    __syncthreads();
    float m1 = s_m;
    float dv = (t < 128) ? (h1 - m1) : 0.f;
    red[t] = dv * dv; __syncthreads();
    for (int s = 256; s > 0; s >>= 1) { if (t < s) red[t] += red[t + s]; __syncthreads(); }
    if (t == 0) s_r = rsqrtf(red[0] / 128.f + 1e-5f);
    __syncthreads();
    float r1 = s_r;
    if (t < 128) a1[t] = fmaxf((h1 - m1) * r1 * ln1_g[t] + ln1_b[t], 0.f);
    __syncthreads();
    float h2 = fc2_b[t];
    for (int j = 0; j < 128; ++j) h2 = fmaf(a1[j], fc2_w[j * 512 + t], h2);
    red[t] = h2; __syncthreads();
    for (int s = 256; s > 0; s >>= 1) { if (t < s) red[t] += red[t + s]; __syncthreads(); }
    if (t == 0) s_m = red[0] / 512.f;
    __syncthreads();
    float m2 = s_m;
    float d2 = h2 - m2;
    red[t] = d2 * d2; __syncthreads();
    for (int s = 256; s > 0; s >>= 1) { if (t < s) red[t] += red[t + s]; __syncthreads(); }
    if (t == 0) s_r = rsqrtf(red[0] / 512.f + 1e-5f);
    __syncthreads();
    float r2 = s_r;
    float y2 = fmaxf((h2 - m2) * r2 * ln2_g[t] + ln2_b[t], 0.f);
    red[t] = y2 * fc3_w[t]; __syncthreads();
    for (int s = 256; s > 0; s >>= 1) { if (t < s) red[t] += red[t + s]; __syncthreads(); }
    if (t == 0) out[0] = 1.f / (1.f + expf(-(red[0] + fc3_b[0])));
}

extern "C" void kernel_launch(void* const* d_in, const int* in_sizes, int n_in,
                              void* d_out, int out_size, void* d_ws, size_t ws_size,
                              hipStream_t stream) {
    const float* x1   = (const float*)d_in[0];
    const int*   ei1  = (const int*)d_in[1];
    const float* x2   = (const float*)d_in[2];
    const int*   ei2  = (const int*)d_in[3];
    const float* w11  = (const float*)d_in[4];
    const float* b11  = (const float*)d_in[5];
    const float* w12  = (const float*)d_in[6];
    const float* b12  = (const float*)d_in[7];
    const float* w21  = (const float*)d_in[8];
    const float* b21  = (const float*)d_in[9];
    const float* w22  = (const float*)d_in[10];
    const float* b22  = (const float*)d_in[11];
    const float* w31  = (const float*)d_in[12];
    const float* b31  = (const float*)d_in[13];
    const float* w32  = (const float*)d_in[14];
    const float* b32  = (const float*)d_in[15];
    const float* lw   = (const float*)d_in[16];
    const float* lb   = (const float*)d_in[17];
    const float* fc1w = (const float*)d_in[18];
    const float* fc1b = (const float*)d_in[19];
    const float* ln1g = (const float*)d_in[20];
    const float* ln1b = (const float*)d_in[21];
    const float* fc2w = (const float*)d_in[22];
    const float* fc2b = (const float*)d_in[23];
    const float* ln2g = (const float*)d_in[24];
    const float* ln2b = (const float*)d_in[25];
    const float* fc3w = (const float*)d_in[26];
    const float* fc3b = (const float*)d_in[27];

    char* ws = (char*)d_ws;
    size_t off = 0;
    auto alloc = [&](size_t bytes) -> void* {
        void* p = ws + off;
        off += (bytes + 255) & ~(size_t)255;
        return p;
    };
    unsigned short* XB  = (unsigned short*)alloc((size_t)NT * FIN_D * 2);
    unsigned char*  XB8 = (unsigned char*)alloc((size_t)NT * FIN_D);       // fp8 inputs
    unsigned short* H0a = (unsigned short*)alloc((size_t)MP1 * HID_D * 2);
    unsigned short* H1a = (unsigned short*)alloc((size_t)MP1 * HID_D * 2);
    unsigned short* H0b = (unsigned short*)alloc((size_t)MP1 * HID_D * 2);
    unsigned short* H1b = (unsigned short*)alloc((size_t)MP1 * HID_D * 2);
    unsigned char*  F8a = (unsigned char*)alloc((size_t)MP1 * HID_D);      // fp8 agg tables
    unsigned char*  F8b = (unsigned char*)alloc((size_t)MP1 * HID_D);
    unsigned short* wt11 = (unsigned short*)alloc((size_t)HID_D * FIN_D * 2);
    unsigned short* wt12 = (unsigned short*)alloc((size_t)HID_D * HID_D * 2);
    unsigned short* wt21 = (unsigned short*)alloc((size_t)HID_D * HID_D * 2);
    unsigned short* wt22 = (unsigned short*)alloc((size_t)HID_D * HID_D * 2);
    unsigned short* wt31 = (unsigned short*)alloc((size_t)HID_D * HID_D * 2);
    unsigned short* wt32 = (unsigned short*)alloc((size_t)HID_D * HID_D * 2);
    float* o         = (float*)alloc((size_t)NT * 2 * 4);
    float* dist      = (float*)alloc((size_t)N1 * 4);
    float* vals      = (float*)alloc((size_t)TOPK * 4);
    int*   row_start = (int*)alloc((size_t)(NT + 1) * 4);
    int*   cursor    = (int*)alloc((size_t)NT * 4);
    int*   deg       = (int*)alloc((size_t)NT * 4);
    int*   scan_tmp  = (int*)alloc((size_t)NT * 4);
    int*   bsum      = (int*)alloc((size_t)SCAN_NB * 4);
    int*   boff      = (int*)alloc((size_t)SCAN_NB * 4);
    int*   csr_src   = (int*)alloc((size_t)ET * 4);
    int*   selblk    = (int*)alloc((size_t)(4096 + 64) * 4);
    int*   hist      = selblk;
    int*   nc        = selblk + 4096;
    int*   selout    = (int*)alloc(2 * 4);
    float* cd        = (float*)alloc((size_t)N1 * 4);
    int*   ci        = (int*)alloc((size_t)N1 * 4);

    // ---- fused prep ----
    hipMemsetAsync(deg, 0, NT * sizeof(int), stream);
    hipMemsetAsync(selblk, 0, (4096 + 64) * sizeof(int), stream);
    prep_kernel<<<16408, 256, 0, stream>>>(ei1, ei2, deg,
                                           w11, wt11, w12, wt12, w21, wt21,
                                           w22, wt22, w31, wt31, w32, wt32,
                                           x1, x2, XB, XB8);
    scan1_kernel<<<SCAN_NB, 256, 0, stream>>>(deg, scan_tmp, bsum);
    scan2_kernel<<<1, 256, 0, stream>>>(bsum, boff, row_start);
    scan3_kernel<<<SCAN_NB, 256, 0, stream>>>(scan_tmp, boff, row_start, cursor);
    fill1_kernel<<<(E1 + 255) / 256, 256, 0, stream>>>(ei1, cursor, csr_src);

    // ---- staggered two-graph pipeline (fp8 gather tables) ----
    const unsigned char* XB8g2 = XB8 + (size_t)N1 * FIN_D;
    int fillB = (E1 + 255) / 256;            // 2500

    // s1: agg1(g1) fp8 || fill(g2)
    fused_aggfill<<<AGG256 + fillB, 256, 0, stream>>>(XB8, row_start, csr_src, H0a,
                                                      ei2, cursor, csr_src, AGG256);
    // s2: G11(g1) bf16 || agg1(g2) fp8
    fused_k<32, 4><<<NGEMM + AGG256, 256, 0, stream>>>(H0a, wt11, b11, H1a, nullptr, FIN_D,
                                                       XB8g2, row_start, csr_src, H0b, N1, NGEMM);
    // s3: G12(g1)->fp8 F8a + G11(g2)->bf16 H1b
    gemm_pair<<<2 * NGEMM, 256, 0, stream>>>(H1a, wt12, b12, nullptr, F8a, HID_D,
                                             H0b, wt11, b11, H1b, nullptr, FIN_D);
    // s4: G12(g2)->fp8 F8b || agg2(g1): F8a -> H1a
    fused_k<64, 8><<<NGEMM + AGG512, 256, 0, stream>>>(H1b, wt12, b12, nullptr, F8b, HID_D,
                                                       F8a, row_start, csr_src, H1a, 0, NGEMM);
    // s5: G21(g1): H1a -> H0a || agg2(g2): F8b -> H1b
    fused_k<64, 8><<<NGEMM + AGG512, 256, 0, stream>>>(H1a, wt21, b21, H0a, nullptr, HID_D,
                                                       F8b, row_start, csr_src, H1b, N1, NGEMM);
    // s6: G22(g1)->fp8 F8a + G21(g2): H1b -> H0b
    gemm_pair<<<2 * NGEMM, 256, 0, stream>>>(H0a, wt22, b22, nullptr, F8a, HID_D,
                                             H1b, wt21, b21, H0b, nullptr, HID_D);
    // s7: G22(g2)->fp8 F8b || agg3(g1): F8a -> H1a
    fused_k<64, 8><<<NGEMM + AGG512, 256, 0, stream>>>(H0b, wt22, b22, nullptr, F8b, HID_D,
                                                       F8a, row_start, csr_src, H1a, 0, NGEMM);
    // s8: G31(g1): H1a -> H0a || agg3(g2): F8b -> H1b
    fused_k<64, 8><<<NGEMM + AGG512, 256, 0, stream>>>(H1a, wt31, b31, H0a, nullptr, HID_D,
                                                       F8b, row_start, csr_src, H1b, N1, NGEMM);
    // s9: G32(g1): H0a -> H1a + G31(g2): H1b -> H0b
    gemm_pair<<<2 * NGEMM, 256, 0, stream>>>(H0a, wt32, b32, H1a, nullptr, HID_D,
                                             H1b, wt31, b31, H0b, nullptr, HID_D);
    // s10: G32(g2): H0b -> H1b || lin(g1) reads H1a
    fused_gemmlin<<<NGEMM + (N1 + 3) / 4, 256, 0, stream>>>(H0b, wt32, b32, H1b, HID_D,
                                                            H1a, lw, lb, o);
    // s11: lin(g2) + dist (no hist atomics)
    lin_dist_kernel<<<(N1 + 3) / 4, 256, 0, stream>>>(H1b, lw, lb, o,
                                                      o + 2 * (size_t)N1, dist);
    // s12: LDS-privatized histogram
    hist_lds_kernel<<<HBLK, 256, 0, stream>>>(dist, hist);

    // ---- radix-select top-k + head ----
    selk_kernel<<<1, 256, 0, stream>>>(hist, selout);
    compact_kernel<<<(N1 + 255) / 256, 256, 0, stream>>>(dist, selout, nc, cd, ci);
    rankc_kernel<<<(N1 + 255) / 256, 256, 0, stream>>>(cd, ci, nc, vals);
    head_kernel<<<1, 512, 0, stream>>>(vals, fc1w, fc1b, ln1g, ln1b,
                                       fc2w, fc2b, ln2g, ln2b, fc3w, fc3b,
                                       (float*)d_out);
}